// Round 6
// baseline (1353.215 us; speedup 1.0000x reference)
//
#include <hip/hip_runtime.h>
#include <hip/hip_bf16.h>
#include <cstdint>
#include <cstddef>

// ---------------------------------------------------------------------------
// GCNPool fused pipeline, MI355X/gfx950.  B=8, C=32, N=4000 (pad 4096), T=12.
// Round 6: GEMM BK 32->64 (half the barrier drains, 32 MFMA per sync) plus
// XOR-swizzled k-slot LDS layout (idx = kseg ^ (row&7)): zero bank conflicts
// by construction (was 1.26e7/dispatch, ~15% of cycles).  Staging keeps LDS
// dest linear and pre-swizzles the GLOBAL source (global_load_lds rule).
// ---------------------------------------------------------------------------

typedef __attribute__((ext_vector_type(8))) short s16x8;
typedef __attribute__((ext_vector_type(4))) short s16x4;
typedef __attribute__((ext_vector_type(4))) float f32x4;

#define DEVFN __device__ __forceinline__

DEVFN void gload16(const void* g, void* l) {
  __builtin_amdgcn_global_load_lds((const __attribute__((address_space(1))) unsigned int*)g,
                                   (__attribute__((address_space(3))) unsigned int*)l, 16, 0, 0);
}

DEVFN unsigned short f2bf(float f) {  // round-to-nearest-even f32 -> bf16
  union { float f; unsigned int u; } v; v.f = f;
  unsigned int u = v.u;
  return (unsigned short)((u + 0x7fffu + ((u >> 16) & 1u)) >> 16);
}

// ---------------------------------------------------------------------------
// x (B,C,4000,12) f32 -> Xt[col=b*384+l*32+c][v 4096] bf16  (GEMM1 P operand)
//                     -> Scat[(b*4000+v)*12+l][224] slice j=0 (cols 0..31)
// ---------------------------------------------------------------------------
__global__ void k_transpose(const float* __restrict__ x,
                            unsigned short* __restrict__ Xt,
                            unsigned short* __restrict__ Scat) {
  __shared__ float ldsT[32 * 417];   // [c]*417 + vv*13 + l
  int v0 = blockIdx.x * 32;
  int b = blockIdx.y;
  int tid = threadIdx.x;
  for (int i = tid; i < 1024; i += 256) {
    int c = i >> 5, vv = i & 31;
    const float* src = x + ((size_t)(b * 32 + c) * 4000 + v0 + vv) * 12;
    f32x4 a0 = *(const f32x4*)(src);
    f32x4 a1 = *(const f32x4*)(src + 4);
    f32x4 a2 = *(const f32x4*)(src + 8);
    float* d = ldsT + c * 417 + vv * 13;
    d[0] = a0.x; d[1] = a0.y; d[2] = a0.z; d[3] = a0.w;
    d[4] = a1.x; d[5] = a1.y; d[6] = a1.z; d[7] = a1.w;
    d[8] = a2.x; d[9] = a2.y; d[10] = a2.z; d[11] = a2.w;
  }
  __syncthreads();
  for (int unit = tid; unit < 384; unit += 256) {
    int l = unit >> 5, c = unit & 31;
    alignas(16) unsigned short tmp[32];
#pragma unroll
    for (int vv = 0; vv < 32; ++vv) tmp[vv] = f2bf(ldsT[c * 417 + vv * 13 + l]);
    unsigned short* dst = Xt + (size_t)(b * 384 + l * 32 + c) * 4096 + v0;
#pragma unroll
    for (int j = 0; j < 4; ++j) *(s16x8*)(dst + j * 8) = *(const s16x8*)(tmp + j * 8);
  }
  for (int unit = tid; unit < 384; unit += 256) {
    int l = unit >> 5, vv = unit & 31;
    alignas(16) unsigned short tmp[32];
#pragma unroll
    for (int c = 0; c < 32; ++c) tmp[c] = f2bf(ldsT[c * 417 + vv * 13 + l]);
    unsigned short* dst = Scat + ((size_t)(b * 4000 + v0 + vv) * 12 + l) * 224;
#pragma unroll
    for (int j = 0; j < 4; ++j) *(s16x8*)(dst + j * 8) = *(const s16x8*)(tmp + j * 8);
  }
}

// A (4000,4000) f32 -> A_bf[4096][4096] bf16, zero-padded rows/cols.
__global__ void k_castA(const float* __restrict__ A, unsigned short* __restrict__ Abf) {
  int idx = blockIdx.x * 256 + threadIdx.x;
  int r = idx >> 10;
  int c4 = (idx & 1023) << 2;
  alignas(8) unsigned short o[4] = {0, 0, 0, 0};
  if (r < 4000 && c4 < 4000) {
    f32x4 v = *(const f32x4*)(A + (size_t)r * 4000 + c4);
    o[0] = f2bf(v.x); o[1] = f2bf(v.y); o[2] = f2bf(v.z); o[3] = f2bf(v.w);
  }
  *(s16x4*)(Abf + (size_t)r * 4096 + c4) = *(const s16x4*)o;
}

// mlp_w (64,224,1,3) f32 -> Wcat[oc][kt*224+ic] bf16 (t-independent)
__global__ void k_wcat(const float* __restrict__ mlp_w, unsigned short* __restrict__ Wcat) {
  int i = blockIdx.x * 256 + threadIdx.x;
  if (i >= 64 * 672) return;
  int oc = i / 672, k = i % 672;
  int kt = k / 224, ic = k % 224;
  Wcat[i] = f2bf(mlp_w[((size_t)oc * 224 + ic) * 3 + kt]);
}

// ---------------------------------------------------------------------------
// C[m][n] = sum_k P[m][k] * Q[n][k], bf16, K=4096.  128x128 tile, BK=64,
// 768 blocks with XCD swizzle.  LDS: Ps[128][8 kslots of 16B] swizzled
// (slot idx = kseg ^ (row&7)) -> conflict-free ds_read_b128; staging keeps
// LDS linear and pre-swizzles the global source column.
// MODE 0 (GEMM1, 24 m-tiles x 32 n-tiles): store C1 + Scat (m-decode).
// MODE 1 (GEMM2, 32 m-tiles x 24 n-tiles): store Scat only (n-decode).
// ---------------------------------------------------------------------------
template <int MODE>
__global__ __launch_bounds__(256, 4)
void k_gemm(const unsigned short* __restrict__ P, const unsigned short* __restrict__ Q,
            unsigned short* __restrict__ C1, unsigned short* __restrict__ Scat, int jcol) {
  __shared__ unsigned short lds[128 * 136];   // 34816 B; staging uses 32KB
  unsigned short* Ps = lds;                   // [128][64] swizzled
  unsigned short* Qs = lds + 8192;            // [128][64] swizzled
  int tid = threadIdx.x;
  int wid = blockIdx.x;
  int swzb = (wid & 7) * 96 + (wid >> 3);     // 768 blocks over 8 XCDs
  int m0, n0;
  if (MODE == 0) { m0 = (swzb >> 5) * 128; n0 = (swzb & 31) * 128; }
  else           { m0 = (swzb / 24) * 128; n0 = (swzb % 24) * 128; }
  int w = tid >> 6, lane = tid & 63;
  int wm = (w >> 1) * 64, wn = (w & 1) * 64;
  int lr = lane & 15, g = lane >> 4;
  int ks0 = ((g ^ (lr & 7)) * 8);             // kk=0 slot offset (shorts)
  f32x4 acc[4][4] = {};

  // staging sources: unit u = j*256+tid -> row u>>3, stored slot u&7,
  // global kseg = (u&7) ^ (row&7)
  const unsigned short* gsp[4];
  const unsigned short* gsq[4];
#pragma unroll
  for (int j = 0; j < 4; ++j) {
    int u = j * 256 + tid;
    int row = u >> 3;
    int kg = ((u & 7) ^ (row & 7)) * 8;
    gsp[j] = P + (size_t)(m0 + row) * 4096 + kg;
    gsq[j] = Q + (size_t)(n0 + row) * 4096 + kg;
  }

  for (int kt = 0; kt < 64; ++kt) {
#pragma unroll
    for (int j = 0; j < 4; ++j) gload16(gsp[j], Ps + (j * 256 + tid) * 8);
#pragma unroll
    for (int j = 0; j < 4; ++j) gload16(gsq[j], Qs + (j * 256 + tid) * 8);
#pragma unroll
    for (int j = 0; j < 4; ++j) { gsp[j] += 64; gsq[j] += 64; }
    __syncthreads();
    const unsigned short* aB = Ps + (wm + lr) * 64 + ks0;
    const unsigned short* bB = Qs + (wn + lr) * 64 + ks0;
    {
      s16x8 a[4], b[4];
#pragma unroll
      for (int f = 0; f < 4; ++f) {
        a[f] = *(const s16x8*)(aB + f * 1024);
        b[f] = *(const s16x8*)(bB + f * 1024);
      }
#pragma unroll
      for (int fm = 0; fm < 4; ++fm)
#pragma unroll
        for (int fn = 0; fn < 4; ++fn)
          acc[fm][fn] = __builtin_amdgcn_mfma_f32_16x16x32_bf16(a[fm], b[fn], acc[fm][fn], 0, 0, 0);
    }
    {
      s16x8 a[4], b[4];
#pragma unroll
      for (int f = 0; f < 4; ++f) {             // kk=1: slot idx ^ 4 -> +/-32 shorts
        a[f] = *(const s16x8*)(aB + f * 1024 + ((ks0 & 32) ? -32 : 32));
        b[f] = *(const s16x8*)(bB + f * 1024 + ((ks0 & 32) ? -32 : 32));
      }
#pragma unroll
      for (int fm = 0; fm < 4; ++fm)
#pragma unroll
        for (int fn = 0; fn < 4; ++fn)
          acc[fm][fn] = __builtin_amdgcn_mfma_f32_16x16x32_bf16(a[fm], b[fn], acc[fm][fn], 0, 0, 0);
    }
    __syncthreads();
  }

  // regs -> LDS [128][136]  (C/D: col=lane&15, row=(lane>>4)*4+reg)
#pragma unroll
  for (int fm = 0; fm < 4; ++fm)
#pragma unroll
    for (int fn = 0; fn < 4; ++fn)
#pragma unroll
      for (int r = 0; r < 4; ++r) {
        int mm = wm + fm * 16 + g * 4 + r;
        int nn = wn + fn * 16 + lr;
        lds[mm * 136 + nn] = f2bf(acc[fm][fn][r]);
      }
  __syncthreads();
  if (MODE == 0) {
    int rr = tid >> 1, half = tid & 1;
    unsigned short* dst = C1 + (size_t)(m0 + rr) * 4096 + n0 + half * 64;
    const unsigned short* srcp = lds + rr * 136 + half * 64;
#pragma unroll
    for (int j = 0; j < 8; ++j) *(s16x8*)(dst + j * 8) = *(const s16x8*)(srcp + j * 8);
    int b = m0 / 384;
    int lbase = (m0 % 384) >> 5;
    for (int unit = tid; unit < 512; unit += 256) {
      int node_l = unit & 127, lg = unit >> 7;
      int node = n0 + node_l;
      if (node < 4000) {
        alignas(16) unsigned short tmp[32];
#pragma unroll
        for (int c = 0; c < 32; ++c) tmp[c] = lds[(lg * 32 + c) * 136 + node_l];
        unsigned short* d2 = Scat + ((size_t)(b * 4000 + node) * 12 + lbase + lg) * 224 + jcol;
#pragma unroll
        for (int j = 0; j < 4; ++j) *(s16x8*)(d2 + j * 8) = *(const s16x8*)(tmp + j * 8);
      }
    }
  } else {
    int b = n0 / 384;
    int lbase = (n0 % 384) >> 5;
    for (int unit = tid; unit < 512; unit += 256) {
      int node_l = unit & 127, lg = unit >> 7;
      int node = m0 + node_l;
      if (node < 4000) {
        alignas(16) unsigned short tmp[32];
        const unsigned short* sp = lds + node_l * 136 + lg * 32;
#pragma unroll
        for (int j = 0; j < 4; ++j) *(s16x8*)(tmp + j * 8) = *(const s16x8*)(sp + j * 8);
        unsigned short* d2 = Scat + ((size_t)(b * 4000 + node) * 12 + lbase + lg) * 224 + jcol;
#pragma unroll
        for (int j = 0; j < 4; ++j) *(s16x8*)(d2 + j * 8) = *(const s16x8*)(tmp + j * 8);
      }
    }
  }
}

// ---------------------------------------------------------------------------
// mlp GEMM: OUT[oc=64][bn] = sum_{k<672} Wcat[oc][k] * Scat[bn*12+t][k..], then
// gate tanh*sigmoid -> G[b][t][c][4096] f32.  Tile 64x256, 4 waves of 64x64.
// ---------------------------------------------------------------------------
__global__ __launch_bounds__(256, 2)
void k_mlp(const unsigned short* __restrict__ Wcat, const unsigned short* __restrict__ Scat,
           const float* __restrict__ mlp_b, float* __restrict__ G) {
  __shared__ unsigned short lds[2048 + 8192];  // Ws[64][32] + Bs[256][32]
  unsigned short* Ws = lds;
  unsigned short* Bs = lds + 2048;
  int tid = threadIdx.x;
  int bn0 = blockIdx.x * 256;
  int t = blockIdx.y;      // 0..9
  int w = tid >> 6, lane = tid & 63;
  int lr = lane & 15, lk = (lane >> 4) * 8;
  f32x4 acc[4][4] = {};
  const unsigned short* gw = Wcat + (size_t)(tid >> 2) * 672 + (tid & 3) * 8;
  const unsigned short* gq = Scat + ((size_t)(bn0 + (tid >> 2)) * 12 + t) * 224 + (tid & 3) * 8;
  unsigned short* lw = Ws + tid * 8;
  unsigned short* lq = Bs + tid * 8;
  for (int s = 0; s < 21; ++s) {
    gload16(gw + s * 32, lw);
#pragma unroll
    for (int r = 0; r < 4; ++r)
      gload16(gq + (size_t)r * 64 * 2688 + s * 32, lq + r * 2048);
    __syncthreads();
    s16x8 a[4], bb[4];
#pragma unroll
    for (int f = 0; f < 4; ++f) {
      a[f] = *(const s16x8*)(Ws + (f * 16 + lr) * 32 + lk);
      bb[f] = *(const s16x8*)(Bs + (w * 64 + f * 16 + lr) * 32 + lk);
    }
#pragma unroll
    for (int fm = 0; fm < 4; ++fm)
#pragma unroll
      for (int fn = 0; fn < 4; ++fn)
        acc[fm][fn] = __builtin_amdgcn_mfma_f32_16x16x32_bf16(a[fm], bb[fn], acc[fm][fn], 0, 0, 0);
    __syncthreads();
  }
  int rbase = (lane >> 4) * 4;
#pragma unroll
  for (int fn = 0; fn < 4; ++fn) {
    int bn = bn0 + w * 64 + fn * 16 + lr;
    int b = bn / 4000;
    int n = bn - b * 4000;
    float* gbase = G + (size_t)(b * 10 + t) * 32 * 4096 + n;
#pragma unroll
    for (int fm = 0; fm < 2; ++fm)
#pragma unroll
      for (int r = 0; r < 4; ++r) {
        int c = fm * 16 + rbase + r;
        float v1 = acc[fm][fn][r] + mlp_b[c];
        float v2 = acc[fm + 2][fn][r] + mlp_b[c + 32];
        gbase[(size_t)c * 4096] = tanhf(v1) * (1.0f / (1.0f + __expf(-v2)));
      }
  }
}

// ct1: g6[b][c][n][q] = ct1_b[q] + sum_{l<10} ct1_w[q][l] * G[b][l][c][n]
__global__ void k_ct1(const float* __restrict__ G, const float* __restrict__ ct1_w,
                      const float* __restrict__ ct1_b, float* __restrict__ g6) {
  int idx = blockIdx.x * 256 + threadIdx.x;
  if (idx >= 8 * 32 * 4000) return;
  int n = idx % 4000;
  int c = (idx / 4000) % 32;
  int b = idx / (4000 * 32);
  const float* gp = G + ((size_t)(b * 10) * 32 + c) * 4096 + n;
  float v[10];
#pragma unroll
  for (int l = 0; l < 10; ++l) v[l] = gp[(size_t)l * 32 * 4096];
  float* o = g6 + (size_t)idx * 6;
#pragma unroll
  for (int q = 0; q < 6; ++q) {
    float a = ct1_b[q];
#pragma unroll
    for (int l = 0; l < 10; ++l) a += ct1_w[q * 10 + l] * v[l];
    o[q] = a;
  }
}

// f1[b][t][n] = sum_c c1[c] * g6[b][c][n][t]
__global__ void k_f1(const float* __restrict__ g6, const float* __restrict__ c1,
                     float* __restrict__ f1) {
  int idx = blockIdx.x * 128 + threadIdx.x;
  if (idx >= 8 * 4000) return;
  int n = idx % 4000, b = idx / 4000;
  float acc[6] = {};
  const float* gp = g6 + ((size_t)b * 32 * 4000 + n) * 6;
  for (int c = 0; c < 32; ++c) {
    float wv = c1[c];
    const float* p = gp + (size_t)c * 4000 * 6;
#pragma unroll
    for (int t = 0; t < 6; ++t) acc[t] += wv * p[t];
  }
  for (int t = 0; t < 6; ++t) f1[((size_t)b * 6 + t) * 4000 + n] = acc[t];
}

// f2[b][c][t] = sum_n c2[n] * g6[b][c][n][t]
__global__ void k_f2(const float* __restrict__ g6, const float* __restrict__ c2,
                     float* __restrict__ f2) {
  __shared__ float red[256 * 6];
  int bc = blockIdx.x;
  int tid = threadIdx.x;
  float acc[6] = {};
  const float* gp = g6 + (size_t)bc * 4000 * 6;
  for (int n = tid; n < 4000; n += 256) {
    float wv = c2[n];
#pragma unroll
    for (int t = 0; t < 6; ++t) acc[t] += wv * gp[(size_t)n * 6 + t];
  }
  for (int t = 0; t < 6; ++t) red[tid * 6 + t] = acc[t];
  __syncthreads();
  for (int s = 128; s > 0; s >>= 1) {
    if (tid < s)
      for (int t = 0; t < 6; ++t) red[tid * 6 + t] += red[(tid + s) * 6 + t];
    __syncthreads();
  }
  if (tid < 6) f2[bc * 6 + tid] = red[tid];
}

// m1[b][t][c] += sum over n-chunk of f1[b][t][n] * tat_w[n][c]; grid (48,16)
__global__ void k_m1(const float* __restrict__ f1, const float* __restrict__ tw,
                     float* __restrict__ m1) {
  __shared__ float red[8][32];
  int bt = blockIdx.x;
  int nc = blockIdx.y;
  int tid = threadIdx.x;
  int c = tid & 31, gi = tid >> 5;
  float acc = 0.f;
  const float* fp = f1 + (size_t)bt * 4000 + nc * 250;
  const float* twp = tw + ((size_t)nc * 250) * 32 + c;
  for (int n = gi; n < 250; n += 8) acc += fp[n] * twp[n * 32];
  red[gi][c] = acc;
  __syncthreads();
  if (tid < 32) {
    float s = 0.f;
#pragma unroll
    for (int gg = 0; gg < 8; ++gg) s += red[gg][c];
    atomicAdd(&m1[(size_t)bt * 32 + c], s);
  }
}

// logits -> sigmoid -> tat_v mix -> BN1 -> softmax -> coefs[b][t][q]
__global__ void k_att(const float* __restrict__ m1, const float* __restrict__ f2,
                      const float* __restrict__ bias, const float* __restrict__ tv,
                      const float* __restrict__ g1, const float* __restrict__ b1,
                      float* __restrict__ coefs) {
  __shared__ float sig[48 * 6], lgs[48 * 6], mu[6], iv[6];
  int tid = threadIdx.x;
  int b = tid / 6, t = tid % 6;
  if (tid < 48) {
    for (int s = 0; s < 6; ++s) {
      float a = bias[t * 6 + s];
      for (int c = 0; c < 32; ++c)
        a += m1[((size_t)b * 6 + t) * 32 + c] * f2[((size_t)b * 32 + c) * 6 + s];
      sig[tid * 6 + s] = 1.0f / (1.0f + __expf(-a));
    }
  }
  __syncthreads();
  if (tid < 48) {
    for (int q = 0; q < 6; ++q) {
      float a = 0.f;
      for (int s = 0; s < 6; ++s) a += tv[t * 6 + s] * sig[(b * 6 + s) * 6 + q];
      lgs[tid * 6 + q] = a;
    }
  }
  __syncthreads();
  if (tid < 6) {
    float s = 0, s2 = 0;
    for (int r = 0; r < 48; ++r) { float v = lgs[r * 6 + tid]; s += v; s2 += v * v; }
    float m = s / 48.f;
    mu[tid] = m;
    iv[tid] = rsqrtf(s2 / 48.f - m * m + 1e-5f);
  }
  __syncthreads();
  if (tid < 48) {
    float v[6], mx = -1e30f;
    for (int q = 0; q < 6; ++q) {
      v[q] = (lgs[tid * 6 + q] - mu[q]) * iv[q] * g1[q] + b1[q];
      mx = fmaxf(mx, v[q]);
    }
    float s = 0;
    for (int q = 0; q < 6; ++q) { v[q] = __expf(v[q] - mx); s += v[q]; }
    float inv = 1.0f / s;
    for (int q = 0; q < 6; ++q) coefs[tid * 6 + q] = v[q] * inv;
  }
}

// y = attention-mix(g6) + conv1(x)[...,6:] -> out (pre-BN2)
__global__ void k_final1(const float* __restrict__ x, const float* __restrict__ cw,
                         const float* __restrict__ cb, const float* __restrict__ g6,
                         const float* __restrict__ coefs, float* __restrict__ out) {
  __shared__ float xt[32 * 8 * 6];
  __shared__ float cwT[1024];
  __shared__ float cfs[36], cbs[32];
  int n0 = blockIdx.x * 8;
  int b = blockIdx.y;
  int tid = threadIdx.x;
  {
    int ci = tid >> 3, seg = tid & 7;
    const float* xp = x + ((size_t)(b * 32 + ci) * 4000 + n0 + seg) * 12 + 6;
#pragma unroll
    for (int q = 0; q < 6; ++q) xt[(ci * 8 + seg) * 6 + q] = xp[q];
  }
  for (int i = tid; i < 1024; i += 256) { int o = i >> 5, ci = i & 31; cwT[ci * 32 + o] = cw[i]; }
  if (tid < 36) cfs[tid] = coefs[b * 36 + tid];
  if (tid < 32) cbs[tid] = cb[tid];
  __syncthreads();
  int nn = tid & 7, c = tid >> 3;
  const float* gp = g6 + ((size_t)(b * 32 + c) * 4000 + n0 + nn) * 6;
  float gv[6];
#pragma unroll
  for (int l = 0; l < 6; ++l) gv[l] = gp[l];
  float y[6];
#pragma unroll
  for (int q = 0; q < 6; ++q) {
    float at = 0.f;
#pragma unroll
    for (int l = 0; l < 6; ++l) at += gv[l] * cfs[q * 6 + l];
    y[q] = at + cbs[c];
  }
  for (int ci = 0; ci < 32; ++ci) {
    float wv = cwT[ci * 32 + c];
#pragma unroll
    for (int q = 0; q < 6; ++q) y[q] += wv * xt[(ci * 8 + nn) * 6 + q];
  }
  float* op = out + ((size_t)(b * 32 + c) * 4000 + n0 + nn) * 6;
#pragma unroll
  for (int q = 0; q < 6; ++q) op[q] = y[q];
}

// per-channel sum/sumsq of out: grid (4, 256), f32x4 + shfl reduce + atomicAdd
__global__ void k_stats(const float* __restrict__ out, float* __restrict__ stats) {
  __shared__ float r1[4], r2[4];
  int bc = blockIdx.y;
  int c = bc & 31;
  int tid = threadIdx.x;
  const float* p = out + (size_t)bc * 24000 + blockIdx.x * 6000;
  float s = 0.f, s2 = 0.f;
  for (int i = tid * 4; i < 6000; i += 1024) {
    f32x4 v = *(const f32x4*)(p + i);
    s  += v.x + v.y + v.z + v.w;
    s2 += v.x * v.x + v.y * v.y + v.z * v.z + v.w * v.w;
  }
#pragma unroll
  for (int off = 32; off > 0; off >>= 1) {
    s  += __shfl_down(s, off);
    s2 += __shfl_down(s2, off);
  }
  int lane = tid & 63, w = tid >> 6;
  if (lane == 0) { r1[w] = s; r2[w] = s2; }
  __syncthreads();
  if (tid == 0) {
    atomicAdd(&stats[c],      r1[0] + r1[1] + r1[2] + r1[3]);
    atomicAdd(&stats[32 + c], r2[0] + r2[1] + r2[2] + r2[3]);
  }
}

__global__ void k_final2(float* __restrict__ out, const float* __restrict__ stats,
                         const float* __restrict__ g2, const float* __restrict__ b2) {
  int idx = (blockIdx.x * 256 + threadIdx.x) * 4;
  if (idx >= 6144000) return;
  int c = (idx / 24000) % 32;
  float mean = stats[c] * (1.0f / 192000.f);
  float var = stats[32 + c] * (1.0f / 192000.f) - mean * mean;
  float sc = rsqrtf(var + 1e-5f) * g2[c];
  float sh = b2[c] - mean * sc;
  f32x4 v = *(f32x4*)(out + idx);
  v.x = v.x * sc + sh; v.y = v.y * sc + sh; v.z = v.z * sc + sh; v.w = v.w * sc + sh;
  *(f32x4*)(out + idx) = v;
}

// ---------------------------------------------------------------------------
extern "C" void kernel_launch(void* const* d_in, const int* in_sizes, int n_in,
                              void* d_out, int out_size, void* d_ws, size_t ws_size,
                              hipStream_t stream) {
  (void)in_sizes; (void)n_in; (void)out_size;
  const float* x       = (const float*)d_in[0];
  const float* A[3]    = {(const float*)d_in[1], (const float*)d_in[2], (const float*)d_in[3]};
  const float* conv1_w = (const float*)d_in[4];
  const float* conv1_b = (const float*)d_in[5];
  const float* mlp_w   = (const float*)d_in[6];
  const float* mlp_b   = (const float*)d_in[7];
  const float* ct1_w   = (const float*)d_in[8];
  const float* ct1_b   = (const float*)d_in[9];
  const float* c1w     = (const float*)d_in[10];
  const float* c2w     = (const float*)d_in[11];
  const float* tw      = (const float*)d_in[12];
  const float* tbias   = (const float*)d_in[13];
  const float* tv      = (const float*)d_in[14];
  const float* bn1g    = (const float*)d_in[15];
  const float* bn1b    = (const float*)d_in[16];
  const float* bn2g    = (const float*)d_in[17];
  const float* bn2b    = (const float*)d_in[18];
  float* out = (float*)d_out;

  char* ws = (char*)d_ws;
  size_t off = 0;
  auto alloc = [&](size_t bytes) { size_t r = off; off += (bytes + 255) & ~(size_t)255; return r; };
  size_t oScat = alloc(172032000);   // [32000*12][224] bf16
  size_t oXt   = alloc(25165824);    // [3072][4096] bf16 ; later g6 (24.576MB f32)
  size_t oA    = alloc(33554432);    // Abf [4096][4096] bf16 ; with oY1t, later G
  size_t oY1t  = alloc(25165824);    // [3072][4096] bf16
  size_t oWcat = alloc(86016);
  size_t oF1 = alloc(768000);
  size_t oF2 = alloc(6144);
  size_t oM1 = alloc(6144);
  size_t oCf = alloc(1152);
  size_t oSt = alloc(256);
  if (ws_size < off) return;  // insufficient scratch -> visible validation failure

  unsigned short* Scat = (unsigned short*)(ws + oScat);
  unsigned short* Xt   = (unsigned short*)(ws + oXt);
  float*          g6   = (float*)(ws + oXt);
  unsigned short* Abf  = (unsigned short*)(ws + oA);
  float*          G    = (float*)(ws + oA);
  unsigned short* Y1t  = (unsigned short*)(ws + oY1t);
  unsigned short* Wcat = (unsigned short*)(ws + oWcat);

  hipMemsetAsync(Xt, 0, 25165824, stream);       // v-padding 4000..4095 must be 0
  hipMemsetAsync(ws + oSt, 0, 256, stream);      // stats accumulators
  hipMemsetAsync(ws + oM1, 0, 6144, stream);     // m1 accumulators
  k_transpose<<<dim3(125, 8), 256, 0, stream>>>(x, Xt, Scat);
  k_wcat<<<168, 256, 0, stream>>>(mlp_w, Wcat);
  for (int i = 0; i < 3; ++i) {
    k_castA<<<16384, 256, 0, stream>>>(A[i], Abf);
    // Y1t[col][node] = sum_v Xt[col][v]*Abf[node][v]; Scat j=2i+1
    k_gemm<0><<<768, 256, 0, stream>>>(Xt, Abf, Y1t, Scat, (2 * i + 1) * 32);
    // x2[node][col] = sum_v Abf[node][v]*Y1t[col][v]; Scat j=2i+2
    k_gemm<1><<<768, 256, 0, stream>>>(Abf, Y1t, nullptr, Scat, (2 * i + 2) * 32);
  }
  k_mlp<<<dim3(125, 10), 256, 0, stream>>>(Wcat, Scat, mlp_b, G);
  k_ct1<<<4000, 256, 0, stream>>>(G, ct1_w, ct1_b, g6);
  k_f1<<<250, 128, 0, stream>>>(g6, c1w, (float*)(ws + oF1));
  k_f2<<<256, 256, 0, stream>>>(g6, c2w, (float*)(ws + oF2));
  k_m1<<<dim3(48, 16), 256, 0, stream>>>((float*)(ws + oF1), tw, (float*)(ws + oM1));
  k_att<<<1, 64, 0, stream>>>((float*)(ws + oM1), (float*)(ws + oF2), tbias, tv, bn1g, bn1b,
                              (float*)(ws + oCf));
  k_final1<<<dim3(500, 8), 256, 0, stream>>>(x, conv1_w, conv1_b, g6, (float*)(ws + oCf), out);
  k_stats<<<dim3(4, 256), 256, 0, stream>>>(out, (float*)(ws + oSt));
  k_final2<<<6000, 256, 0, stream>>>(out, (float*)(ws + oSt), bn2g, bn2b);
}

// Round 7
// 913.354 us; speedup vs baseline: 1.4816x; 1.4816x over previous
//
#include <hip/hip_runtime.h>
#include <hip/hip_bf16.h>
#include <cstdint>
#include <cstddef>

// ---------------------------------------------------------------------------
// GCNPool fused pipeline, MI355X/gfx950.  B=8, C=32, N=4000 (pad 4096), T=12.
// Round 7: round-6 GEMM (BK=64, XOR-swizzled k-slots, 0 bank conflicts) with
// the spill bug fixed: __launch_bounds__(256,2) not (256,4).  gfx950's unified
// VGPR/AGPR file means (256,4) capped us at 128 regs -> acc(64 AGPR) left only
// 64 VGPRs -> per-iteration scratch spills (VGPR_Count=64, +100MB HBM traffic).
// ---------------------------------------------------------------------------

typedef __attribute__((ext_vector_type(8))) short s16x8;
typedef __attribute__((ext_vector_type(4))) short s16x4;
typedef __attribute__((ext_vector_type(4))) float f32x4;

#define DEVFN __device__ __forceinline__

DEVFN void gload16(const void* g, void* l) {
  __builtin_amdgcn_global_load_lds((const __attribute__((address_space(1))) unsigned int*)g,
                                   (__attribute__((address_space(3))) unsigned int*)l, 16, 0, 0);
}

DEVFN unsigned short f2bf(float f) {  // round-to-nearest-even f32 -> bf16
  union { float f; unsigned int u; } v; v.f = f;
  unsigned int u = v.u;
  return (unsigned short)((u + 0x7fffu + ((u >> 16) & 1u)) >> 16);
}

// ---------------------------------------------------------------------------
// x (B,C,4000,12) f32 -> Xt[col=b*384+l*32+c][v 4096] bf16  (GEMM1 P operand)
//                     -> Scat[(b*4000+v)*12+l][224] slice j=0 (cols 0..31)
// ---------------------------------------------------------------------------
__global__ void k_transpose(const float* __restrict__ x,
                            unsigned short* __restrict__ Xt,
                            unsigned short* __restrict__ Scat) {
  __shared__ float ldsT[32 * 417];   // [c]*417 + vv*13 + l
  int v0 = blockIdx.x * 32;
  int b = blockIdx.y;
  int tid = threadIdx.x;
  for (int i = tid; i < 1024; i += 256) {
    int c = i >> 5, vv = i & 31;
    const float* src = x + ((size_t)(b * 32 + c) * 4000 + v0 + vv) * 12;
    f32x4 a0 = *(const f32x4*)(src);
    f32x4 a1 = *(const f32x4*)(src + 4);
    f32x4 a2 = *(const f32x4*)(src + 8);
    float* d = ldsT + c * 417 + vv * 13;
    d[0] = a0.x; d[1] = a0.y; d[2] = a0.z; d[3] = a0.w;
    d[4] = a1.x; d[5] = a1.y; d[6] = a1.z; d[7] = a1.w;
    d[8] = a2.x; d[9] = a2.y; d[10] = a2.z; d[11] = a2.w;
  }
  __syncthreads();
  for (int unit = tid; unit < 384; unit += 256) {
    int l = unit >> 5, c = unit & 31;
    alignas(16) unsigned short tmp[32];
#pragma unroll
    for (int vv = 0; vv < 32; ++vv) tmp[vv] = f2bf(ldsT[c * 417 + vv * 13 + l]);
    unsigned short* dst = Xt + (size_t)(b * 384 + l * 32 + c) * 4096 + v0;
#pragma unroll
    for (int j = 0; j < 4; ++j) *(s16x8*)(dst + j * 8) = *(const s16x8*)(tmp + j * 8);
  }
  for (int unit = tid; unit < 384; unit += 256) {
    int l = unit >> 5, vv = unit & 31;
    alignas(16) unsigned short tmp[32];
#pragma unroll
    for (int c = 0; c < 32; ++c) tmp[c] = f2bf(ldsT[c * 417 + vv * 13 + l]);
    unsigned short* dst = Scat + ((size_t)(b * 4000 + v0 + vv) * 12 + l) * 224;
#pragma unroll
    for (int j = 0; j < 4; ++j) *(s16x8*)(dst + j * 8) = *(const s16x8*)(tmp + j * 8);
  }
}

// A (4000,4000) f32 -> A_bf[4096][4096] bf16, zero-padded rows/cols.
__global__ void k_castA(const float* __restrict__ A, unsigned short* __restrict__ Abf) {
  int idx = blockIdx.x * 256 + threadIdx.x;
  int r = idx >> 10;
  int c4 = (idx & 1023) << 2;
  alignas(8) unsigned short o[4] = {0, 0, 0, 0};
  if (r < 4000 && c4 < 4000) {
    f32x4 v = *(const f32x4*)(A + (size_t)r * 4000 + c4);
    o[0] = f2bf(v.x); o[1] = f2bf(v.y); o[2] = f2bf(v.z); o[3] = f2bf(v.w);
  }
  *(s16x4*)(Abf + (size_t)r * 4096 + c4) = *(const s16x4*)o;
}

// mlp_w (64,224,1,3) f32 -> Wcat[oc][kt*224+ic] bf16 (t-independent)
__global__ void k_wcat(const float* __restrict__ mlp_w, unsigned short* __restrict__ Wcat) {
  int i = blockIdx.x * 256 + threadIdx.x;
  if (i >= 64 * 672) return;
  int oc = i / 672, k = i % 672;
  int kt = k / 224, ic = k % 224;
  Wcat[i] = f2bf(mlp_w[((size_t)oc * 224 + ic) * 3 + kt]);
}

// ---------------------------------------------------------------------------
// C[m][n] = sum_k P[m][k] * Q[n][k], bf16, K=4096.  128x128 tile, BK=64,
// 768 blocks with XCD swizzle.  LDS: Ps[128][8 kslots of 16B] swizzled
// (slot idx = kseg ^ (row&7)) -> conflict-free ds_read_b128; staging keeps
// LDS linear and pre-swizzles the global source column.
// MODE 0 (GEMM1, 24 m-tiles x 32 n-tiles): store C1 + Scat (m-decode).
// MODE 1 (GEMM2, 32 m-tiles x 24 n-tiles): store Scat only (n-decode).
// ---------------------------------------------------------------------------
template <int MODE>
__global__ __launch_bounds__(256, 2)
void k_gemm(const unsigned short* __restrict__ P, const unsigned short* __restrict__ Q,
            unsigned short* __restrict__ C1, unsigned short* __restrict__ Scat, int jcol) {
  __shared__ unsigned short lds[128 * 136];   // 34816 B; staging uses 32KB
  unsigned short* Ps = lds;                   // [128][64] swizzled
  unsigned short* Qs = lds + 8192;            // [128][64] swizzled
  int tid = threadIdx.x;
  int wid = blockIdx.x;
  int swzb = (wid & 7) * 96 + (wid >> 3);     // 768 blocks over 8 XCDs
  int m0, n0;
  if (MODE == 0) { m0 = (swzb >> 5) * 128; n0 = (swzb & 31) * 128; }
  else           { m0 = (swzb / 24) * 128; n0 = (swzb % 24) * 128; }
  int w = tid >> 6, lane = tid & 63;
  int wm = (w >> 1) * 64, wn = (w & 1) * 64;
  int lr = lane & 15, g = lane >> 4;
  int ks0 = ((g ^ (lr & 7)) * 8);             // kk=0 slot offset (shorts)
  f32x4 acc[4][4] = {};

  // staging sources: unit u = j*256+tid -> row u>>3, stored slot u&7,
  // global kseg = (u&7) ^ (row&7)
  const unsigned short* gsp[4];
  const unsigned short* gsq[4];
#pragma unroll
  for (int j = 0; j < 4; ++j) {
    int u = j * 256 + tid;
    int row = u >> 3;
    int kg = ((u & 7) ^ (row & 7)) * 8;
    gsp[j] = P + (size_t)(m0 + row) * 4096 + kg;
    gsq[j] = Q + (size_t)(n0 + row) * 4096 + kg;
  }

  for (int kt = 0; kt < 64; ++kt) {
#pragma unroll
    for (int j = 0; j < 4; ++j) gload16(gsp[j], Ps + (j * 256 + tid) * 8);
#pragma unroll
    for (int j = 0; j < 4; ++j) gload16(gsq[j], Qs + (j * 256 + tid) * 8);
#pragma unroll
    for (int j = 0; j < 4; ++j) { gsp[j] += 64; gsq[j] += 64; }
    __syncthreads();
    const unsigned short* aB = Ps + (wm + lr) * 64 + ks0;
    const unsigned short* bB = Qs + (wn + lr) * 64 + ks0;
    {
      s16x8 a[4], b[4];
#pragma unroll
      for (int f = 0; f < 4; ++f) {
        a[f] = *(const s16x8*)(aB + f * 1024);
        b[f] = *(const s16x8*)(bB + f * 1024);
      }
#pragma unroll
      for (int fm = 0; fm < 4; ++fm)
#pragma unroll
        for (int fn = 0; fn < 4; ++fn)
          acc[fm][fn] = __builtin_amdgcn_mfma_f32_16x16x32_bf16(a[fm], b[fn], acc[fm][fn], 0, 0, 0);
    }
    {
      s16x8 a[4], b[4];
#pragma unroll
      for (int f = 0; f < 4; ++f) {             // kk=1: slot idx ^ 4 -> +/-32 shorts
        a[f] = *(const s16x8*)(aB + f * 1024 + ((ks0 & 32) ? -32 : 32));
        b[f] = *(const s16x8*)(bB + f * 1024 + ((ks0 & 32) ? -32 : 32));
      }
#pragma unroll
      for (int fm = 0; fm < 4; ++fm)
#pragma unroll
        for (int fn = 0; fn < 4; ++fn)
          acc[fm][fn] = __builtin_amdgcn_mfma_f32_16x16x32_bf16(a[fm], b[fn], acc[fm][fn], 0, 0, 0);
    }
    __syncthreads();
  }

  // regs -> LDS [128][136]  (C/D: col=lane&15, row=(lane>>4)*4+reg)
#pragma unroll
  for (int fm = 0; fm < 4; ++fm)
#pragma unroll
    for (int fn = 0; fn < 4; ++fn)
#pragma unroll
      for (int r = 0; r < 4; ++r) {
        int mm = wm + fm * 16 + g * 4 + r;
        int nn = wn + fn * 16 + lr;
        lds[mm * 136 + nn] = f2bf(acc[fm][fn][r]);
      }
  __syncthreads();
  if (MODE == 0) {
    int rr = tid >> 1, half = tid & 1;
    unsigned short* dst = C1 + (size_t)(m0 + rr) * 4096 + n0 + half * 64;
    const unsigned short* srcp = lds + rr * 136 + half * 64;
#pragma unroll
    for (int j = 0; j < 8; ++j) *(s16x8*)(dst + j * 8) = *(const s16x8*)(srcp + j * 8);
    int b = m0 / 384;
    int lbase = (m0 % 384) >> 5;
    for (int unit = tid; unit < 512; unit += 256) {
      int node_l = unit & 127, lg = unit >> 7;
      int node = n0 + node_l;
      if (node < 4000) {
        alignas(16) unsigned short tmp[32];
#pragma unroll
        for (int c = 0; c < 32; ++c) tmp[c] = lds[(lg * 32 + c) * 136 + node_l];
        unsigned short* d2 = Scat + ((size_t)(b * 4000 + node) * 12 + lbase + lg) * 224 + jcol;
#pragma unroll
        for (int j = 0; j < 4; ++j) *(s16x8*)(d2 + j * 8) = *(const s16x8*)(tmp + j * 8);
      }
    }
  } else {
    int b = n0 / 384;
    int lbase = (n0 % 384) >> 5;
    for (int unit = tid; unit < 512; unit += 256) {
      int node_l = unit & 127, lg = unit >> 7;
      int node = m0 + node_l;
      if (node < 4000) {
        alignas(16) unsigned short tmp[32];
        const unsigned short* sp = lds + node_l * 136 + lg * 32;
#pragma unroll
        for (int j = 0; j < 4; ++j) *(s16x8*)(tmp + j * 8) = *(const s16x8*)(sp + j * 8);
        unsigned short* d2 = Scat + ((size_t)(b * 4000 + node) * 12 + lbase + lg) * 224 + jcol;
#pragma unroll
        for (int j = 0; j < 4; ++j) *(s16x8*)(d2 + j * 8) = *(const s16x8*)(tmp + j * 8);
      }
    }
  }
}

// ---------------------------------------------------------------------------
// mlp GEMM: OUT[oc=64][bn] = sum_{k<672} Wcat[oc][k] * Scat[bn*12+t][k..], then
// gate tanh*sigmoid -> G[b][t][c][4096] f32.  Tile 64x256, 4 waves of 64x64.
// ---------------------------------------------------------------------------
__global__ __launch_bounds__(256, 2)
void k_mlp(const unsigned short* __restrict__ Wcat, const unsigned short* __restrict__ Scat,
           const float* __restrict__ mlp_b, float* __restrict__ G) {
  __shared__ unsigned short lds[2048 + 8192];  // Ws[64][32] + Bs[256][32]
  unsigned short* Ws = lds;
  unsigned short* Bs = lds + 2048;
  int tid = threadIdx.x;
  int bn0 = blockIdx.x * 256;
  int t = blockIdx.y;      // 0..9
  int w = tid >> 6, lane = tid & 63;
  int lr = lane & 15, lk = (lane >> 4) * 8;
  f32x4 acc[4][4] = {};
  const unsigned short* gw = Wcat + (size_t)(tid >> 2) * 672 + (tid & 3) * 8;
  const unsigned short* gq = Scat + ((size_t)(bn0 + (tid >> 2)) * 12 + t) * 224 + (tid & 3) * 8;
  unsigned short* lw = Ws + tid * 8;
  unsigned short* lq = Bs + tid * 8;
  for (int s = 0; s < 21; ++s) {
    gload16(gw + s * 32, lw);
#pragma unroll
    for (int r = 0; r < 4; ++r)
      gload16(gq + (size_t)r * 64 * 2688 + s * 32, lq + r * 2048);
    __syncthreads();
    s16x8 a[4], bb[4];
#pragma unroll
    for (int f = 0; f < 4; ++f) {
      a[f] = *(const s16x8*)(Ws + (f * 16 + lr) * 32 + lk);
      bb[f] = *(const s16x8*)(Bs + (w * 64 + f * 16 + lr) * 32 + lk);
    }
#pragma unroll
    for (int fm = 0; fm < 4; ++fm)
#pragma unroll
      for (int fn = 0; fn < 4; ++fn)
        acc[fm][fn] = __builtin_amdgcn_mfma_f32_16x16x32_bf16(a[fm], bb[fn], acc[fm][fn], 0, 0, 0);
    __syncthreads();
  }
  int rbase = (lane >> 4) * 4;
#pragma unroll
  for (int fn = 0; fn < 4; ++fn) {
    int bn = bn0 + w * 64 + fn * 16 + lr;
    int b = bn / 4000;
    int n = bn - b * 4000;
    float* gbase = G + (size_t)(b * 10 + t) * 32 * 4096 + n;
#pragma unroll
    for (int fm = 0; fm < 2; ++fm)
#pragma unroll
      for (int r = 0; r < 4; ++r) {
        int c = fm * 16 + rbase + r;
        float v1 = acc[fm][fn][r] + mlp_b[c];
        float v2 = acc[fm + 2][fn][r] + mlp_b[c + 32];
        gbase[(size_t)c * 4096] = tanhf(v1) * (1.0f / (1.0f + __expf(-v2)));
      }
  }
}

// ct1: g6[b][c][n][q] = ct1_b[q] + sum_{l<10} ct1_w[q][l] * G[b][l][c][n]
__global__ void k_ct1(const float* __restrict__ G, const float* __restrict__ ct1_w,
                      const float* __restrict__ ct1_b, float* __restrict__ g6) {
  int idx = blockIdx.x * 256 + threadIdx.x;
  if (idx >= 8 * 32 * 4000) return;
  int n = idx % 4000;
  int c = (idx / 4000) % 32;
  int b = idx / (4000 * 32);
  const float* gp = G + ((size_t)(b * 10) * 32 + c) * 4096 + n;
  float v[10];
#pragma unroll
  for (int l = 0; l < 10; ++l) v[l] = gp[(size_t)l * 32 * 4096];
  float* o = g6 + (size_t)idx * 6;
#pragma unroll
  for (int q = 0; q < 6; ++q) {
    float a = ct1_b[q];
#pragma unroll
    for (int l = 0; l < 10; ++l) a += ct1_w[q * 10 + l] * v[l];
    o[q] = a;
  }
}

// f1[b][t][n] = sum_c c1[c] * g6[b][c][n][t]
__global__ void k_f1(const float* __restrict__ g6, const float* __restrict__ c1,
                     float* __restrict__ f1) {
  int idx = blockIdx.x * 128 + threadIdx.x;
  if (idx >= 8 * 4000) return;
  int n = idx % 4000, b = idx / 4000;
  float acc[6] = {};
  const float* gp = g6 + ((size_t)b * 32 * 4000 + n) * 6;
  for (int c = 0; c < 32; ++c) {
    float wv = c1[c];
    const float* p = gp + (size_t)c * 4000 * 6;
#pragma unroll
    for (int t = 0; t < 6; ++t) acc[t] += wv * p[t];
  }
  for (int t = 0; t < 6; ++t) f1[((size_t)b * 6 + t) * 4000 + n] = acc[t];
}

// f2[b][c][t] = sum_n c2[n] * g6[b][c][n][t]
__global__ void k_f2(const float* __restrict__ g6, const float* __restrict__ c2,
                     float* __restrict__ f2) {
  __shared__ float red[256 * 6];
  int bc = blockIdx.x;
  int tid = threadIdx.x;
  float acc[6] = {};
  const float* gp = g6 + (size_t)bc * 4000 * 6;
  for (int n = tid; n < 4000; n += 256) {
    float wv = c2[n];
#pragma unroll
    for (int t = 0; t < 6; ++t) acc[t] += wv * gp[(size_t)n * 6 + t];
  }
  for (int t = 0; t < 6; ++t) red[tid * 6 + t] = acc[t];
  __syncthreads();
  for (int s = 128; s > 0; s >>= 1) {
    if (tid < s)
      for (int t = 0; t < 6; ++t) red[tid * 6 + t] += red[(tid + s) * 6 + t];
    __syncthreads();
  }
  if (tid < 6) f2[bc * 6 + tid] = red[tid];
}

// m1[b][t][c] += sum over n-chunk of f1[b][t][n] * tat_w[n][c]; grid (48,16)
__global__ void k_m1(const float* __restrict__ f1, const float* __restrict__ tw,
                     float* __restrict__ m1) {
  __shared__ float red[8][32];
  int bt = blockIdx.x;
  int nc = blockIdx.y;
  int tid = threadIdx.x;
  int c = tid & 31, gi = tid >> 5;
  float acc = 0.f;
  const float* fp = f1 + (size_t)bt * 4000 + nc * 250;
  const float* twp = tw + ((size_t)nc * 250) * 32 + c;
  for (int n = gi; n < 250; n += 8) acc += fp[n] * twp[n * 32];
  red[gi][c] = acc;
  __syncthreads();
  if (tid < 32) {
    float s = 0.f;
#pragma unroll
    for (int gg = 0; gg < 8; ++gg) s += red[gg][c];
    atomicAdd(&m1[(size_t)bt * 32 + c], s);
  }
}

// logits -> sigmoid -> tat_v mix -> BN1 -> softmax -> coefs[b][t][q]
__global__ void k_att(const float* __restrict__ m1, const float* __restrict__ f2,
                      const float* __restrict__ bias, const float* __restrict__ tv,
                      const float* __restrict__ g1, const float* __restrict__ b1,
                      float* __restrict__ coefs) {
  __shared__ float sig[48 * 6], lgs[48 * 6], mu[6], iv[6];
  int tid = threadIdx.x;
  int b = tid / 6, t = tid % 6;
  if (tid < 48) {
    for (int s = 0; s < 6; ++s) {
      float a = bias[t * 6 + s];
      for (int c = 0; c < 32; ++c)
        a += m1[((size_t)b * 6 + t) * 32 + c] * f2[((size_t)b * 32 + c) * 6 + s];
      sig[tid * 6 + s] = 1.0f / (1.0f + __expf(-a));
    }
  }
  __syncthreads();
  if (tid < 48) {
    for (int q = 0; q < 6; ++q) {
      float a = 0.f;
      for (int s = 0; s < 6; ++s) a += tv[t * 6 + s] * sig[(b * 6 + s) * 6 + q];
      lgs[tid * 6 + q] = a;
    }
  }
  __syncthreads();
  if (tid < 6) {
    float s = 0, s2 = 0;
    for (int r = 0; r < 48; ++r) { float v = lgs[r * 6 + tid]; s += v; s2 += v * v; }
    float m = s / 48.f;
    mu[tid] = m;
    iv[tid] = rsqrtf(s2 / 48.f - m * m + 1e-5f);
  }
  __syncthreads();
  if (tid < 48) {
    float v[6], mx = -1e30f;
    for (int q = 0; q < 6; ++q) {
      v[q] = (lgs[tid * 6 + q] - mu[q]) * iv[q] * g1[q] + b1[q];
      mx = fmaxf(mx, v[q]);
    }
    float s = 0;
    for (int q = 0; q < 6; ++q) { v[q] = __expf(v[q] - mx); s += v[q]; }
    float inv = 1.0f / s;
    for (int q = 0; q < 6; ++q) coefs[tid * 6 + q] = v[q] * inv;
  }
}

// y = attention-mix(g6) + conv1(x)[...,6:] -> out (pre-BN2)
__global__ void k_final1(const float* __restrict__ x, const float* __restrict__ cw,
                         const float* __restrict__ cb, const float* __restrict__ g6,
                         const float* __restrict__ coefs, float* __restrict__ out) {
  __shared__ float xt[32 * 8 * 6];
  __shared__ float cwT[1024];
  __shared__ float cfs[36], cbs[32];
  int n0 = blockIdx.x * 8;
  int b = blockIdx.y;
  int tid = threadIdx.x;
  {
    int ci = tid >> 3, seg = tid & 7;
    const float* xp = x + ((size_t)(b * 32 + ci) * 4000 + n0 + seg) * 12 + 6;
#pragma unroll
    for (int q = 0; q < 6; ++q) xt[(ci * 8 + seg) * 6 + q] = xp[q];
  }
  for (int i = tid; i < 1024; i += 256) { int o = i >> 5, ci = i & 31; cwT[ci * 32 + o] = cw[i]; }
  if (tid < 36) cfs[tid] = coefs[b * 36 + tid];
  if (tid < 32) cbs[tid] = cb[tid];
  __syncthreads();
  int nn = tid & 7, c = tid >> 3;
  const float* gp = g6 + ((size_t)(b * 32 + c) * 4000 + n0 + nn) * 6;
  float gv[6];
#pragma unroll
  for (int l = 0; l < 6; ++l) gv[l] = gp[l];
  float y[6];
#pragma unroll
  for (int q = 0; q < 6; ++q) {
    float at = 0.f;
#pragma unroll
    for (int l = 0; l < 6; ++l) at += gv[l] * cfs[q * 6 + l];
    y[q] = at + cbs[c];
  }
  for (int ci = 0; ci < 32; ++ci) {
    float wv = cwT[ci * 32 + c];
#pragma unroll
    for (int q = 0; q < 6; ++q) y[q] += wv * xt[(ci * 8 + nn) * 6 + q];
  }
  float* op = out + ((size_t)(b * 32 + c) * 4000 + n0 + nn) * 6;
#pragma unroll
  for (int q = 0; q < 6; ++q) op[q] = y[q];
}

// per-channel sum/sumsq of out: grid (4, 256), f32x4 + shfl reduce + atomicAdd
__global__ void k_stats(const float* __restrict__ out, float* __restrict__ stats) {
  __shared__ float r1[4], r2[4];
  int bc = blockIdx.y;
  int c = bc & 31;
  int tid = threadIdx.x;
  const float* p = out + (size_t)bc * 24000 + blockIdx.x * 6000;
  float s = 0.f, s2 = 0.f;
  for (int i = tid * 4; i < 6000; i += 1024) {
    f32x4 v = *(const f32x4*)(p + i);
    s  += v.x + v.y + v.z + v.w;
    s2 += v.x * v.x + v.y * v.y + v.z * v.z + v.w * v.w;
  }
#pragma unroll
  for (int off = 32; off > 0; off >>= 1) {
    s  += __shfl_down(s, off);
    s2 += __shfl_down(s2, off);
  }
  int lane = tid & 63, w = tid >> 6;
  if (lane == 0) { r1[w] = s; r2[w] = s2; }
  __syncthreads();
  if (tid == 0) {
    atomicAdd(&stats[c],      r1[0] + r1[1] + r1[2] + r1[3]);
    atomicAdd(&stats[32 + c], r2[0] + r2[1] + r2[2] + r2[3]);
  }
}

__global__ void k_final2(float* __restrict__ out, const float* __restrict__ stats,
                         const float* __restrict__ g2, const float* __restrict__ b2) {
  int idx = (blockIdx.x * 256 + threadIdx.x) * 4;
  if (idx >= 6144000) return;
  int c = (idx / 24000) % 32;
  float mean = stats[c] * (1.0f / 192000.f);
  float var = stats[32 + c] * (1.0f / 192000.f) - mean * mean;
  float sc = rsqrtf(var + 1e-5f) * g2[c];
  float sh = b2[c] - mean * sc;
  f32x4 v = *(f32x4*)(out + idx);
  v.x = v.x * sc + sh; v.y = v.y * sc + sh; v.z = v.z * sc + sh; v.w = v.w * sc + sh;
  *(f32x4*)(out + idx) = v;
}

// ---------------------------------------------------------------------------
extern "C" void kernel_launch(void* const* d_in, const int* in_sizes, int n_in,
                              void* d_out, int out_size, void* d_ws, size_t ws_size,
                              hipStream_t stream) {
  (void)in_sizes; (void)n_in; (void)out_size;
  const float* x       = (const float*)d_in[0];
  const float* A[3]    = {(const float*)d_in[1], (const float*)d_in[2], (const float*)d_in[3]};
  const float* conv1_w = (const float*)d_in[4];
  const float* conv1_b = (const float*)d_in[5];
  const float* mlp_w   = (const float*)d_in[6];
  const float* mlp_b   = (const float*)d_in[7];
  const float* ct1_w   = (const float*)d_in[8];
  const float* ct1_b   = (const float*)d_in[9];
  const float* c1w     = (const float*)d_in[10];
  const float* c2w     = (const float*)d_in[11];
  const float* tw      = (const float*)d_in[12];
  const float* tbias   = (const float*)d_in[13];
  const float* tv      = (const float*)d_in[14];
  const float* bn1g    = (const float*)d_in[15];
  const float* bn1b    = (const float*)d_in[16];
  const float* bn2g    = (const float*)d_in[17];
  const float* bn2b    = (const float*)d_in[18];
  float* out = (float*)d_out;

  char* ws = (char*)d_ws;
  size_t off = 0;
  auto alloc = [&](size_t bytes) { size_t r = off; off += (bytes + 255) & ~(size_t)255; return r; };
  size_t oScat = alloc(172032000);   // [32000*12][224] bf16
  size_t oXt   = alloc(25165824);    // [3072][4096] bf16 ; later g6 (24.576MB f32)
  size_t oA    = alloc(33554432);    // Abf [4096][4096] bf16 ; with oY1t, later G
  size_t oY1t  = alloc(25165824);    // [3072][4096] bf16
  size_t oWcat = alloc(86016);
  size_t oF1 = alloc(768000);
  size_t oF2 = alloc(6144);
  size_t oM1 = alloc(6144);
  size_t oCf = alloc(1152);
  size_t oSt = alloc(256);
  if (ws_size < off) return;  // insufficient scratch -> visible validation failure

  unsigned short* Scat = (unsigned short*)(ws + oScat);
  unsigned short* Xt   = (unsigned short*)(ws + oXt);
  float*          g6   = (float*)(ws + oXt);
  unsigned short* Abf  = (unsigned short*)(ws + oA);
  float*          G    = (float*)(ws + oA);
  unsigned short* Y1t  = (unsigned short*)(ws + oY1t);
  unsigned short* Wcat = (unsigned short*)(ws + oWcat);

  hipMemsetAsync(Xt, 0, 25165824, stream);       // v-padding 4000..4095 must be 0
  hipMemsetAsync(ws + oSt, 0, 256, stream);      // stats accumulators
  hipMemsetAsync(ws + oM1, 0, 6144, stream);     // m1 accumulators
  k_transpose<<<dim3(125, 8), 256, 0, stream>>>(x, Xt, Scat);
  k_wcat<<<168, 256, 0, stream>>>(mlp_w, Wcat);
  for (int i = 0; i < 3; ++i) {
    k_castA<<<16384, 256, 0, stream>>>(A[i], Abf);
    // Y1t[col][node] = sum_v Xt[col][v]*Abf[node][v]; Scat j=2i+1
    k_gemm<0><<<768, 256, 0, stream>>>(Xt, Abf, Y1t, Scat, (2 * i + 1) * 32);
    // x2[node][col] = sum_v Abf[node][v]*Y1t[col][v]; Scat j=2i+2
    k_gemm<1><<<768, 256, 0, stream>>>(Abf, Y1t, nullptr, Scat, (2 * i + 2) * 32);
  }
  k_mlp<<<dim3(125, 10), 256, 0, stream>>>(Wcat, Scat, mlp_b, G);
  k_ct1<<<4000, 256, 0, stream>>>(G, ct1_w, ct1_b, g6);
  k_f1<<<250, 128, 0, stream>>>(g6, c1w, (float*)(ws + oF1));
  k_f2<<<256, 256, 0, stream>>>(g6, c2w, (float*)(ws + oF2));
  k_m1<<<dim3(48, 16), 256, 0, stream>>>((float*)(ws + oF1), tw, (float*)(ws + oM1));
  k_att<<<1, 64, 0, stream>>>((float*)(ws + oM1), (float*)(ws + oF2), tbias, tv, bn1g, bn1b,
                              (float*)(ws + oCf));
  k_final1<<<dim3(500, 8), 256, 0, stream>>>(x, conv1_w, conv1_b, g6, (float*)(ws + oCf), out);
  k_stats<<<dim3(4, 256), 256, 0, stream>>>(out, (float*)(ws + oSt));
  k_final2<<<6000, 256, 0, stream>>>(out, (float*)(ws + oSt), bn2g, bn2b);
}

// Round 8
// 909.467 us; speedup vs baseline: 1.4879x; 1.0043x over previous
//
#include <hip/hip_runtime.h>
#include <hip/hip_bf16.h>
#include <cstdint>
#include <cstddef>

// ---------------------------------------------------------------------------
// GCNPool fused pipeline, MI355X/gfx950.  B=8, C=32, N=4000 (pad 4096), T=12.
// Round 8: 8-phase 256x256 deep-pipelined GEMM (m201 template port): BK=64,
// 8 waves, 128KiB LDS (A/B x dbuf x half of 16KB), half-tile staging 1/phase,
// counted vmcnt(4) at phases 4/8 only, setprio around MFMA clusters, XOR
// k-slot swizzle (round-6/7, 0 conflicts).  Grid 192 (12x16), XCD-blocked.
// ---------------------------------------------------------------------------

typedef __attribute__((ext_vector_type(8))) short s16x8;
typedef __attribute__((ext_vector_type(4))) short s16x4;
typedef __attribute__((ext_vector_type(4))) float f32x4;

#define DEVFN __device__ __forceinline__

DEVFN void gload16(const void* g, void* l) {
  __builtin_amdgcn_global_load_lds((const __attribute__((address_space(1))) unsigned int*)g,
                                   (__attribute__((address_space(3))) unsigned int*)l, 16, 0, 0);
}

DEVFN unsigned short f2bf(float f) {  // round-to-nearest-even f32 -> bf16
  union { float f; unsigned int u; } v; v.f = f;
  unsigned int u = v.u;
  return (unsigned short)((u + 0x7fffu + ((u >> 16) & 1u)) >> 16);
}

// ---------------------------------------------------------------------------
// x (B,C,4000,12) f32 -> Xt[col=b*384+l*32+c][v 4096] bf16  (GEMM1 P operand)
//                     -> Scat[(b*4000+v)*12+l][224] slice j=0 (cols 0..31)
// ---------------------------------------------------------------------------
__global__ void k_transpose(const float* __restrict__ x,
                            unsigned short* __restrict__ Xt,
                            unsigned short* __restrict__ Scat) {
  __shared__ float ldsT[32 * 417];   // [c]*417 + vv*13 + l
  int v0 = blockIdx.x * 32;
  int b = blockIdx.y;
  int tid = threadIdx.x;
  for (int i = tid; i < 1024; i += 256) {
    int c = i >> 5, vv = i & 31;
    const float* src = x + ((size_t)(b * 32 + c) * 4000 + v0 + vv) * 12;
    f32x4 a0 = *(const f32x4*)(src);
    f32x4 a1 = *(const f32x4*)(src + 4);
    f32x4 a2 = *(const f32x4*)(src + 8);
    float* d = ldsT + c * 417 + vv * 13;
    d[0] = a0.x; d[1] = a0.y; d[2] = a0.z; d[3] = a0.w;
    d[4] = a1.x; d[5] = a1.y; d[6] = a1.z; d[7] = a1.w;
    d[8] = a2.x; d[9] = a2.y; d[10] = a2.z; d[11] = a2.w;
  }
  __syncthreads();
  for (int unit = tid; unit < 384; unit += 256) {
    int l = unit >> 5, c = unit & 31;
    alignas(16) unsigned short tmp[32];
#pragma unroll
    for (int vv = 0; vv < 32; ++vv) tmp[vv] = f2bf(ldsT[c * 417 + vv * 13 + l]);
    unsigned short* dst = Xt + (size_t)(b * 384 + l * 32 + c) * 4096 + v0;
#pragma unroll
    for (int j = 0; j < 4; ++j) *(s16x8*)(dst + j * 8) = *(const s16x8*)(tmp + j * 8);
  }
  for (int unit = tid; unit < 384; unit += 256) {
    int l = unit >> 5, vv = unit & 31;
    alignas(16) unsigned short tmp[32];
#pragma unroll
    for (int c = 0; c < 32; ++c) tmp[c] = f2bf(ldsT[c * 417 + vv * 13 + l]);
    unsigned short* dst = Scat + ((size_t)(b * 4000 + v0 + vv) * 12 + l) * 224;
#pragma unroll
    for (int j = 0; j < 4; ++j) *(s16x8*)(dst + j * 8) = *(const s16x8*)(tmp + j * 8);
  }
}

// A (4000,4000) f32 -> A_bf[4096][4096] bf16, zero-padded rows/cols.
__global__ void k_castA(const float* __restrict__ A, unsigned short* __restrict__ Abf) {
  int idx = blockIdx.x * 256 + threadIdx.x;
  int r = idx >> 10;
  int c4 = (idx & 1023) << 2;
  alignas(8) unsigned short o[4] = {0, 0, 0, 0};
  if (r < 4000 && c4 < 4000) {
    f32x4 v = *(const f32x4*)(A + (size_t)r * 4000 + c4);
    o[0] = f2bf(v.x); o[1] = f2bf(v.y); o[2] = f2bf(v.z); o[3] = f2bf(v.w);
  }
  *(s16x4*)(Abf + (size_t)r * 4096 + c4) = *(const s16x4*)o;
}

// mlp_w (64,224,1,3) f32 -> Wcat[oc][kt*224+ic] bf16 (t-independent)
__global__ void k_wcat(const float* __restrict__ mlp_w, unsigned short* __restrict__ Wcat) {
  int i = blockIdx.x * 256 + threadIdx.x;
  if (i >= 64 * 672) return;
  int oc = i / 672, k = i % 672;
  int kt = k / 224, ic = k % 224;
  Wcat[i] = f2bf(mlp_w[((size_t)oc * 224 + ic) * 3 + kt]);
}

// ---------------------------------------------------------------------------
// C[m][n] = sum_k P[m][k] * Q[n][k], bf16, K=4096.  256x256 tile, BK=64,
// 8 waves (2M x 4N, each 128x64), 8-phase schedule, counted vmcnt.
// LDS (shorts): A(d,h) at (d*2+h)*8192 ; B(d,h) at 32768 + (d*2+h)*8192.
// MODE 0 (GEMM1, 12 m x 16 n tiles): C1[m][4096] + Scat (m-decode).
// MODE 1 (GEMM2, 16 m x 12 n tiles): Scat only (n-decode).
// ---------------------------------------------------------------------------
#define MFMA_(a, b, c) __builtin_amdgcn_mfma_f32_16x16x32_bf16(a, b, c, 0, 0, 0)

// stage half-tile: OPER 0=A(from P) 1=B(from Q); dbuf d; half h; K-tile t
#define STG(OPER, d, h, t) do {                                                  \
    const unsigned short* _s = (OPER ? baseB : baseA) + (size_t)(h) * 524288 + (size_t)(t) * 64; \
    int _l = (OPER ? 32768 : 0) + ((d) * 2 + (h)) * 8192;                        \
    gload16(_s, smem + _l + tid * 8);                                            \
    gload16(_s + 262144, smem + _l + (512 + tid) * 8);                           \
  } while (0)

#define LDA_(d, mr, kk) (*(const s16x8*)(smem + ((d) * 2 + ha) * 8192 + aoff + (mr) * 1024 + ((kk) ? sxor : 0)))
#define LDB_(d, nr, kk) (*(const s16x8*)(smem + 32768 + ((d) * 2 + hb) * 8192 + boff + (nr) * 1024 + ((kk) ? sxor : 0)))

#define PHASE(d, mp, FIRST, STAGE_CODE, VM) do {                                 \
    s16x8 a00 = LDA_(d, 2 * (mp), 0),     a01 = LDA_(d, 2 * (mp), 1);            \
    s16x8 a10 = LDA_(d, 2 * (mp) + 1, 0), a11 = LDA_(d, 2 * (mp) + 1, 1);        \
    if (FIRST) {                                                                 \
      _Pragma("unroll")                                                          \
      for (int nr = 0; nr < 4; ++nr) { bfr[nr][0] = LDB_(d, nr, 0); bfr[nr][1] = LDB_(d, nr, 1); } \
    }                                                                            \
    STAGE_CODE;                                                                  \
    if (VM) asm volatile("s_waitcnt vmcnt(4)" ::: "memory");                     \
    __builtin_amdgcn_s_barrier();                                                \
    asm volatile("s_waitcnt lgkmcnt(0)" ::: "memory");                           \
    __builtin_amdgcn_s_setprio(1);                                               \
    _Pragma("unroll")                                                            \
    for (int nr = 0; nr < 4; ++nr) {                                             \
      acc[2 * (mp)][nr]     = MFMA_(a00, bfr[nr][0], acc[2 * (mp)][nr]);         \
      acc[2 * (mp)][nr]     = MFMA_(a01, bfr[nr][1], acc[2 * (mp)][nr]);         \
      acc[2 * (mp) + 1][nr] = MFMA_(a10, bfr[nr][0], acc[2 * (mp) + 1][nr]);     \
      acc[2 * (mp) + 1][nr] = MFMA_(a11, bfr[nr][1], acc[2 * (mp) + 1][nr]);     \
    }                                                                            \
    __builtin_amdgcn_s_setprio(0);                                               \
    __builtin_amdgcn_s_barrier();                                                \
  } while (0)

template <int MODE>
__global__ __launch_bounds__(512, 2)
void k_gemm(const unsigned short* __restrict__ P, const unsigned short* __restrict__ Q,
            unsigned short* __restrict__ C1, unsigned short* __restrict__ Scat, int jcol) {
  extern __shared__ unsigned short smem[];   // 65536 shorts = 128 KiB
  int tid = threadIdx.x;
  int w = tid >> 6, lane = tid & 63;
  int lr = lane & 15, g = lane >> 4;
  int bid = blockIdx.x;
  int xcd = bid & 7, lid = bid >> 3;         // 192 blocks, per-XCD 3x8 tile block
  int mt, nt;
  if (MODE == 0) { mt = (xcd & 3) * 3 + (lid >> 3); nt = (xcd >> 2) * 8 + (lid & 7); }
  else           { nt = (xcd & 3) * 3 + (lid >> 3); mt = (xcd >> 2) * 8 + (lid & 7); }
  int m0 = mt * 256, n0 = nt * 256;
  int ha = w >> 2;                 // A half (rows wm = ha*128)
  int hb = (w & 3) >> 1;           // B half
  int wn = (w & 3) * 64;
  int slot0 = (g ^ (lr & 7)) * 8;
  int aoff = lr * 64 + slot0;
  int boff = ((w & 1) * 64 + lr) * 64 + slot0;
  int sxor = (slot0 & 32) ? -32 : 32;
  int gk = ((tid & 7) ^ ((tid >> 3) & 7)) * 8;   // pre-swizzled global k offset
  const unsigned short* baseA = P + (size_t)(m0 + (tid >> 3)) * 4096 + gk;
  const unsigned short* baseB = Q + (size_t)(n0 + (tid >> 3)) * 4096 + gk;
  f32x4 acc[8][4] = {};
  s16x8 bfr[4][2];

  // prologue: B(0) -> d0, A(0) -> d0, B(1) -> d1 ; drain all but B(1)
  STG(1, 0, 0, 0); STG(1, 0, 1, 0);
  STG(0, 0, 0, 0); STG(0, 0, 1, 0);
  STG(1, 1, 0, 1); STG(1, 1, 1, 1);
  asm volatile("s_waitcnt vmcnt(4)" ::: "memory");
  __builtin_amdgcn_s_barrier();

#pragma unroll 1
  for (int i = 0; i < 32; ++i) {
    int t1 = 2 * i + 1, t2 = 2 * i + 2, t3 = 2 * i + 3;
    PHASE(0, 0, 1, STG(0, 1, 0, t1), 0);   // ph1: A(d1,h0,t1)
    PHASE(0, 1, 0, STG(0, 1, 1, t1), 0);   // ph2: A(d1,h1,t1)
    PHASE(0, 2, 0, STG(1, 0, 0, t2), 0);   // ph3: B(d0,h0,t2)
    PHASE(0, 3, 0, STG(1, 0, 1, t2), 1);   // ph4: B(d0,h1,t2) + vmcnt(4)
    PHASE(1, 0, 1, STG(0, 0, 0, t2), 0);   // ph5: A(d0,h0,t2)
    PHASE(1, 1, 0, STG(0, 0, 1, t2), 0);   // ph6: A(d0,h1,t2)
    PHASE(1, 2, 0, STG(1, 1, 0, t3), 0);   // ph7: B(d1,h0,t3)
    PHASE(1, 3, 0, STG(1, 1, 1, t3), 1);   // ph8: B(d1,h1,t3) + vmcnt(4)
  }

  // epilogue: drain everything, repack via LDS [128][264], two m-halves
  asm volatile("s_waitcnt vmcnt(0) lgkmcnt(0)" ::: "memory");
  __syncthreads();
  unsigned short* eld = smem;
  int rb = g * 4;
#pragma unroll
  for (int h = 0; h < 2; ++h) {
    if (h) __syncthreads();
    if ((w >> 2) == h) {
#pragma unroll
      for (int mr = 0; mr < 8; ++mr)
#pragma unroll
        for (int nr = 0; nr < 4; ++nr)
#pragma unroll
          for (int r = 0; r < 4; ++r)
            eld[(mr * 16 + rb + r) * 264 + wn + nr * 16 + lr] = f2bf(acc[mr][nr][r]);
    }
    __syncthreads();
    if (MODE == 0) {
      int rowh = tid >> 2, q = tid & 3;
      unsigned short* dst = C1 + (size_t)(m0 + h * 128 + rowh) * 4096 + n0 + q * 64;
      const unsigned short* sp = eld + rowh * 264 + q * 64;
#pragma unroll
      for (int j = 0; j < 8; ++j) *(s16x8*)(dst + j * 8) = *(const s16x8*)(sp + j * 8);
#pragma unroll
      for (int uu = 0; uu < 2; ++uu) {
        int u = uu * 512 + tid;
        int lg = u >> 8, nl = u & 255;
        int node = n0 + nl;
        if (node < 4000) {
          int gcol = m0 + h * 128 + lg * 32;
          int bb2 = gcol / 384, ll = (gcol % 384) >> 5;
          alignas(16) unsigned short tmp[32];
#pragma unroll
          for (int c = 0; c < 32; ++c) tmp[c] = eld[(lg * 32 + c) * 264 + nl];
          unsigned short* d2 = Scat + ((size_t)(bb2 * 4000 + node) * 12 + ll) * 224 + jcol;
#pragma unroll
          for (int j = 0; j < 4; ++j) *(s16x8*)(d2 + j * 8) = *(const s16x8*)(tmp + j * 8);
        }
      }
    } else {
#pragma unroll
      for (int uu = 0; uu < 2; ++uu) {
        int u = uu * 512 + tid;
        int lg = u >> 7, nrow = u & 127;
        int node = m0 + h * 128 + nrow;
        if (node < 4000) {
          int gcol = n0 + lg * 32;
          int bb2 = gcol / 384, ll = (gcol % 384) >> 5;
          alignas(16) unsigned short tmp[32];
          const unsigned short* sp = eld + nrow * 264 + lg * 32;
#pragma unroll
          for (int j = 0; j < 4; ++j) *(s16x8*)(tmp + j * 8) = *(const s16x8*)(sp + j * 8);
          unsigned short* d2 = Scat + ((size_t)(bb2 * 4000 + node) * 12 + ll) * 224 + jcol;
#pragma unroll
          for (int j = 0; j < 4; ++j) *(s16x8*)(d2 + j * 8) = *(const s16x8*)(tmp + j * 8);
        }
      }
    }
  }
}

// ---------------------------------------------------------------------------
// mlp GEMM: OUT[oc=64][bn] = sum_{k<672} Wcat[oc][k] * Scat[bn*12+t][k..], then
// gate tanh*sigmoid -> G[b][t][c][4096] f32.  Tile 64x256, 4 waves of 64x64.
// ---------------------------------------------------------------------------
__global__ __launch_bounds__(256, 2)
void k_mlp(const unsigned short* __restrict__ Wcat, const unsigned short* __restrict__ Scat,
           const float* __restrict__ mlp_b, float* __restrict__ G) {
  __shared__ unsigned short lds[2048 + 8192];  // Ws[64][32] + Bs[256][32]
  unsigned short* Ws = lds;
  unsigned short* Bs = lds + 2048;
  int tid = threadIdx.x;
  int bn0 = blockIdx.x * 256;
  int t = blockIdx.y;      // 0..9
  int w = tid >> 6, lane = tid & 63;
  int lr = lane & 15, lk = (lane >> 4) * 8;
  f32x4 acc[4][4] = {};
  const unsigned short* gw = Wcat + (size_t)(tid >> 2) * 672 + (tid & 3) * 8;
  const unsigned short* gq = Scat + ((size_t)(bn0 + (tid >> 2)) * 12 + t) * 224 + (tid & 3) * 8;
  unsigned short* lw = Ws + tid * 8;
  unsigned short* lq = Bs + tid * 8;
  for (int s = 0; s < 21; ++s) {
    gload16(gw + s * 32, lw);
#pragma unroll
    for (int r = 0; r < 4; ++r)
      gload16(gq + (size_t)r * 64 * 2688 + s * 32, lq + r * 2048);
    __syncthreads();
    s16x8 a[4], bb[4];
#pragma unroll
    for (int f = 0; f < 4; ++f) {
      a[f] = *(const s16x8*)(Ws + (f * 16 + lr) * 32 + lk);
      bb[f] = *(const s16x8*)(Bs + (w * 64 + f * 16 + lr) * 32 + lk);
    }
#pragma unroll
    for (int fm = 0; fm < 4; ++fm)
#pragma unroll
      for (int fn = 0; fn < 4; ++fn)
        acc[fm][fn] = __builtin_amdgcn_mfma_f32_16x16x32_bf16(a[fm], bb[fn], acc[fm][fn], 0, 0, 0);
    __syncthreads();
  }
  int rbase = (lane >> 4) * 4;
#pragma unroll
  for (int fn = 0; fn < 4; ++fn) {
    int bn = bn0 + w * 64 + fn * 16 + lr;
    int b = bn / 4000;
    int n = bn - b * 4000;
    float* gbase = G + (size_t)(b * 10 + t) * 32 * 4096 + n;
#pragma unroll
    for (int fm = 0; fm < 2; ++fm)
#pragma unroll
      for (int r = 0; r < 4; ++r) {
        int c = fm * 16 + rbase + r;
        float v1 = acc[fm][fn][r] + mlp_b[c];
        float v2 = acc[fm + 2][fn][r] + mlp_b[c + 32];
        gbase[(size_t)c * 4096] = tanhf(v1) * (1.0f / (1.0f + __expf(-v2)));
      }
  }
}

// ct1: g6[b][c][n][q] = ct1_b[q] + sum_{l<10} ct1_w[q][l] * G[b][l][c][n]
__global__ void k_ct1(const float* __restrict__ G, const float* __restrict__ ct1_w,
                      const float* __restrict__ ct1_b, float* __restrict__ g6) {
  int idx = blockIdx.x * 256 + threadIdx.x;
  if (idx >= 8 * 32 * 4000) return;
  int n = idx % 4000;
  int c = (idx / 4000) % 32;
  int b = idx / (4000 * 32);
  const float* gp = G + ((size_t)(b * 10) * 32 + c) * 4096 + n;
  float v[10];
#pragma unroll
  for (int l = 0; l < 10; ++l) v[l] = gp[(size_t)l * 32 * 4096];
  float* o = g6 + (size_t)idx * 6;
#pragma unroll
  for (int q = 0; q < 6; ++q) {
    float a = ct1_b[q];
#pragma unroll
    for (int l = 0; l < 10; ++l) a += ct1_w[q * 10 + l] * v[l];
    o[q] = a;
  }
}

// f1[b][t][n] = sum_c c1[c] * g6[b][c][n][t]
__global__ void k_f1(const float* __restrict__ g6, const float* __restrict__ c1,
                     float* __restrict__ f1) {
  int idx = blockIdx.x * 128 + threadIdx.x;
  if (idx >= 8 * 4000) return;
  int n = idx % 4000, b = idx / 4000;
  float acc[6] = {};
  const float* gp = g6 + ((size_t)b * 32 * 4000 + n) * 6;
  for (int c = 0; c < 32; ++c) {
    float wv = c1[c];
    const float* p = gp + (size_t)c * 4000 * 6;
#pragma unroll
    for (int t = 0; t < 6; ++t) acc[t] += wv * p[t];
  }
  for (int t = 0; t < 6; ++t) f1[((size_t)b * 6 + t) * 4000 + n] = acc[t];
}

// f2[b][c][t] = sum_n c2[n] * g6[b][c][n][t]
__global__ void k_f2(const float* __restrict__ g6, const float* __restrict__ c2,
                     float* __restrict__ f2) {
  __shared__ float red[256 * 6];
  int bc = blockIdx.x;
  int tid = threadIdx.x;
  float acc[6] = {};
  const float* gp = g6 + (size_t)bc * 4000 * 6;
  for (int n = tid; n < 4000; n += 256) {
    float wv = c2[n];
#pragma unroll
    for (int t = 0; t < 6; ++t) acc[t] += wv * gp[(size_t)n * 6 + t];
  }
  for (int t = 0; t < 6; ++t) red[tid * 6 + t] = acc[t];
  __syncthreads();
  for (int s = 128; s > 0; s >>= 1) {
    if (tid < s)
      for (int t = 0; t < 6; ++t) red[tid * 6 + t] += red[(tid + s) * 6 + t];
    __syncthreads();
  }
  if (tid < 6) f2[bc * 6 + tid] = red[tid];
}

// m1[b][t][c] += sum over n-chunk of f1[b][t][n] * tat_w[n][c]; grid (48,16)
__global__ void k_m1(const float* __restrict__ f1, const float* __restrict__ tw,
                     float* __restrict__ m1) {
  __shared__ float red[8][32];
  int bt = blockIdx.x;
  int nc = blockIdx.y;
  int tid = threadIdx.x;
  int c = tid & 31, gi = tid >> 5;
  float acc = 0.f;
  const float* fp = f1 + (size_t)bt * 4000 + nc * 250;
  const float* twp = tw + ((size_t)nc * 250) * 32 + c;
  for (int n = gi; n < 250; n += 8) acc += fp[n] * twp[n * 32];
  red[gi][c] = acc;
  __syncthreads();
  if (tid < 32) {
    float s = 0.f;
#pragma unroll
    for (int gg = 0; gg < 8; ++gg) s += red[gg][c];
    atomicAdd(&m1[(size_t)bt * 32 + c], s);
  }
}

// logits -> sigmoid -> tat_v mix -> BN1 -> softmax -> coefs[b][t][q]
__global__ void k_att(const float* __restrict__ m1, const float* __restrict__ f2,
                      const float* __restrict__ bias, const float* __restrict__ tv,
                      const float* __restrict__ g1, const float* __restrict__ b1,
                      float* __restrict__ coefs) {
  __shared__ float sig[48 * 6], lgs[48 * 6], mu[6], iv[6];
  int tid = threadIdx.x;
  int b = tid / 6, t = tid % 6;
  if (tid < 48) {
    for (int s = 0; s < 6; ++s) {
      float a = bias[t * 6 + s];
      for (int c = 0; c < 32; ++c)
        a += m1[((size_t)b * 6 + t) * 32 + c] * f2[((size_t)b * 32 + c) * 6 + s];
      sig[tid * 6 + s] = 1.0f / (1.0f + __expf(-a));
    }
  }
  __syncthreads();
  if (tid < 48) {
    for (int q = 0; q < 6; ++q) {
      float a = 0.f;
      for (int s = 0; s < 6; ++s) a += tv[t * 6 + s] * sig[(b * 6 + s) * 6 + q];
      lgs[tid * 6 + q] = a;
    }
  }
  __syncthreads();
  if (tid < 6) {
    float s = 0, s2 = 0;
    for (int r = 0; r < 48; ++r) { float v = lgs[r * 6 + tid]; s += v; s2 += v * v; }
    float m = s / 48.f;
    mu[tid] = m;
    iv[tid] = rsqrtf(s2 / 48.f - m * m + 1e-5f);
  }
  __syncthreads();
  if (tid < 48) {
    float v[6], mx = -1e30f;
    for (int q = 0; q < 6; ++q) {
      v[q] = (lgs[tid * 6 + q] - mu[q]) * iv[q] * g1[q] + b1[q];
      mx = fmaxf(mx, v[q]);
    }
    float s = 0;
    for (int q = 0; q < 6; ++q) { v[q] = __expf(v[q] - mx); s += v[q]; }
    float inv = 1.0f / s;
    for (int q = 0; q < 6; ++q) coefs[tid * 6 + q] = v[q] * inv;
  }
}

// y = attention-mix(g6) + conv1(x)[...,6:] -> out (pre-BN2)
__global__ void k_final1(const float* __restrict__ x, const float* __restrict__ cw,
                         const float* __restrict__ cb, const float* __restrict__ g6,
                         const float* __restrict__ coefs, float* __restrict__ out) {
  __shared__ float xt[32 * 8 * 6];
  __shared__ float cwT[1024];
  __shared__ float cfs[36], cbs[32];
  int n0 = blockIdx.x * 8;
  int b = blockIdx.y;
  int tid = threadIdx.x;
  {
    int ci = tid >> 3, seg = tid & 7;
    const float* xp = x + ((size_t)(b * 32 + ci) * 4000 + n0 + seg) * 12 + 6;
#pragma unroll
    for (int q = 0; q < 6; ++q) xt[(ci * 8 + seg) * 6 + q] = xp[q];
  }
  for (int i = tid; i < 1024; i += 256) { int o = i >> 5, ci = i & 31; cwT[ci * 32 + o] = cw[i]; }
  if (tid < 36) cfs[tid] = coefs[b * 36 + tid];
  if (tid < 32) cbs[tid] = cb[tid];
  __syncthreads();
  int nn = tid & 7, c = tid >> 3;
  const float* gp = g6 + ((size_t)(b * 32 + c) * 4000 + n0 + nn) * 6;
  float gv[6];
#pragma unroll
  for (int l = 0; l < 6; ++l) gv[l] = gp[l];
  float y[6];
#pragma unroll
  for (int q = 0; q < 6; ++q) {
    float at = 0.f;
#pragma unroll
    for (int l = 0; l < 6; ++l) at += gv[l] * cfs[q * 6 + l];
    y[q] = at + cbs[c];
  }
  for (int ci = 0; ci < 32; ++ci) {
    float wv = cwT[ci * 32 + c];
#pragma unroll
    for (int q = 0; q < 6; ++q) y[q] += wv * xt[(ci * 8 + nn) * 6 + q];
  }
  float* op = out + ((size_t)(b * 32 + c) * 4000 + n0 + nn) * 6;
#pragma unroll
  for (int q = 0; q < 6; ++q) op[q] = y[q];
}

// per-channel sum/sumsq of out: grid (4, 256), f32x4 + shfl reduce + atomicAdd
__global__ void k_stats(const float* __restrict__ out, float* __restrict__ stats) {
  __shared__ float r1[4], r2[4];
  int bc = blockIdx.y;
  int c = bc & 31;
  int tid = threadIdx.x;
  const float* p = out + (size_t)bc * 24000 + blockIdx.x * 6000;
  float s = 0.f, s2 = 0.f;
  for (int i = tid * 4; i < 6000; i += 1024) {
    f32x4 v = *(const f32x4*)(p + i);
    s  += v.x + v.y + v.z + v.w;
    s2 += v.x * v.x + v.y * v.y + v.z * v.z + v.w * v.w;
  }
#pragma unroll
  for (int off = 32; off > 0; off >>= 1) {
    s  += __shfl_down(s, off);
    s2 += __shfl_down(s2, off);
  }
  int lane = tid & 63, w = tid >> 6;
  if (lane == 0) { r1[w] = s; r2[w] = s2; }
  __syncthreads();
  if (tid == 0) {
    atomicAdd(&stats[c],      r1[0] + r1[1] + r1[2] + r1[3]);
    atomicAdd(&stats[32 + c], r2[0] + r2[1] + r2[2] + r2[3]);
  }
}

__global__ void k_final2(float* __restrict__ out, const float* __restrict__ stats,
                         const float* __restrict__ g2, const float* __restrict__ b2) {
  int idx = (blockIdx.x * 256 + threadIdx.x) * 4;
  if (idx >= 6144000) return;
  int c = (idx / 24000) % 32;
  float mean = stats[c] * (1.0f / 192000.f);
  float var = stats[32 + c] * (1.0f / 192000.f) - mean * mean;
  float sc = rsqrtf(var + 1e-5f) * g2[c];
  float sh = b2[c] - mean * sc;
  f32x4 v = *(f32x4*)(out + idx);
  v.x = v.x * sc + sh; v.y = v.y * sc + sh; v.z = v.z * sc + sh; v.w = v.w * sc + sh;
  *(f32x4*)(out + idx) = v;
}

// ---------------------------------------------------------------------------
extern "C" void kernel_launch(void* const* d_in, const int* in_sizes, int n_in,
                              void* d_out, int out_size, void* d_ws, size_t ws_size,
                              hipStream_t stream) {
  (void)in_sizes; (void)n_in; (void)out_size;
  const float* x       = (const float*)d_in[0];
  const float* A[3]    = {(const float*)d_in[1], (const float*)d_in[2], (const float*)d_in[3]};
  const float* conv1_w = (const float*)d_in[4];
  const float* conv1_b = (const float*)d_in[5];
  const float* mlp_w   = (const float*)d_in[6];
  const float* mlp_b   = (const float*)d_in[7];
  const float* ct1_w   = (const float*)d_in[8];
  const float* ct1_b   = (const float*)d_in[9];
  const float* c1w     = (const float*)d_in[10];
  const float* c2w     = (const float*)d_in[11];
  const float* tw      = (const float*)d_in[12];
  const float* tbias   = (const float*)d_in[13];
  const float* tv      = (const float*)d_in[14];
  const float* bn1g    = (const float*)d_in[15];
  const float* bn1b    = (const float*)d_in[16];
  const float* bn2g    = (const float*)d_in[17];
  const float* bn2b    = (const float*)d_in[18];
  float* out = (float*)d_out;

  char* ws = (char*)d_ws;
  size_t off = 0;
  auto alloc = [&](size_t bytes) { size_t r = off; off += (bytes + 255) & ~(size_t)255; return r; };
  size_t oScat = alloc(172032000);   // [32000*12][224] bf16
  size_t oXt   = alloc(25165824);    // [3072][4096] bf16 ; later g6 (24.576MB f32)
  size_t oA    = alloc(33554432);    // Abf [4096][4096] bf16 ; with oY1t, later G
  size_t oY1t  = alloc(25165824);    // [3072][4096] bf16
  size_t oWcat = alloc(86016);
  size_t oF1 = alloc(768000);
  size_t oF2 = alloc(6144);
  size_t oM1 = alloc(6144);
  size_t oCf = alloc(1152);
  size_t oSt = alloc(256);
  if (ws_size < off) return;  // insufficient scratch -> visible validation failure

  unsigned short* Scat = (unsigned short*)(ws + oScat);
  unsigned short* Xt   = (unsigned short*)(ws + oXt);
  float*          g6   = (float*)(ws + oXt);
  unsigned short* Abf  = (unsigned short*)(ws + oA);
  float*          G    = (float*)(ws + oA);
  unsigned short* Y1t  = (unsigned short*)(ws + oY1t);
  unsigned short* Wcat = (unsigned short*)(ws + oWcat);

  hipFuncSetAttribute((const void*)k_gemm<0>, hipFuncAttributeMaxDynamicSharedMemorySize, 131072);
  hipFuncSetAttribute((const void*)k_gemm<1>, hipFuncAttributeMaxDynamicSharedMemorySize, 131072);

  hipMemsetAsync(Xt, 0, 25165824, stream);       // v-padding 4000..4095 must be 0
  hipMemsetAsync(ws + oSt, 0, 256, stream);      // stats accumulators
  hipMemsetAsync(ws + oM1, 0, 6144, stream);     // m1 accumulators
  k_transpose<<<dim3(125, 8), 256, 0, stream>>>(x, Xt, Scat);
  k_wcat<<<168, 256, 0, stream>>>(mlp_w, Wcat);
  for (int i = 0; i < 3; ++i) {
    k_castA<<<16384, 256, 0, stream>>>(A[i], Abf);
    // Y1t[col][node] = sum_v Xt[col][v]*Abf[node][v]; Scat j=2i+1
    k_gemm<0><<<192, 512, 131072, stream>>>(Xt, Abf, Y1t, Scat, (2 * i + 1) * 32);
    // x2[node][col] = sum_v Abf[node][v]*Y1t[col][v]; Scat j=2i+2
    k_gemm<1><<<192, 512, 131072, stream>>>(Abf, Y1t, nullptr, Scat, (2 * i + 2) * 32);
  }
  k_mlp<<<dim3(125, 10), 256, 0, stream>>>(Wcat, Scat, mlp_b, G);
  k_ct1<<<4000, 256, 0, stream>>>(G, ct1_w, ct1_b, g6);
  k_f1<<<250, 128, 0, stream>>>(g6, c1w, (float*)(ws + oF1));
  k_f2<<<256, 256, 0, stream>>>(g6, c2w, (float*)(ws + oF2));
  k_m1<<<dim3(48, 16), 256, 0, stream>>>((float*)(ws + oF1), tw, (float*)(ws + oM1));
  k_att<<<1, 64, 0, stream>>>((float*)(ws + oM1), (float*)(ws + oF2), tbias, tv, bn1g, bn1b,
                              (float*)(ws + oCf));
  k_final1<<<dim3(500, 8), 256, 0, stream>>>(x, conv1_w, conv1_b, g6, (float*)(ws + oCf), out);
  k_stats<<<dim3(4, 256), 256, 0, stream>>>(out, (float*)(ws + oSt));
  k_final2<<<6000, 256, 0, stream>>>(out, (float*)(ws + oSt), bn2g, bn2b);
}

// Round 9
// 819.894 us; speedup vs baseline: 1.6505x; 1.1092x over previous
//
#include <hip/hip_runtime.h>
#include <hip/hip_bf16.h>
#include <cstdint>
#include <cstddef>

// ---------------------------------------------------------------------------
// GCNPool fused pipeline, MI355X/gfx950.  B=8, C=32, N=4000 (pad 4096), T=12.
// Round 9: 192x256-tile 6-phase deep-pipelined GEMM -> grid 256 = 1 block/CU
// (round-8's 256^2 tile gave only 192 blocks = 75% CU coverage; per-active-CU
// it beat round-7, so reshape the tile to fill the chip).  Both GEMMs now
// share one geometry: P in {Xt, Y1t} (3072 col-rows), Q = Abf (4096 nodes).
// 16 MFMA/phase, A staged full-tile (3 loads), B half-tile (2), vmcnt(4).
// ---------------------------------------------------------------------------

typedef __attribute__((ext_vector_type(8))) short s16x8;
typedef __attribute__((ext_vector_type(4))) short s16x4;
typedef __attribute__((ext_vector_type(4))) float f32x4;

#define DEVFN __device__ __forceinline__

DEVFN void gload16(const void* g, void* l) {
  __builtin_amdgcn_global_load_lds((const __attribute__((address_space(1))) unsigned int*)g,
                                   (__attribute__((address_space(3))) unsigned int*)l, 16, 0, 0);
}

DEVFN unsigned short f2bf(float f) {  // round-to-nearest-even f32 -> bf16
  union { float f; unsigned int u; } v; v.f = f;
  unsigned int u = v.u;
  return (unsigned short)((u + 0x7fffu + ((u >> 16) & 1u)) >> 16);
}

// ---------------------------------------------------------------------------
// x (B,C,4000,12) f32 -> Xt[col=b*384+l*32+c][v 4096] bf16  (GEMM1 P operand)
//                     -> Scat[(b*4000+v)*12+l][224] slice j=0 (cols 0..31)
// ---------------------------------------------------------------------------
__global__ void k_transpose(const float* __restrict__ x,
                            unsigned short* __restrict__ Xt,
                            unsigned short* __restrict__ Scat) {
  __shared__ float ldsT[32 * 417];   // [c]*417 + vv*13 + l
  int v0 = blockIdx.x * 32;
  int b = blockIdx.y;
  int tid = threadIdx.x;
  for (int i = tid; i < 1024; i += 256) {
    int c = i >> 5, vv = i & 31;
    const float* src = x + ((size_t)(b * 32 + c) * 4000 + v0 + vv) * 12;
    f32x4 a0 = *(const f32x4*)(src);
    f32x4 a1 = *(const f32x4*)(src + 4);
    f32x4 a2 = *(const f32x4*)(src + 8);
    float* d = ldsT + c * 417 + vv * 13;
    d[0] = a0.x; d[1] = a0.y; d[2] = a0.z; d[3] = a0.w;
    d[4] = a1.x; d[5] = a1.y; d[6] = a1.z; d[7] = a1.w;
    d[8] = a2.x; d[9] = a2.y; d[10] = a2.z; d[11] = a2.w;
  }
  __syncthreads();
  for (int unit = tid; unit < 384; unit += 256) {
    int l = unit >> 5, c = unit & 31;
    alignas(16) unsigned short tmp[32];
#pragma unroll
    for (int vv = 0; vv < 32; ++vv) tmp[vv] = f2bf(ldsT[c * 417 + vv * 13 + l]);
    unsigned short* dst = Xt + (size_t)(b * 384 + l * 32 + c) * 4096 + v0;
#pragma unroll
    for (int j = 0; j < 4; ++j) *(s16x8*)(dst + j * 8) = *(const s16x8*)(tmp + j * 8);
  }
  for (int unit = tid; unit < 384; unit += 256) {
    int l = unit >> 5, vv = unit & 31;
    alignas(16) unsigned short tmp[32];
#pragma unroll
    for (int c = 0; c < 32; ++c) tmp[c] = f2bf(ldsT[c * 417 + vv * 13 + l]);
    unsigned short* dst = Scat + ((size_t)(b * 4000 + v0 + vv) * 12 + l) * 224;
#pragma unroll
    for (int j = 0; j < 4; ++j) *(s16x8*)(dst + j * 8) = *(const s16x8*)(tmp + j * 8);
  }
}

// A (4000,4000) f32 -> A_bf[4096][4096] bf16, zero-padded rows/cols.
__global__ void k_castA(const float* __restrict__ A, unsigned short* __restrict__ Abf) {
  int idx = blockIdx.x * 256 + threadIdx.x;
  int r = idx >> 10;
  int c4 = (idx & 1023) << 2;
  alignas(8) unsigned short o[4] = {0, 0, 0, 0};
  if (r < 4000 && c4 < 4000) {
    f32x4 v = *(const f32x4*)(A + (size_t)r * 4000 + c4);
    o[0] = f2bf(v.x); o[1] = f2bf(v.y); o[2] = f2bf(v.z); o[3] = f2bf(v.w);
  }
  *(s16x4*)(Abf + (size_t)r * 4096 + c4) = *(const s16x4*)o;
}

// mlp_w (64,224,1,3) f32 -> Wcat[oc][kt*224+ic] bf16 (t-independent)
__global__ void k_wcat(const float* __restrict__ mlp_w, unsigned short* __restrict__ Wcat) {
  int i = blockIdx.x * 256 + threadIdx.x;
  if (i >= 64 * 672) return;
  int oc = i / 672, k = i % 672;
  int kt = k / 224, ic = k % 224;
  Wcat[i] = f2bf(mlp_w[((size_t)oc * 224 + ic) * 3 + kt]);
}

// ---------------------------------------------------------------------------
// C[m][n] = sum_k P[m][k] * Q[n][k], bf16, K=4096.  192x256 tile, BK=64,
// 8 waves (2M x 4N, wave-tile 96x64), 6-phase schedule per 2 K-tiles,
// counted vmcnt(4), XOR k-slot swizzle (0 conflicts).  Grid 256 = 1/CU.
// LDS (shorts): A(d) full tile at d*12288 (192x64); B(d,h) at
// 24576 + (d*2+h)*8192 (128x64 each).  Total 57344 shorts = 112 KiB.
// Epilogue: single-pass repack [192][264] -> C1 (if WRITE_C1) + Scat slice.
// ---------------------------------------------------------------------------
#define MFMA_(a, b, c) __builtin_amdgcn_mfma_f32_16x16x32_bf16(a, b, c, 0, 0, 0)

#define STGA(d, t) do {                                                          \
    const unsigned short* _s = aSrc + (size_t)(t) * 64;                          \
    unsigned short* _l = smem + (d) * 12288;                                     \
    gload16(_s,          _l + tid * 8);                                          \
    gload16(_s + 262144, _l + (512 + tid) * 8);                                  \
    gload16(_s + 524288, _l + (1024 + tid) * 8);                                 \
  } while (0)

#define STGB(d, h, t) do {                                                       \
    const unsigned short* _s = bSrc + (size_t)(h) * 524288 + (size_t)(t) * 64;   \
    unsigned short* _l = smem + 24576 + ((d) * 2 + (h)) * 8192;                  \
    gload16(_s,          _l + tid * 8);                                          \
    gload16(_s + 262144, _l + (512 + tid) * 8);                                  \
  } while (0)

#define LDA_(d, f, kk) (*(const s16x8*)(smem + (d) * 12288 + aoff + (f) * 1024 + ((kk) ? sxor : 0)))
#define LDB_(d, nf, kk) (*(const s16x8*)(smem + 24576 + ((d) * 2 + hb) * 8192 + boff + (nf) * 1024 + ((kk) ? sxor : 0)))

#define PHASE(d, mp, FIRST, STAGE_CODE, VM) do {                                 \
    s16x8 a00 = LDA_(d, 2 * (mp), 0),     a01 = LDA_(d, 2 * (mp), 1);            \
    s16x8 a10 = LDA_(d, 2 * (mp) + 1, 0), a11 = LDA_(d, 2 * (mp) + 1, 1);        \
    if (FIRST) {                                                                 \
      _Pragma("unroll")                                                          \
      for (int nf = 0; nf < 4; ++nf) { bfr[nf][0] = LDB_(d, nf, 0); bfr[nf][1] = LDB_(d, nf, 1); } \
    }                                                                            \
    STAGE_CODE;                                                                  \
    if (VM) asm volatile("s_waitcnt vmcnt(4)" ::: "memory");                     \
    __builtin_amdgcn_s_barrier();                                                \
    asm volatile("s_waitcnt lgkmcnt(0)" ::: "memory");                           \
    __builtin_amdgcn_s_setprio(1);                                               \
    _Pragma("unroll")                                                            \
    for (int nf = 0; nf < 4; ++nf) {                                             \
      acc[2 * (mp)][nf]     = MFMA_(a00, bfr[nf][0], acc[2 * (mp)][nf]);         \
      acc[2 * (mp)][nf]     = MFMA_(a01, bfr[nf][1], acc[2 * (mp)][nf]);         \
      acc[2 * (mp) + 1][nf] = MFMA_(a10, bfr[nf][0], acc[2 * (mp) + 1][nf]);     \
      acc[2 * (mp) + 1][nf] = MFMA_(a11, bfr[nf][1], acc[2 * (mp) + 1][nf]);     \
    }                                                                            \
    __builtin_amdgcn_s_setprio(0);                                               \
    __builtin_amdgcn_s_barrier();                                                \
  } while (0)

template <int WRITE_C1>
__global__ __launch_bounds__(512, 2)
void k_gemm(const unsigned short* __restrict__ P, const unsigned short* __restrict__ Q,
            unsigned short* __restrict__ C1, unsigned short* __restrict__ Scat, int jcol) {
  extern __shared__ unsigned short smem[];   // 57344 shorts = 112 KiB
  int tid = threadIdx.x;
  int w = tid >> 6, lane = tid & 63;
  int lr = lane & 15, g = lane >> 4;
  int mq = w >> 1, nq = w & 1;               // wait: need 2M x 4N -> mq 0..1? see below
  // 2M x 4N wave grid: mq = w>>2 (0..1) covers 96 rows, nq = w&3 (0..3) covers 64 cols
  mq = w >> 2; nq = w & 3;
  int bid = blockIdx.x;
  int xcd = bid & 7, lid = bid >> 3;         // 256 blocks; per XCD: 2 n-tiles x 16 m-tiles
  int nt = xcd * 2 + (lid >> 4);
  int mt = lid & 15;
  int m0 = mt * 192, n0 = nt * 256;
  int hb = nq >> 1;
  int slot0 = (g ^ (lr & 7)) * 8;
  int sxor = (slot0 & 32) ? -32 : 32;
  int aoff = (mq * 96 + lr) * 64 + slot0;
  int boff = ((nq & 1) * 64 + lr) * 64 + slot0;
  int gk = ((tid & 7) ^ ((tid >> 3) & 7)) * 8;   // pre-swizzled global k offset
  const unsigned short* aSrc = P + (size_t)(m0 + (tid >> 3)) * 4096 + gk;
  const unsigned short* bSrc = Q + (size_t)(n0 + (tid >> 3)) * 4096 + gk;
  f32x4 acc[6][4] = {};
  s16x8 bfr[4][2];

  // prologue: B(d0,t0) both halves, A(d0,t0), B(d1,t1) both halves
  STGB(0, 0, 0); STGB(0, 1, 0);
  STGA(0, 0);
  STGB(1, 0, 1); STGB(1, 1, 1);
  asm volatile("s_waitcnt vmcnt(4)" ::: "memory");
  __builtin_amdgcn_s_barrier();

#pragma unroll 1
  for (int i = 0; i < 32; ++i) {
    int t1 = 2 * i + 1, t2 = 2 * i + 2, t3 = 2 * i + 3;
    PHASE(0, 0, 1, STGA(1, t1), 0);        // ph1: A(d1,t1) full
    PHASE(0, 1, 0, STGB(0, 0, t2), 0);     // ph2: B(d0,h0,t2)
    PHASE(0, 2, 0, STGB(0, 1, t2), 1);     // ph3: B(d0,h1,t2) + vmcnt(4)
    PHASE(1, 0, 1, STGA(0, t2), 0);        // ph4: A(d0,t2) full
    PHASE(1, 1, 0, STGB(1, 0, t3), 0);     // ph5: B(d1,h0,t3)
    PHASE(1, 2, 0, STGB(1, 1, t3), 1);     // ph6: B(d1,h1,t3) + vmcnt(4)
  }

  // epilogue: drain, single-pass repack via LDS [192][264]
  asm volatile("s_waitcnt vmcnt(0) lgkmcnt(0)" ::: "memory");
  __syncthreads();
  unsigned short* eld = smem;
  int rb = g * 4;
#pragma unroll
  for (int f = 0; f < 6; ++f)
#pragma unroll
    for (int nf = 0; nf < 4; ++nf)
#pragma unroll
      for (int r = 0; r < 4; ++r)
        eld[(mq * 96 + f * 16 + rb + r) * 264 + nq * 64 + nf * 16 + lr] = f2bf(acc[f][nf][r]);
  __syncthreads();
  if (WRITE_C1) {
#pragma unroll
    for (int uu = 0; uu < 2; ++uu) {
      int u = uu * 512 + tid;
      if (u < 768) {
        int row = u >> 2, q = u & 3;
        unsigned short* dst = C1 + (size_t)(m0 + row) * 4096 + n0 + q * 64;
        const unsigned short* sp = eld + row * 264 + q * 64;
#pragma unroll
        for (int j = 0; j < 8; ++j) *(s16x8*)(dst + j * 8) = *(const s16x8*)(sp + j * 8);
      }
    }
  }
  int bb2 = m0 / 384, lb = (m0 % 384) >> 5;
#pragma unroll
  for (int uu = 0; uu < 3; ++uu) {
    int u = uu * 512 + tid;                  // 1536 units: 6 lg x 256 nl
    int lg = u >> 8, nl = u & 255;
    int node = n0 + nl;
    if (node < 4000) {
      alignas(16) unsigned short tmp[32];
#pragma unroll
      for (int c = 0; c < 32; ++c) tmp[c] = eld[(lg * 32 + c) * 264 + nl];
      unsigned short* d2 = Scat + ((size_t)(bb2 * 4000 + node) * 12 + lb + lg) * 224 + jcol;
#pragma unroll
      for (int j = 0; j < 4; ++j) *(s16x8*)(d2 + j * 8) = *(const s16x8*)(tmp + j * 8);
    }
  }
}

// ---------------------------------------------------------------------------
// mlp GEMM: OUT[oc=64][bn] = sum_{k<672} Wcat[oc][k] * Scat[bn*12+t][k..], then
// gate tanh*sigmoid -> G[b][t][c][4096] f32.  Tile 64x256, 4 waves of 64x64.
// ---------------------------------------------------------------------------
__global__ __launch_bounds__(256, 2)
void k_mlp(const unsigned short* __restrict__ Wcat, const unsigned short* __restrict__ Scat,
           const float* __restrict__ mlp_b, float* __restrict__ G) {
  __shared__ unsigned short lds[2048 + 8192];  // Ws[64][32] + Bs[256][32]
  unsigned short* Ws = lds;
  unsigned short* Bs = lds + 2048;
  int tid = threadIdx.x;
  int bn0 = blockIdx.x * 256;
  int t = blockIdx.y;      // 0..9
  int w = tid >> 6, lane = tid & 63;
  int lr = lane & 15, lk = (lane >> 4) * 8;
  f32x4 acc[4][4] = {};
  const unsigned short* gw = Wcat + (size_t)(tid >> 2) * 672 + (tid & 3) * 8;
  const unsigned short* gq = Scat + ((size_t)(bn0 + (tid >> 2)) * 12 + t) * 224 + (tid & 3) * 8;
  unsigned short* lw = Ws + tid * 8;
  unsigned short* lq = Bs + tid * 8;
  for (int s = 0; s < 21; ++s) {
    gload16(gw + s * 32, lw);
#pragma unroll
    for (int r = 0; r < 4; ++r)
      gload16(gq + (size_t)r * 64 * 2688 + s * 32, lq + r * 2048);
    __syncthreads();
    s16x8 a[4], bb[4];
#pragma unroll
    for (int f = 0; f < 4; ++f) {
      a[f] = *(const s16x8*)(Ws + (f * 16 + lr) * 32 + lk);
      bb[f] = *(const s16x8*)(Bs + (w * 64 + f * 16 + lr) * 32 + lk);
    }
#pragma unroll
    for (int fm = 0; fm < 4; ++fm)
#pragma unroll
      for (int fn = 0; fn < 4; ++fn)
        acc[fm][fn] = __builtin_amdgcn_mfma_f32_16x16x32_bf16(a[fm], bb[fn], acc[fm][fn], 0, 0, 0);
    __syncthreads();
  }
  int rbase = (lane >> 4) * 4;
#pragma unroll
  for (int fn = 0; fn < 4; ++fn) {
    int bn = bn0 + w * 64 + fn * 16 + lr;
    int b = bn / 4000;
    int n = bn - b * 4000;
    float* gbase = G + (size_t)(b * 10 + t) * 32 * 4096 + n;
#pragma unroll
    for (int fm = 0; fm < 2; ++fm)
#pragma unroll
      for (int r = 0; r < 4; ++r) {
        int c = fm * 16 + rbase + r;
        float v1 = acc[fm][fn][r] + mlp_b[c];
        float v2 = acc[fm + 2][fn][r] + mlp_b[c + 32];
        gbase[(size_t)c * 4096] = tanhf(v1) * (1.0f / (1.0f + __expf(-v2)));
      }
  }
}

// ct1: g6[b][c][n][q] = ct1_b[q] + sum_{l<10} ct1_w[q][l] * G[b][l][c][n]
__global__ void k_ct1(const float* __restrict__ G, const float* __restrict__ ct1_w,
                      const float* __restrict__ ct1_b, float* __restrict__ g6) {
  int idx = blockIdx.x * 256 + threadIdx.x;
  if (idx >= 8 * 32 * 4000) return;
  int n = idx % 4000;
  int c = (idx / 4000) % 32;
  int b = idx / (4000 * 32);
  const float* gp = G + ((size_t)(b * 10) * 32 + c) * 4096 + n;
  float v[10];
#pragma unroll
  for (int l = 0; l < 10; ++l) v[l] = gp[(size_t)l * 32 * 4096];
  float* o = g6 + (size_t)idx * 6;
#pragma unroll
  for (int q = 0; q < 6; ++q) {
    float a = ct1_b[q];
#pragma unroll
    for (int l = 0; l < 10; ++l) a += ct1_w[q * 10 + l] * v[l];
    o[q] = a;
  }
}

// f1[b][t][n] = sum_c c1[c] * g6[b][c][n][t]
__global__ void k_f1(const float* __restrict__ g6, const float* __restrict__ c1,
                     float* __restrict__ f1) {
  int idx = blockIdx.x * 128 + threadIdx.x;
  if (idx >= 8 * 4000) return;
  int n = idx % 4000, b = idx / 4000;
  float acc[6] = {};
  const float* gp = g6 + ((size_t)b * 32 * 4000 + n) * 6;
  for (int c = 0; c < 32; ++c) {
    float wv = c1[c];
    const float* p = gp + (size_t)c * 4000 * 6;
#pragma unroll
    for (int t = 0; t < 6; ++t) acc[t] += wv * p[t];
  }
  for (int t = 0; t < 6; ++t) f1[((size_t)b * 6 + t) * 4000 + n] = acc[t];
}

// f2[b][c][t] = sum_n c2[n] * g6[b][c][n][t]
__global__ void k_f2(const float* __restrict__ g6, const float* __restrict__ c2,
                     float* __restrict__ f2) {
  __shared__ float red[256 * 6];
  int bc = blockIdx.x;
  int tid = threadIdx.x;
  float acc[6] = {};
  const float* gp = g6 + (size_t)bc * 4000 * 6;
  for (int n = tid; n < 4000; n += 256) {
    float wv = c2[n];
#pragma unroll
    for (int t = 0; t < 6; ++t) acc[t] += wv * gp[(size_t)n * 6 + t];
  }
  for (int t = 0; t < 6; ++t) red[tid * 6 + t] = acc[t];
  __syncthreads();
  for (int s = 128; s > 0; s >>= 1) {
    if (tid < s)
      for (int t = 0; t < 6; ++t) red[tid * 6 + t] += red[(tid + s) * 6 + t];
    __syncthreads();
  }
  if (tid < 6) f2[bc * 6 + tid] = red[tid];
}

// m1[b][t][c] += sum over n-chunk of f1[b][t][n] * tat_w[n][c]; grid (48,16)
__global__ void k_m1(const float* __restrict__ f1, const float* __restrict__ tw,
                     float* __restrict__ m1) {
  __shared__ float red[8][32];
  int bt = blockIdx.x;
  int nc = blockIdx.y;
  int tid = threadIdx.x;
  int c = tid & 31, gi = tid >> 5;
  float acc = 0.f;
  const float* fp = f1 + (size_t)bt * 4000 + nc * 250;
  const float* twp = tw + ((size_t)nc * 250) * 32 + c;
  for (int n = gi; n < 250; n += 8) acc += fp[n] * twp[n * 32];
  red[gi][c] = acc;
  __syncthreads();
  if (tid < 32) {
    float s = 0.f;
#pragma unroll
    for (int gg = 0; gg < 8; ++gg) s += red[gg][c];
    atomicAdd(&m1[(size_t)bt * 32 + c], s);
  }
}

// logits -> sigmoid -> tat_v mix -> BN1 -> softmax -> coefs[b][t][q]
__global__ void k_att(const float* __restrict__ m1, const float* __restrict__ f2,
                      const float* __restrict__ bias, const float* __restrict__ tv,
                      const float* __restrict__ g1, const float* __restrict__ b1,
                      float* __restrict__ coefs) {
  __shared__ float sig[48 * 6], lgs[48 * 6], mu[6], iv[6];
  int tid = threadIdx.x;
  int b = tid / 6, t = tid % 6;
  if (tid < 48) {
    for (int s = 0; s < 6; ++s) {
      float a = bias[t * 6 + s];
      for (int c = 0; c < 32; ++c)
        a += m1[((size_t)b * 6 + t) * 32 + c] * f2[((size_t)b * 32 + c) * 6 + s];
      sig[tid * 6 + s] = 1.0f / (1.0f + __expf(-a));
    }
  }
  __syncthreads();
  if (tid < 48) {
    for (int q = 0; q < 6; ++q) {
      float a = 0.f;
      for (int s = 0; s < 6; ++s) a += tv[t * 6 + s] * sig[(b * 6 + s) * 6 + q];
      lgs[tid * 6 + q] = a;
    }
  }
  __syncthreads();
  if (tid < 6) {
    float s = 0, s2 = 0;
    for (int r = 0; r < 48; ++r) { float v = lgs[r * 6 + tid]; s += v; s2 += v * v; }
    float m = s / 48.f;
    mu[tid] = m;
    iv[tid] = rsqrtf(s2 / 48.f - m * m + 1e-5f);
  }
  __syncthreads();
  if (tid < 48) {
    float v[6], mx = -1e30f;
    for (int q = 0; q < 6; ++q) {
      v[q] = (lgs[tid * 6 + q] - mu[q]) * iv[q] * g1[q] + b1[q];
      mx = fmaxf(mx, v[q]);
    }
    float s = 0;
    for (int q = 0; q < 6; ++q) { v[q] = __expf(v[q] - mx); s += v[q]; }
    float inv = 1.0f / s;
    for (int q = 0; q < 6; ++q) coefs[tid * 6 + q] = v[q] * inv;
  }
}

// y = attention-mix(g6) + conv1(x)[...,6:] -> out (pre-BN2)
__global__ void k_final1(const float* __restrict__ x, const float* __restrict__ cw,
                         const float* __restrict__ cb, const float* __restrict__ g6,
                         const float* __restrict__ coefs, float* __restrict__ out) {
  __shared__ float xt[32 * 8 * 6];
  __shared__ float cwT[1024];
  __shared__ float cfs[36], cbs[32];
  int n0 = blockIdx.x * 8;
  int b = blockIdx.y;
  int tid = threadIdx.x;
  {
    int ci = tid >> 3, seg = tid & 7;
    const float* xp = x + ((size_t)(b * 32 + ci) * 4000 + n0 + seg) * 12 + 6;
#pragma unroll
    for (int q = 0; q < 6; ++q) xt[(ci * 8 + seg) * 6 + q] = xp[q];
  }
  for (int i = tid; i < 1024; i += 256) { int o = i >> 5, ci = i & 31; cwT[ci * 32 + o] = cw[i]; }
  if (tid < 36) cfs[tid] = coefs[b * 36 + tid];
  if (tid < 32) cbs[tid] = cb[tid];
  __syncthreads();
  int nn = tid & 7, c = tid >> 3;
  const float* gp = g6 + ((size_t)(b * 32 + c) * 4000 + n0 + nn) * 6;
  float gv[6];
#pragma unroll
  for (int l = 0; l < 6; ++l) gv[l] = gp[l];
  float y[6];
#pragma unroll
  for (int q = 0; q < 6; ++q) {
    float at = 0.f;
#pragma unroll
    for (int l = 0; l < 6; ++l) at += gv[l] * cfs[q * 6 + l];
    y[q] = at + cbs[c];
  }
  for (int ci = 0; ci < 32; ++ci) {
    float wv = cwT[ci * 32 + c];
#pragma unroll
    for (int q = 0; q < 6; ++q) y[q] += wv * xt[(ci * 8 + nn) * 6 + q];
  }
  float* op = out + ((size_t)(b * 32 + c) * 4000 + n0 + nn) * 6;
#pragma unroll
  for (int q = 0; q < 6; ++q) op[q] = y[q];
}

// per-channel sum/sumsq of out: grid (4, 256), f32x4 + shfl reduce + atomicAdd
__global__ void k_stats(const float* __restrict__ out, float* __restrict__ stats) {
  __shared__ float r1[4], r2[4];
  int bc = blockIdx.y;
  int c = bc & 31;
  int tid = threadIdx.x;
  const float* p = out + (size_t)bc * 24000 + blockIdx.x * 6000;
  float s = 0.f, s2 = 0.f;
  for (int i = tid * 4; i < 6000; i += 1024) {
    f32x4 v = *(const f32x4*)(p + i);
    s  += v.x + v.y + v.z + v.w;
    s2 += v.x * v.x + v.y * v.y + v.z * v.z + v.w * v.w;
  }
#pragma unroll
  for (int off = 32; off > 0; off >>= 1) {
    s  += __shfl_down(s, off);
    s2 += __shfl_down(s2, off);
  }
  int lane = tid & 63, w = tid >> 6;
  if (lane == 0) { r1[w] = s; r2[w] = s2; }
  __syncthreads();
  if (tid == 0) {
    atomicAdd(&stats[c],      r1[0] + r1[1] + r1[2] + r1[3]);
    atomicAdd(&stats[32 + c], r2[0] + r2[1] + r2[2] + r2[3]);
  }
}

__global__ void k_final2(float* __restrict__ out, const float* __restrict__ stats,
                         const float* __restrict__ g2, const float* __restrict__ b2) {
  int idx = (blockIdx.x * 256 + threadIdx.x) * 4;
  if (idx >= 6144000) return;
  int c = (idx / 24000) % 32;
  float mean = stats[c] * (1.0f / 192000.f);
  float var = stats[32 + c] * (1.0f / 192000.f) - mean * mean;
  float sc = rsqrtf(var + 1e-5f) * g2[c];
  float sh = b2[c] - mean * sc;
  f32x4 v = *(f32x4*)(out + idx);
  v.x = v.x * sc + sh; v.y = v.y * sc + sh; v.z = v.z * sc + sh; v.w = v.w * sc + sh;
  *(f32x4*)(out + idx) = v;
}

// ---------------------------------------------------------------------------
extern "C" void kernel_launch(void* const* d_in, const int* in_sizes, int n_in,
                              void* d_out, int out_size, void* d_ws, size_t ws_size,
                              hipStream_t stream) {
  (void)in_sizes; (void)n_in; (void)out_size;
  const float* x       = (const float*)d_in[0];
  const float* A[3]    = {(const float*)d_in[1], (const float*)d_in[2], (const float*)d_in[3]};
  const float* conv1_w = (const float*)d_in[4];
  const float* conv1_b = (const float*)d_in[5];
  const float* mlp_w   = (const float*)d_in[6];
  const float* mlp_b   = (const float*)d_in[7];
  const float* ct1_w   = (const float*)d_in[8];
  const float* ct1_b   = (const float*)d_in[9];
  const float* c1w     = (const float*)d_in[10];
  const float* c2w     = (const float*)d_in[11];
  const float* tw      = (const float*)d_in[12];
  const float* tbias   = (const float*)d_in[13];
  const float* tv      = (const float*)d_in[14];
  const float* bn1g    = (const float*)d_in[15];
  const float* bn1b    = (const float*)d_in[16];
  const float* bn2g    = (const float*)d_in[17];
  const float* bn2b    = (const float*)d_in[18];
  float* out = (float*)d_out;

  char* ws = (char*)d_ws;
  size_t off = 0;
  auto alloc = [&](size_t bytes) { size_t r = off; off += (bytes + 255) & ~(size_t)255; return r; };
  size_t oScat = alloc(172032000);   // [32000*12][224] bf16
  size_t oXt   = alloc(25165824);    // [3072][4096] bf16 ; later g6 (24.576MB f32)
  size_t oA    = alloc(33554432);    // Abf [4096][4096] bf16 ; with oY1t, later G
  size_t oY1t  = alloc(25165824);    // [3072][4096] bf16
  size_t oWcat = alloc(86016);
  size_t oF1 = alloc(768000);
  size_t oF2 = alloc(6144);
  size_t oM1 = alloc(6144);
  size_t oCf = alloc(1152);
  size_t oSt = alloc(256);
  if (ws_size < off) return;  // insufficient scratch -> visible validation failure

  unsigned short* Scat = (unsigned short*)(ws + oScat);
  unsigned short* Xt   = (unsigned short*)(ws + oXt);
  float*          g6   = (float*)(ws + oXt);
  unsigned short* Abf  = (unsigned short*)(ws + oA);
  float*          G    = (float*)(ws + oA);
  unsigned short* Y1t  = (unsigned short*)(ws + oY1t);
  unsigned short* Wcat = (unsigned short*)(ws + oWcat);

  hipFuncSetAttribute((const void*)k_gemm<0>, hipFuncAttributeMaxDynamicSharedMemorySize, 114688);
  hipFuncSetAttribute((const void*)k_gemm<1>, hipFuncAttributeMaxDynamicSharedMemorySize, 114688);

  hipMemsetAsync(Xt, 0, 25165824, stream);       // v-padding 4000..4095 must be 0
  hipMemsetAsync(ws + oSt, 0, 256, stream);      // stats accumulators
  hipMemsetAsync(ws + oM1, 0, 6144, stream);     // m1 accumulators
  k_transpose<<<dim3(125, 8), 256, 0, stream>>>(x, Xt, Scat);
  k_wcat<<<168, 256, 0, stream>>>(mlp_w, Wcat);
  for (int i = 0; i < 3; ++i) {
    k_castA<<<16384, 256, 0, stream>>>(A[i], Abf);
    // Y1t[col][node] = sum_v Xt[col][v]*Abf[node][v]; Scat j=2i+1
    k_gemm<1><<<256, 512, 114688, stream>>>(Xt, Abf, Y1t, Scat, (2 * i + 1) * 32);
    // x2^T[col][node] = sum_v Y1t[col][v]*Abf[node][v]; Scat j=2i+2
    k_gemm<0><<<256, 512, 114688, stream>>>(Y1t, Abf, nullptr, Scat, (2 * i + 2) * 32);
  }
  k_mlp<<<dim3(125, 10), 256, 0, stream>>>(Wcat, Scat, mlp_b, G);
  k_ct1<<<4000, 256, 0, stream>>>(G, ct1_w, ct1_b, g6);
  k_f1<<<250, 128, 0, stream>>>(g6, c1w, (float*)(ws + oF1));
  k_f2<<<256, 256, 0, stream>>>(g6, c2w, (float*)(ws + oF2));
  k_m1<<<dim3(48, 16), 256, 0, stream>>>((float*)(ws + oF1), tw, (float*)(ws + oM1));
  k_att<<<1, 64, 0, stream>>>((float*)(ws + oM1), (float*)(ws + oF2), tbias, tv, bn1g, bn1b,
                              (float*)(ws + oCf));
  k_final1<<<dim3(500, 8), 256, 0, stream>>>(x, conv1_w, conv1_b, g6, (float*)(ws + oCf), out);
  k_stats<<<dim3(4, 256), 256, 0, stream>>>(out, (float*)(ws + oSt));
  k_final2<<<6000, 256, 0, stream>>>(out, (float*)(ws + oSt), bn2g, bn2b);
}

// Round 10
// 815.087 us; speedup vs baseline: 1.6602x; 1.0059x over previous
//
#include <hip/hip_runtime.h>
#include <hip/hip_bf16.h>
#include <cstdint>
#include <cstddef>

// ---------------------------------------------------------------------------
// GCNPool fused pipeline, MI355X/gfx950.  B=8, C=32, N=4000 (pad 4096), T=12.
// Round 10: single-barrier 6-phase GEMM.  Round 9's post-MFMA barrier removed
// (12 -> 6 barriers per 2 K-tiles); staging reassigned so every phase stages
// only buffers not read in this phase or the previous one (wave skew is
// bounded by one barrier interval), vmcnt(2) at ph3/ph6 re-derived by FIFO
// count.  Waves now desync within a barrier interval -> cross-wave MFMA/LDS
// overlap inside the single resident block.
// ---------------------------------------------------------------------------

typedef __attribute__((ext_vector_type(8))) short s16x8;
typedef __attribute__((ext_vector_type(4))) short s16x4;
typedef __attribute__((ext_vector_type(4))) float f32x4;

#define DEVFN __device__ __forceinline__

DEVFN void gload16(const void* g, void* l) {
  __builtin_amdgcn_global_load_lds((const __attribute__((address_space(1))) unsigned int*)g,
                                   (__attribute__((address_space(3))) unsigned int*)l, 16, 0, 0);
}

DEVFN unsigned short f2bf(float f) {  // round-to-nearest-even f32 -> bf16
  union { float f; unsigned int u; } v; v.f = f;
  unsigned int u = v.u;
  return (unsigned short)((u + 0x7fffu + ((u >> 16) & 1u)) >> 16);
}

// ---------------------------------------------------------------------------
// x (B,C,4000,12) f32 -> Xt[col=b*384+l*32+c][v 4096] bf16  (GEMM1 P operand)
//                     -> Scat[(b*4000+v)*12+l][224] slice j=0 (cols 0..31)
// ---------------------------------------------------------------------------
__global__ void k_transpose(const float* __restrict__ x,
                            unsigned short* __restrict__ Xt,
                            unsigned short* __restrict__ Scat) {
  __shared__ float ldsT[32 * 417];   // [c]*417 + vv*13 + l
  int v0 = blockIdx.x * 32;
  int b = blockIdx.y;
  int tid = threadIdx.x;
  for (int i = tid; i < 1024; i += 256) {
    int c = i >> 5, vv = i & 31;
    const float* src = x + ((size_t)(b * 32 + c) * 4000 + v0 + vv) * 12;
    f32x4 a0 = *(const f32x4*)(src);
    f32x4 a1 = *(const f32x4*)(src + 4);
    f32x4 a2 = *(const f32x4*)(src + 8);
    float* d = ldsT + c * 417 + vv * 13;
    d[0] = a0.x; d[1] = a0.y; d[2] = a0.z; d[3] = a0.w;
    d[4] = a1.x; d[5] = a1.y; d[6] = a1.z; d[7] = a1.w;
    d[8] = a2.x; d[9] = a2.y; d[10] = a2.z; d[11] = a2.w;
  }
  __syncthreads();
  for (int unit = tid; unit < 384; unit += 256) {
    int l = unit >> 5, c = unit & 31;
    alignas(16) unsigned short tmp[32];
#pragma unroll
    for (int vv = 0; vv < 32; ++vv) tmp[vv] = f2bf(ldsT[c * 417 + vv * 13 + l]);
    unsigned short* dst = Xt + (size_t)(b * 384 + l * 32 + c) * 4096 + v0;
#pragma unroll
    for (int j = 0; j < 4; ++j) *(s16x8*)(dst + j * 8) = *(const s16x8*)(tmp + j * 8);
  }
  for (int unit = tid; unit < 384; unit += 256) {
    int l = unit >> 5, vv = unit & 31;
    alignas(16) unsigned short tmp[32];
#pragma unroll
    for (int c = 0; c < 32; ++c) tmp[c] = f2bf(ldsT[c * 417 + vv * 13 + l]);
    unsigned short* dst = Scat + ((size_t)(b * 4000 + v0 + vv) * 12 + l) * 224;
#pragma unroll
    for (int j = 0; j < 4; ++j) *(s16x8*)(dst + j * 8) = *(const s16x8*)(tmp + j * 8);
  }
}

// A (4000,4000) f32 -> A_bf[4096][4096] bf16, zero-padded rows/cols.
__global__ void k_castA(const float* __restrict__ A, unsigned short* __restrict__ Abf) {
  int idx = blockIdx.x * 256 + threadIdx.x;
  int r = idx >> 10;
  int c4 = (idx & 1023) << 2;
  alignas(8) unsigned short o[4] = {0, 0, 0, 0};
  if (r < 4000 && c4 < 4000) {
    f32x4 v = *(const f32x4*)(A + (size_t)r * 4000 + c4);
    o[0] = f2bf(v.x); o[1] = f2bf(v.y); o[2] = f2bf(v.z); o[3] = f2bf(v.w);
  }
  *(s16x4*)(Abf + (size_t)r * 4096 + c4) = *(const s16x4*)o;
}

// mlp_w (64,224,1,3) f32 -> Wcat[oc][kt*224+ic] bf16 (t-independent)
__global__ void k_wcat(const float* __restrict__ mlp_w, unsigned short* __restrict__ Wcat) {
  int i = blockIdx.x * 256 + threadIdx.x;
  if (i >= 64 * 672) return;
  int oc = i / 672, k = i % 672;
  int kt = k / 224, ic = k % 224;
  Wcat[i] = f2bf(mlp_w[((size_t)oc * 224 + ic) * 3 + kt]);
}

// ---------------------------------------------------------------------------
// C[m][n] = sum_k P[m][k] * Q[n][k], bf16, K=4096.  192x256 tile, BK=64,
// 8 waves (2M x 4N, wave-tile 96x64), 6 single-barrier phases per 2 K-tiles,
// counted vmcnt(2), XOR k-slot swizzle.  Grid 256 = 1/CU.
// LDS (shorts): A(d) full tile at d*12288 (192x64); B(d,h) at
// 24576 + (d*2+h)*8192 (128x64 each).  Total 57344 shorts = 112 KiB.
// Staging safety rule (single barrier, skew <= 1 interval): a phase stages
// only buffers not read in this phase or the previous one.
// ---------------------------------------------------------------------------
#define MFMA_(a, b, c) __builtin_amdgcn_mfma_f32_16x16x32_bf16(a, b, c, 0, 0, 0)

#define STGA(d, t) do {                                                          \
    const unsigned short* _s = aSrc + (size_t)(t) * 64;                          \
    unsigned short* _l = smem + (d) * 12288;                                     \
    gload16(_s,          _l + tid * 8);                                          \
    gload16(_s + 262144, _l + (512 + tid) * 8);                                  \
    gload16(_s + 524288, _l + (1024 + tid) * 8);                                 \
  } while (0)

#define STGB(d, h, t) do {                                                       \
    const unsigned short* _s = bSrc + (size_t)(h) * 524288 + (size_t)(t) * 64;   \
    unsigned short* _l = smem + 24576 + ((d) * 2 + (h)) * 8192;                  \
    gload16(_s,          _l + tid * 8);                                          \
    gload16(_s + 262144, _l + (512 + tid) * 8);                                  \
  } while (0)

#define LDA_(d, f, kk) (*(const s16x8*)(smem + (d) * 12288 + aoff + (f) * 1024 + ((kk) ? sxor : 0)))
#define LDB_(d, nf, kk) (*(const s16x8*)(smem + 24576 + ((d) * 2 + hb) * 8192 + boff + (nf) * 1024 + ((kk) ? sxor : 0)))

// single-barrier phase: {reads; stage; [vmcnt]; barrier; lgkm(0); MFMA}
#define PHASE(d, mp, FIRST, STAGE_CODE, VM) do {                                 \
    s16x8 a00 = LDA_(d, 2 * (mp), 0),     a01 = LDA_(d, 2 * (mp), 1);            \
    s16x8 a10 = LDA_(d, 2 * (mp) + 1, 0), a11 = LDA_(d, 2 * (mp) + 1, 1);        \
    if (FIRST) {                                                                 \
      _Pragma("unroll")                                                          \
      for (int nf = 0; nf < 4; ++nf) { bfr[nf][0] = LDB_(d, nf, 0); bfr[nf][1] = LDB_(d, nf, 1); } \
    }                                                                            \
    STAGE_CODE;                                                                  \
    if (VM) asm volatile("s_waitcnt vmcnt(2)" ::: "memory");                     \
    __builtin_amdgcn_s_barrier();                                                \
    asm volatile("s_waitcnt lgkmcnt(0)" ::: "memory");                           \
    __builtin_amdgcn_s_setprio(1);                                               \
    _Pragma("unroll")                                                            \
    for (int nf = 0; nf < 4; ++nf) {                                             \
      acc[2 * (mp)][nf]     = MFMA_(a00, bfr[nf][0], acc[2 * (mp)][nf]);         \
      acc[2 * (mp)][nf]     = MFMA_(a01, bfr[nf][1], acc[2 * (mp)][nf]);         \
      acc[2 * (mp) + 1][nf] = MFMA_(a10, bfr[nf][0], acc[2 * (mp) + 1][nf]);     \
      acc[2 * (mp) + 1][nf] = MFMA_(a11, bfr[nf][1], acc[2 * (mp) + 1][nf]);     \
    }                                                                            \
    __builtin_amdgcn_s_setprio(0);                                               \
  } while (0)

template <int WRITE_C1>
__global__ __launch_bounds__(512, 2)
void k_gemm(const unsigned short* __restrict__ P, const unsigned short* __restrict__ Q,
            unsigned short* __restrict__ C1, unsigned short* __restrict__ Scat, int jcol) {
  extern __shared__ unsigned short smem[];   // 57344 shorts = 112 KiB
  int tid = threadIdx.x;
  int w = tid >> 6, lane = tid & 63;
  int lr = lane & 15, g = lane >> 4;
  int mq = w >> 2, nq = w & 3;               // 2M x 4N wave grid (96 x 64 each)
  int bid = blockIdx.x;
  int xcd = bid & 7, lid = bid >> 3;         // 256 blocks; per XCD: 2 n-tiles x 16 m-tiles
  int nt = xcd * 2 + (lid >> 4);
  int mt = lid & 15;
  int m0 = mt * 192, n0 = nt * 256;
  int hb = nq >> 1;
  int slot0 = (g ^ (lr & 7)) * 8;
  int sxor = (slot0 & 32) ? -32 : 32;
  int aoff = (mq * 96 + lr) * 64 + slot0;
  int boff = ((nq & 1) * 64 + lr) * 64 + slot0;
  int gk = ((tid & 7) ^ ((tid >> 3) & 7)) * 8;   // pre-swizzled global k offset
  const unsigned short* aSrc = P + (size_t)(m0 + (tid >> 3)) * 4096 + gk;
  const unsigned short* bSrc = Q + (size_t)(n0 + (tid >> 3)) * 4096 + gk;
  f32x4 acc[6][4] = {};
  s16x8 bfr[4][2];

  // prologue: A(d0,t0), B(d0,t0) h0+h1, B(d1,t1) h0; vmcnt(2) retires the
  // first 7 (A(d0)+B(d0)), keeps B(d1,t1)h0 in flight.
  STGA(0, 0);
  STGB(0, 0, 0); STGB(0, 1, 0);
  STGB(1, 0, 1);
  asm volatile("s_waitcnt vmcnt(2)" ::: "memory");
  __builtin_amdgcn_s_barrier();

#pragma unroll 1
  for (int i = 0; i < 32; ++i) {
    int t1 = 2 * i + 1, t2 = 2 * i + 2, t3 = 2 * i + 3;
    // stage targets chosen so staged buffer is never read in this or the
    // previous phase (reads: ph1-3 = A(d0)+B(d0)@ph1; ph4-6 = A(d1)+B(d1)@ph4)
    PHASE(0, 0, 1, STGB(1, 1, t1), 0);   // ph1: B(d1,h1,t1)
    PHASE(0, 1, 0, STGA(1, t1),    0);   // ph2: A(d1,t1)
    PHASE(0, 2, 0, STGB(0, 0, t2), 1);   // ph3: B(d0,h0,t2) + vmcnt(2) -> d1 ready
    PHASE(1, 0, 1, STGB(0, 1, t2), 0);   // ph4: B(d0,h1,t2)
    PHASE(1, 1, 0, STGA(0, t2),    0);   // ph5: A(d0,t2)
    PHASE(1, 2, 0, STGB(1, 0, t3), 1);   // ph6: B(d1,h0,t3) + vmcnt(2) -> d0 ready
  }

  // epilogue: drain, single-pass repack via LDS [192][264]
  asm volatile("s_waitcnt vmcnt(0) lgkmcnt(0)" ::: "memory");
  __syncthreads();
  unsigned short* eld = smem;
  int rb = g * 4;
#pragma unroll
  for (int f = 0; f < 6; ++f)
#pragma unroll
    for (int nf = 0; nf < 4; ++nf)
#pragma unroll
      for (int r = 0; r < 4; ++r)
        eld[(mq * 96 + f * 16 + rb + r) * 264 + nq * 64 + nf * 16 + lr] = f2bf(acc[f][nf][r]);
  __syncthreads();
  if (WRITE_C1) {
#pragma unroll
    for (int uu = 0; uu < 2; ++uu) {
      int u = uu * 512 + tid;
      if (u < 768) {
        int row = u >> 2, q = u & 3;
        unsigned short* dst = C1 + (size_t)(m0 + row) * 4096 + n0 + q * 64;
        const unsigned short* sp = eld + row * 264 + q * 64;
#pragma unroll
        for (int j = 0; j < 8; ++j) *(s16x8*)(dst + j * 8) = *(const s16x8*)(sp + j * 8);
      }
    }
  }
  int bb2 = m0 / 384, lb = (m0 % 384) >> 5;
#pragma unroll
  for (int uu = 0; uu < 3; ++uu) {
    int u = uu * 512 + tid;                  // 1536 units: 6 lg x 256 nl
    int lg = u >> 8, nl = u & 255;
    int node = n0 + nl;
    if (node < 4000) {
      alignas(16) unsigned short tmp[32];
#pragma unroll
      for (int c = 0; c < 32; ++c) tmp[c] = eld[(lg * 32 + c) * 264 + nl];
      unsigned short* d2 = Scat + ((size_t)(bb2 * 4000 + node) * 12 + lb + lg) * 224 + jcol;
#pragma unroll
      for (int j = 0; j < 4; ++j) *(s16x8*)(d2 + j * 8) = *(const s16x8*)(tmp + j * 8);
    }
  }
}

// ---------------------------------------------------------------------------
// mlp GEMM: OUT[oc=64][bn] = sum_{k<672} Wcat[oc][k] * Scat[bn*12+t][k..], then
// gate tanh*sigmoid -> G[b][t][c][4096] f32.  Tile 64x256, 4 waves of 64x64.
// ---------------------------------------------------------------------------
__global__ __launch_bounds__(256, 2)
void k_mlp(const unsigned short* __restrict__ Wcat, const unsigned short* __restrict__ Scat,
           const float* __restrict__ mlp_b, float* __restrict__ G) {
  __shared__ unsigned short lds[2048 + 8192];  // Ws[64][32] + Bs[256][32]
  unsigned short* Ws = lds;
  unsigned short* Bs = lds + 2048;
  int tid = threadIdx.x;
  int bn0 = blockIdx.x * 256;
  int t = blockIdx.y;      // 0..9
  int w = tid >> 6, lane = tid & 63;
  int lr = lane & 15, lk = (lane >> 4) * 8;
  f32x4 acc[4][4] = {};
  const unsigned short* gw = Wcat + (size_t)(tid >> 2) * 672 + (tid & 3) * 8;
  const unsigned short* gq = Scat + ((size_t)(bn0 + (tid >> 2)) * 12 + t) * 224 + (tid & 3) * 8;
  unsigned short* lw = Ws + tid * 8;
  unsigned short* lq = Bs + tid * 8;
  for (int s = 0; s < 21; ++s) {
    gload16(gw + s * 32, lw);
#pragma unroll
    for (int r = 0; r < 4; ++r)
      gload16(gq + (size_t)r * 64 * 2688 + s * 32, lq + r * 2048);
    __syncthreads();
    s16x8 a[4], bb[4];
#pragma unroll
    for (int f = 0; f < 4; ++f) {
      a[f] = *(const s16x8*)(Ws + (f * 16 + lr) * 32 + lk);
      bb[f] = *(const s16x8*)(Bs + (w * 64 + f * 16 + lr) * 32 + lk);
    }
#pragma unroll
    for (int fm = 0; fm < 4; ++fm)
#pragma unroll
      for (int fn = 0; fn < 4; ++fn)
        acc[fm][fn] = __builtin_amdgcn_mfma_f32_16x16x32_bf16(a[fm], bb[fn], acc[fm][fn], 0, 0, 0);
    __syncthreads();
  }
  int rbase = (lane >> 4) * 4;
#pragma unroll
  for (int fn = 0; fn < 4; ++fn) {
    int bn = bn0 + w * 64 + fn * 16 + lr;
    int b = bn / 4000;
    int n = bn - b * 4000;
    float* gbase = G + (size_t)(b * 10 + t) * 32 * 4096 + n;
#pragma unroll
    for (int fm = 0; fm < 2; ++fm)
#pragma unroll
      for (int r = 0; r < 4; ++r) {
        int c = fm * 16 + rbase + r;
        float v1 = acc[fm][fn][r] + mlp_b[c];
        float v2 = acc[fm + 2][fn][r] + mlp_b[c + 32];
        gbase[(size_t)c * 4096] = tanhf(v1) * (1.0f / (1.0f + __expf(-v2)));
      }
  }
}

// ct1: g6[b][c][n][q] = ct1_b[q] + sum_{l<10} ct1_w[q][l] * G[b][l][c][n]
__global__ void k_ct1(const float* __restrict__ G, const float* __restrict__ ct1_w,
                      const float* __restrict__ ct1_b, float* __restrict__ g6) {
  int idx = blockIdx.x * 256 + threadIdx.x;
  if (idx >= 8 * 32 * 4000) return;
  int n = idx % 4000;
  int c = (idx / 4000) % 32;
  int b = idx / (4000 * 32);
  const float* gp = G + ((size_t)(b * 10) * 32 + c) * 4096 + n;
  float v[10];
#pragma unroll
  for (int l = 0; l < 10; ++l) v[l] = gp[(size_t)l * 32 * 4096];
  float* o = g6 + (size_t)idx * 6;
#pragma unroll
  for (int q = 0; q < 6; ++q) {
    float a = ct1_b[q];
#pragma unroll
    for (int l = 0; l < 10; ++l) a += ct1_w[q * 10 + l] * v[l];
    o[q] = a;
  }
}

// f1[b][t][n] = sum_c c1[c] * g6[b][c][n][t]
__global__ void k_f1(const float* __restrict__ g6, const float* __restrict__ c1,
                     float* __restrict__ f1) {
  int idx = blockIdx.x * 128 + threadIdx.x;
  if (idx >= 8 * 4000) return;
  int n = idx % 4000, b = idx / 4000;
  float acc[6] = {};
  const float* gp = g6 + ((size_t)b * 32 * 4000 + n) * 6;
  for (int c = 0; c < 32; ++c) {
    float wv = c1[c];
    const float* p = gp + (size_t)c * 4000 * 6;
#pragma unroll
    for (int t = 0; t < 6; ++t) acc[t] += wv * p[t];
  }
  for (int t = 0; t < 6; ++t) f1[((size_t)b * 6 + t) * 4000 + n] = acc[t];
}

// f2[b][c][t] = sum_n c2[n] * g6[b][c][n][t]
__global__ void k_f2(const float* __restrict__ g6, const float* __restrict__ c2,
                     float* __restrict__ f2) {
  __shared__ float red[256 * 6];
  int bc = blockIdx.x;
  int tid = threadIdx.x;
  float acc[6] = {};
  const float* gp = g6 + (size_t)bc * 4000 * 6;
  for (int n = tid; n < 4000; n += 256) {
    float wv = c2[n];
#pragma unroll
    for (int t = 0; t < 6; ++t) acc[t] += wv * gp[(size_t)n * 6 + t];
  }
  for (int t = 0; t < 6; ++t) red[tid * 6 + t] = acc[t];
  __syncthreads();
  for (int s = 128; s > 0; s >>= 1) {
    if (tid < s)
      for (int t = 0; t < 6; ++t) red[tid * 6 + t] += red[(tid + s) * 6 + t];
    __syncthreads();
  }
  if (tid < 6) f2[bc * 6 + tid] = red[tid];
}

// m1[b][t][c] += sum over n-chunk of f1[b][t][n] * tat_w[n][c]; grid (48,16)
__global__ void k_m1(const float* __restrict__ f1, const float* __restrict__ tw,
                     float* __restrict__ m1) {
  __shared__ float red[8][32];
  int bt = blockIdx.x;
  int nc = blockIdx.y;
  int tid = threadIdx.x;
  int c = tid & 31, gi = tid >> 5;
  float acc = 0.f;
  const float* fp = f1 + (size_t)bt * 4000 + nc * 250;
  const float* twp = tw + ((size_t)nc * 250) * 32 + c;
  for (int n = gi; n < 250; n += 8) acc += fp[n] * twp[n * 32];
  red[gi][c] = acc;
  __syncthreads();
  if (tid < 32) {
    float s = 0.f;
#pragma unroll
    for (int gg = 0; gg < 8; ++gg) s += red[gg][c];
    atomicAdd(&m1[(size_t)bt * 32 + c], s);
  }
}

// logits -> sigmoid -> tat_v mix -> BN1 -> softmax -> coefs[b][t][q]
__global__ void k_att(const float* __restrict__ m1, const float* __restrict__ f2,
                      const float* __restrict__ bias, const float* __restrict__ tv,
                      const float* __restrict__ g1, const float* __restrict__ b1,
                      float* __restrict__ coefs) {
  __shared__ float sig[48 * 6], lgs[48 * 6], mu[6], iv[6];
  int tid = threadIdx.x;
  int b = tid / 6, t = tid % 6;
  if (tid < 48) {
    for (int s = 0; s < 6; ++s) {
      float a = bias[t * 6 + s];
      for (int c = 0; c < 32; ++c)
        a += m1[((size_t)b * 6 + t) * 32 + c] * f2[((size_t)b * 32 + c) * 6 + s];
      sig[tid * 6 + s] = 1.0f / (1.0f + __expf(-a));
    }
  }
  __syncthreads();
  if (tid < 48) {
    for (int q = 0; q < 6; ++q) {
      float a = 0.f;
      for (int s = 0; s < 6; ++s) a += tv[t * 6 + s] * sig[(b * 6 + s) * 6 + q];
      lgs[tid * 6 + q] = a;
    }
  }
  __syncthreads();
  if (tid < 6) {
    float s = 0, s2 = 0;
    for (int r = 0; r < 48; ++r) { float v = lgs[r * 6 + tid]; s += v; s2 += v * v; }
    float m = s / 48.f;
    mu[tid] = m;
    iv[tid] = rsqrtf(s2 / 48.f - m * m + 1e-5f);
  }
  __syncthreads();
  if (tid < 48) {
    float v[6], mx = -1e30f;
    for (int q = 0; q < 6; ++q) {
      v[q] = (lgs[tid * 6 + q] - mu[q]) * iv[q] * g1[q] + b1[q];
      mx = fmaxf(mx, v[q]);
    }
    float s = 0;
    for (int q = 0; q < 6; ++q) { v[q] = __expf(v[q] - mx); s += v[q]; }
    float inv = 1.0f / s;
    for (int q = 0; q < 6; ++q) coefs[tid * 6 + q] = v[q] * inv;
  }
}

// y = attention-mix(g6) + conv1(x)[...,6:] -> out (pre-BN2)
__global__ void k_final1(const float* __restrict__ x, const float* __restrict__ cw,
                         const float* __restrict__ cb, const float* __restrict__ g6,
                         const float* __restrict__ coefs, float* __restrict__ out) {
  __shared__ float xt[32 * 8 * 6];
  __shared__ float cwT[1024];
  __shared__ float cfs[36], cbs[32];
  int n0 = blockIdx.x * 8;
  int b = blockIdx.y;
  int tid = threadIdx.x;
  {
    int ci = tid >> 3, seg = tid & 7;
    const float* xp = x + ((size_t)(b * 32 + ci) * 4000 + n0 + seg) * 12 + 6;
#pragma unroll
    for (int q = 0; q < 6; ++q) xt[(ci * 8 + seg) * 6 + q] = xp[q];
  }
  for (int i = tid; i < 1024; i += 256) { int o = i >> 5, ci = i & 31; cwT[ci * 32 + o] = cw[i]; }
  if (tid < 36) cfs[tid] = coefs[b * 36 + tid];
  if (tid < 32) cbs[tid] = cb[tid];
  __syncthreads();
  int nn = tid & 7, c = tid >> 3;
  const float* gp = g6 + ((size_t)(b * 32 + c) * 4000 + n0 + nn) * 6;
  float gv[6];
#pragma unroll
  for (int l = 0; l < 6; ++l) gv[l] = gp[l];
  float y[6];
#pragma unroll
  for (int q = 0; q < 6; ++q) {
    float at = 0.f;
#pragma unroll
    for (int l = 0; l < 6; ++l) at += gv[l] * cfs[q * 6 + l];
    y[q] = at + cbs[c];
  }
  for (int ci = 0; ci < 32; ++ci) {
    float wv = cwT[ci * 32 + c];
#pragma unroll
    for (int q = 0; q < 6; ++q) y[q] += wv * xt[(ci * 8 + nn) * 6 + q];
  }
  float* op = out + ((size_t)(b * 32 + c) * 4000 + n0 + nn) * 6;
#pragma unroll
  for (int q = 0; q < 6; ++q) op[q] = y[q];
}

// per-channel sum/sumsq of out: grid (4, 256), f32x4 + shfl reduce + atomicAdd
__global__ void k_stats(const float* __restrict__ out, float* __restrict__ stats) {
  __shared__ float r1[4], r2[4];
  int bc = blockIdx.y;
  int c = bc & 31;
  int tid = threadIdx.x;
  const float* p = out + (size_t)bc * 24000 + blockIdx.x * 6000;
  float s = 0.f, s2 = 0.f;
  for (int i = tid * 4; i < 6000; i += 1024) {
    f32x4 v = *(const f32x4*)(p + i);
    s  += v.x + v.y + v.z + v.w;
    s2 += v.x * v.x + v.y * v.y + v.z * v.z + v.w * v.w;
  }
#pragma unroll
  for (int off = 32; off > 0; off >>= 1) {
    s  += __shfl_down(s, off);
    s2 += __shfl_down(s2, off);
  }
  int lane = tid & 63, w = tid >> 6;
  if (lane == 0) { r1[w] = s; r2[w] = s2; }
  __syncthreads();
  if (tid == 0) {
    atomicAdd(&stats[c],      r1[0] + r1[1] + r1[2] + r1[3]);
    atomicAdd(&stats[32 + c], r2[0] + r2[1] + r2[2] + r2[3]);
  }
}

__global__ void k_final2(float* __restrict__ out, const float* __restrict__ stats,
                         const float* __restrict__ g2, const float* __restrict__ b2) {
  int idx = (blockIdx.x * 256 + threadIdx.x) * 4;
  if (idx >= 6144000) return;
  int c = (idx / 24000) % 32;
  float mean = stats[c] * (1.0f / 192000.f);
  float var = stats[32 + c] * (1.0f / 192000.f) - mean * mean;
  float sc = rsqrtf(var + 1e-5f) * g2[c];
  float sh = b2[c] - mean * sc;
  f32x4 v = *(f32x4*)(out + idx);
  v.x = v.x * sc + sh; v.y = v.y * sc + sh; v.z = v.z * sc + sh; v.w = v.w * sc + sh;
  *(f32x4*)(out + idx) = v;
}

// ---------------------------------------------------------------------------
extern "C" void kernel_launch(void* const* d_in, const int* in_sizes, int n_in,
                              void* d_out, int out_size, void* d_ws, size_t ws_size,
                              hipStream_t stream) {
  (void)in_sizes; (void)n_in; (void)out_size;
  const float* x       = (const float*)d_in[0];
  const float* A[3]    = {(const float*)d_in[1], (const float*)d_in[2], (const float*)d_in[3]};
  const float* conv1_w = (const float*)d_in[4];
  const float* conv1_b = (const float*)d_in[5];
  const float* mlp_w   = (const float*)d_in[6];
  const float* mlp_b   = (const float*)d_in[7];
  const float* ct1_w   = (const float*)d_in[8];
  const float* ct1_b   = (const float*)d_in[9];
  const float* c1w     = (const float*)d_in[10];
  const float* c2w     = (const float*)d_in[11];
  const float* tw      = (const float*)d_in[12];
  const float* tbias   = (const float*)d_in[13];
  const float* tv      = (const float*)d_in[14];
  const float* bn1g    = (const float*)d_in[15];
  const float* bn1b    = (const float*)d_in[16];
  const float* bn2g    = (const float*)d_in[17];
  const float* bn2b    = (const float*)d_in[18];
  float* out = (float*)d_out;

  char* ws = (char*)d_ws;
  size_t off = 0;
  auto alloc = [&](size_t bytes) { size_t r = off; off += (bytes + 255) & ~(size_t)255; return r; };
  size_t oScat = alloc(172032000);   // [32000*12][224] bf16
  size_t oXt   = alloc(25165824);    // [3072][4096] bf16 ; later g6 (24.576MB f32)
  size_t oA    = alloc(33554432);    // Abf [4096][4096] bf16 ; with oY1t, later G
  size_t oY1t  = alloc(25165824);    // [3072][4096] bf16
  size_t oWcat = alloc(86016);
  size_t oF1 = alloc(768000);
  size_t oF2 = alloc(6144);
  size_t oM1 = alloc(6144);
  size_t oCf = alloc(1152);
  size_t oSt = alloc(256);
  if (ws_size < off) return;  // insufficient scratch -> visible validation failure

  unsigned short* Scat = (unsigned short*)(ws + oScat);
  unsigned short* Xt   = (unsigned short*)(ws + oXt);
  float*          g6   = (float*)(ws + oXt);
  unsigned short* Abf  = (unsigned short*)(ws + oA);
  float*          G    = (float*)(ws + oA);
  unsigned short* Y1t  = (unsigned short*)(ws + oY1t);
  unsigned short* Wcat = (unsigned short*)(ws + oWcat);

  hipFuncSetAttribute((const void*)k_gemm<0>, hipFuncAttributeMaxDynamicSharedMemorySize, 114688);
  hipFuncSetAttribute((const void*)k_gemm<1>, hipFuncAttributeMaxDynamicSharedMemorySize, 114688);

  hipMemsetAsync(Xt, 0, 25165824, stream);       // v-padding 4000..4095 must be 0
  hipMemsetAsync(ws + oSt, 0, 256, stream);      // stats accumulators
  hipMemsetAsync(ws + oM1, 0, 6144, stream);     // m1 accumulators
  k_transpose<<<dim3(125, 8), 256, 0, stream>>>(x, Xt, Scat);
  k_wcat<<<168, 256, 0, stream>>>(mlp_w, Wcat);
  for (int i = 0; i < 3; ++i) {
    k_castA<<<16384, 256, 0, stream>>>(A[i], Abf);
    // Y1t[col][node] = sum_v Xt[col][v]*Abf[node][v]; Scat j=2i+1
    k_gemm<1><<<256, 512, 114688, stream>>>(Xt, Abf, Y1t, Scat, (2 * i + 1) * 32);
    // x2^T[col][node] = sum_v Y1t[col][v]*Abf[node][v]; Scat j=2i+2
    k_gemm<0><<<256, 512, 114688, stream>>>(Y1t, Abf, nullptr, Scat, (2 * i + 2) * 32);
  }
  k_mlp<<<dim3(125, 10), 256, 0, stream>>>(Wcat, Scat, mlp_b, G);
  k_ct1<<<4000, 256, 0, stream>>>(G, ct1_w, ct1_b, g6);
  k_f1<<<250, 128, 0, stream>>>(g6, c1w, (float*)(ws + oF1));
  k_f2<<<256, 256, 0, stream>>>(g6, c2w, (float*)(ws + oF2));
  k_m1<<<dim3(48, 16), 256, 0, stream>>>((float*)(ws + oF1), tw, (float*)(ws + oM1));
  k_att<<<1, 64, 0, stream>>>((float*)(ws + oM1), (float*)(ws + oF2), tbias, tv, bn1g, bn1b,
                              (float*)(ws + oCf));
  k_final1<<<dim3(500, 8), 256, 0, stream>>>(x, conv1_w, conv1_b, g6, (float*)(ws + oCf), out);
  k_stats<<<dim3(4, 256), 256, 0, stream>>>(out, (float*)(ws + oSt));
  k_final2<<<6000, 256, 0, stream>>>(out, (float*)(ws + oSt), bn2g, bn2b);
}

// Round 11
// 808.630 us; speedup vs baseline: 1.6735x; 1.0080x over previous
//
#include <hip/hip_runtime.h>
#include <hip/hip_bf16.h>
#include <cstdint>
#include <cstddef>

// ---------------------------------------------------------------------------
// GCNPool fused pipeline, MI355X/gfx950.  B=8, C=32, N=4000 (pad 4096), T=12.
// Round 11: one-pass k_mlp.  Old version re-read each Scat K-row ~2.5x (t
// windows overlap) -> 267MB FETCH, 40% HBM, 101us.  New: iterate l-slices of
// Scat once; each contributes to t in {l-2,l-1,l} via weight slice kt=l-t;
// rolling 3-t accumulators (static t%3 under full unroll); retire t=l-2 with
// fused gate.  S staged k-slot-major [28][64][16B] (conflict-free quarter-wave
// reads); W frags straight from global (86KB, L2-resident).
// ---------------------------------------------------------------------------

typedef __attribute__((ext_vector_type(8))) short s16x8;
typedef __attribute__((ext_vector_type(4))) short s16x4;
typedef __attribute__((ext_vector_type(4))) float f32x4;

#define DEVFN __device__ __forceinline__

DEVFN void gload16(const void* g, void* l) {
  __builtin_amdgcn_global_load_lds((const __attribute__((address_space(1))) unsigned int*)g,
                                   (__attribute__((address_space(3))) unsigned int*)l, 16, 0, 0);
}

DEVFN unsigned short f2bf(float f) {  // round-to-nearest-even f32 -> bf16
  union { float f; unsigned int u; } v; v.f = f;
  unsigned int u = v.u;
  return (unsigned short)((u + 0x7fffu + ((u >> 16) & 1u)) >> 16);
}

// ---------------------------------------------------------------------------
// x (B,C,4000,12) f32 -> Xt[col=b*384+l*32+c][v 4096] bf16  (GEMM1 P operand)
//                     -> Scat[(b*4000+v)*12+l][224] slice j=0 (cols 0..31)
// ---------------------------------------------------------------------------
__global__ void k_transpose(const float* __restrict__ x,
                            unsigned short* __restrict__ Xt,
                            unsigned short* __restrict__ Scat) {
  __shared__ float ldsT[32 * 417];   // [c]*417 + vv*13 + l
  int v0 = blockIdx.x * 32;
  int b = blockIdx.y;
  int tid = threadIdx.x;
  for (int i = tid; i < 1024; i += 256) {
    int c = i >> 5, vv = i & 31;
    const float* src = x + ((size_t)(b * 32 + c) * 4000 + v0 + vv) * 12;
    f32x4 a0 = *(const f32x4*)(src);
    f32x4 a1 = *(const f32x4*)(src + 4);
    f32x4 a2 = *(const f32x4*)(src + 8);
    float* d = ldsT + c * 417 + vv * 13;
    d[0] = a0.x; d[1] = a0.y; d[2] = a0.z; d[3] = a0.w;
    d[4] = a1.x; d[5] = a1.y; d[6] = a1.z; d[7] = a1.w;
    d[8] = a2.x; d[9] = a2.y; d[10] = a2.z; d[11] = a2.w;
  }
  __syncthreads();
  for (int unit = tid; unit < 384; unit += 256) {
    int l = unit >> 5, c = unit & 31;
    alignas(16) unsigned short tmp[32];
#pragma unroll
    for (int vv = 0; vv < 32; ++vv) tmp[vv] = f2bf(ldsT[c * 417 + vv * 13 + l]);
    unsigned short* dst = Xt + (size_t)(b * 384 + l * 32 + c) * 4096 + v0;
#pragma unroll
    for (int j = 0; j < 4; ++j) *(s16x8*)(dst + j * 8) = *(const s16x8*)(tmp + j * 8);
  }
  for (int unit = tid; unit < 384; unit += 256) {
    int l = unit >> 5, vv = unit & 31;
    alignas(16) unsigned short tmp[32];
#pragma unroll
    for (int c = 0; c < 32; ++c) tmp[c] = f2bf(ldsT[c * 417 + vv * 13 + l]);
    unsigned short* dst = Scat + ((size_t)(b * 4000 + v0 + vv) * 12 + l) * 224;
#pragma unroll
    for (int j = 0; j < 4; ++j) *(s16x8*)(dst + j * 8) = *(const s16x8*)(tmp + j * 8);
  }
}

// A (4000,4000) f32 -> A_bf[4096][4096] bf16, zero-padded rows/cols.
__global__ void k_castA(const float* __restrict__ A, unsigned short* __restrict__ Abf) {
  int idx = blockIdx.x * 256 + threadIdx.x;
  int r = idx >> 10;
  int c4 = (idx & 1023) << 2;
  alignas(8) unsigned short o[4] = {0, 0, 0, 0};
  if (r < 4000 && c4 < 4000) {
    f32x4 v = *(const f32x4*)(A + (size_t)r * 4000 + c4);
    o[0] = f2bf(v.x); o[1] = f2bf(v.y); o[2] = f2bf(v.z); o[3] = f2bf(v.w);
  }
  *(s16x4*)(Abf + (size_t)r * 4096 + c4) = *(const s16x4*)o;
}

// mlp_w (64,224,1,3) f32 -> Wcat[oc][kt*224+ic] bf16 (t-independent)
__global__ void k_wcat(const float* __restrict__ mlp_w, unsigned short* __restrict__ Wcat) {
  int i = blockIdx.x * 256 + threadIdx.x;
  if (i >= 64 * 672) return;
  int oc = i / 672, k = i % 672;
  int kt = k / 224, ic = k % 224;
  Wcat[i] = f2bf(mlp_w[((size_t)oc * 224 + ic) * 3 + kt]);
}

// ---------------------------------------------------------------------------
// C[m][n] = sum_k P[m][k] * Q[n][k], bf16, K=4096.  192x256 tile, BK=64,
// 8 waves (2M x 4N, wave-tile 96x64), 6 single-barrier phases per 2 K-tiles,
// counted vmcnt(2), XOR k-slot swizzle.  Grid 256 = 1/CU.
// ---------------------------------------------------------------------------
#define MFMA_(a, b, c) __builtin_amdgcn_mfma_f32_16x16x32_bf16(a, b, c, 0, 0, 0)

#define STGA(d, t) do {                                                          \
    const unsigned short* _s = aSrc + (size_t)(t) * 64;                          \
    unsigned short* _l = smem + (d) * 12288;                                     \
    gload16(_s,          _l + tid * 8);                                          \
    gload16(_s + 262144, _l + (512 + tid) * 8);                                  \
    gload16(_s + 524288, _l + (1024 + tid) * 8);                                 \
  } while (0)

#define STGB(d, h, t) do {                                                       \
    const unsigned short* _s = bSrc + (size_t)(h) * 524288 + (size_t)(t) * 64;   \
    unsigned short* _l = smem + 24576 + ((d) * 2 + (h)) * 8192;                  \
    gload16(_s,          _l + tid * 8);                                          \
    gload16(_s + 262144, _l + (512 + tid) * 8);                                  \
  } while (0)

#define LDA_(d, f, kk) (*(const s16x8*)(smem + (d) * 12288 + aoff + (f) * 1024 + ((kk) ? sxor : 0)))
#define LDB_(d, nf, kk) (*(const s16x8*)(smem + 24576 + ((d) * 2 + hb) * 8192 + boff + (nf) * 1024 + ((kk) ? sxor : 0)))

// single-barrier phase: {reads; stage; [vmcnt]; barrier; lgkm(0); MFMA}
#define PHASE(d, mp, FIRST, STAGE_CODE, VM) do {                                 \
    s16x8 a00 = LDA_(d, 2 * (mp), 0),     a01 = LDA_(d, 2 * (mp), 1);            \
    s16x8 a10 = LDA_(d, 2 * (mp) + 1, 0), a11 = LDA_(d, 2 * (mp) + 1, 1);        \
    if (FIRST) {                                                                 \
      _Pragma("unroll")                                                          \
      for (int nf = 0; nf < 4; ++nf) { bfr[nf][0] = LDB_(d, nf, 0); bfr[nf][1] = LDB_(d, nf, 1); } \
    }                                                                            \
    STAGE_CODE;                                                                  \
    if (VM) asm volatile("s_waitcnt vmcnt(2)" ::: "memory");                     \
    __builtin_amdgcn_s_barrier();                                                \
    asm volatile("s_waitcnt lgkmcnt(0)" ::: "memory");                           \
    __builtin_amdgcn_s_setprio(1);                                               \
    _Pragma("unroll")                                                            \
    for (int nf = 0; nf < 4; ++nf) {                                             \
      acc[2 * (mp)][nf]     = MFMA_(a00, bfr[nf][0], acc[2 * (mp)][nf]);         \
      acc[2 * (mp)][nf]     = MFMA_(a01, bfr[nf][1], acc[2 * (mp)][nf]);         \
      acc[2 * (mp) + 1][nf] = MFMA_(a10, bfr[nf][0], acc[2 * (mp) + 1][nf]);     \
      acc[2 * (mp) + 1][nf] = MFMA_(a11, bfr[nf][1], acc[2 * (mp) + 1][nf]);     \
    }                                                                            \
    __builtin_amdgcn_s_setprio(0);                                               \
  } while (0)

template <int WRITE_C1>
__global__ __launch_bounds__(512, 2)
void k_gemm(const unsigned short* __restrict__ P, const unsigned short* __restrict__ Q,
            unsigned short* __restrict__ C1, unsigned short* __restrict__ Scat, int jcol) {
  extern __shared__ unsigned short smem[];   // 57344 shorts = 112 KiB
  int tid = threadIdx.x;
  int w = tid >> 6, lane = tid & 63;
  int lr = lane & 15, g = lane >> 4;
  int mq = w >> 2, nq = w & 3;               // 2M x 4N wave grid (96 x 64 each)
  int bid = blockIdx.x;
  int xcd = bid & 7, lid = bid >> 3;         // 256 blocks; per XCD: 2 n-tiles x 16 m-tiles
  int nt = xcd * 2 + (lid >> 4);
  int mt = lid & 15;
  int m0 = mt * 192, n0 = nt * 256;
  int hb = nq >> 1;
  int slot0 = (g ^ (lr & 7)) * 8;
  int sxor = (slot0 & 32) ? -32 : 32;
  int aoff = (mq * 96 + lr) * 64 + slot0;
  int boff = ((nq & 1) * 64 + lr) * 64 + slot0;
  int gk = ((tid & 7) ^ ((tid >> 3) & 7)) * 8;   // pre-swizzled global k offset
  const unsigned short* aSrc = P + (size_t)(m0 + (tid >> 3)) * 4096 + gk;
  const unsigned short* bSrc = Q + (size_t)(n0 + (tid >> 3)) * 4096 + gk;
  f32x4 acc[6][4] = {};
  s16x8 bfr[4][2];

  // prologue: A(d0,t0), B(d0,t0) h0+h1, B(d1,t1) h0; vmcnt(2) retires the
  // first 7 (A(d0)+B(d0)), keeps B(d1,t1)h0 in flight.
  STGA(0, 0);
  STGB(0, 0, 0); STGB(0, 1, 0);
  STGB(1, 0, 1);
  asm volatile("s_waitcnt vmcnt(2)" ::: "memory");
  __builtin_amdgcn_s_barrier();

#pragma unroll 1
  for (int i = 0; i < 32; ++i) {
    int t1 = 2 * i + 1, t2 = 2 * i + 2, t3 = 2 * i + 3;
    PHASE(0, 0, 1, STGB(1, 1, t1), 0);   // ph1: B(d1,h1,t1)
    PHASE(0, 1, 0, STGA(1, t1),    0);   // ph2: A(d1,t1)
    PHASE(0, 2, 0, STGB(0, 0, t2), 1);   // ph3: B(d0,h0,t2) + vmcnt(2) -> d1 ready
    PHASE(1, 0, 1, STGB(0, 1, t2), 0);   // ph4: B(d0,h1,t2)
    PHASE(1, 1, 0, STGA(0, t2),    0);   // ph5: A(d0,t2)
    PHASE(1, 2, 0, STGB(1, 0, t3), 1);   // ph6: B(d1,h0,t3) + vmcnt(2) -> d0 ready
  }

  // epilogue: drain, single-pass repack via LDS [192][264]
  asm volatile("s_waitcnt vmcnt(0) lgkmcnt(0)" ::: "memory");
  __syncthreads();
  unsigned short* eld = smem;
  int rb = g * 4;
#pragma unroll
  for (int f = 0; f < 6; ++f)
#pragma unroll
    for (int nf = 0; nf < 4; ++nf)
#pragma unroll
      for (int r = 0; r < 4; ++r)
        eld[(mq * 96 + f * 16 + rb + r) * 264 + nq * 64 + nf * 16 + lr] = f2bf(acc[f][nf][r]);
  __syncthreads();
  if (WRITE_C1) {
#pragma unroll
    for (int uu = 0; uu < 2; ++uu) {
      int u = uu * 512 + tid;
      if (u < 768) {
        int row = u >> 2, q = u & 3;
        unsigned short* dst = C1 + (size_t)(m0 + row) * 4096 + n0 + q * 64;
        const unsigned short* sp = eld + row * 264 + q * 64;
#pragma unroll
        for (int j = 0; j < 8; ++j) *(s16x8*)(dst + j * 8) = *(const s16x8*)(sp + j * 8);
      }
    }
  }
  int bb2 = m0 / 384, lb = (m0 % 384) >> 5;
#pragma unroll
  for (int uu = 0; uu < 3; ++uu) {
    int u = uu * 512 + tid;                  // 1536 units: 6 lg x 256 nl
    int lg = u >> 8, nl = u & 255;
    int node = n0 + nl;
    if (node < 4000) {
      alignas(16) unsigned short tmp[32];
#pragma unroll
      for (int c = 0; c < 32; ++c) tmp[c] = eld[(lg * 32 + c) * 264 + nl];
      unsigned short* d2 = Scat + ((size_t)(bb2 * 4000 + node) * 12 + lb + lg) * 224 + jcol;
#pragma unroll
      for (int j = 0; j < 4; ++j) *(s16x8*)(d2 + j * 8) = *(const s16x8*)(tmp + j * 8);
    }
  }
}

// ---------------------------------------------------------------------------
// k_mlp v2: one pass over Scat.  Grid 500 x 256 (4 waves), bn-tile 64.
// l = 0..11: stage S-slice [64 bn][224] k-slot-major into LDS dbuf; slice l
// feeds t in {l-2,l-1,l} with weight slice kt = l-t.  Rolling acc[t%3][4].
// Wave w: p=w&1 -> oc rows {p*16..+15, 32+p*16..+15} (gate pairs in-wave);
// q=w>>1 -> bn half.  Retire t=l-2: gate tanh*sigmoid -> G[b][t][c][4096].
// ---------------------------------------------------------------------------
#define MLPSTG(L, BUF) do {                                                   \
    _Pragma("unroll")                                                         \
    for (int j = 0; j < 7; ++j) {                                             \
      int u = j * 256 + tid;                                                  \
      int s = u >> 6, bn = u & 63;                                            \
      gload16(Scat + ((size_t)(bn0 + bn) * 12 + (L)) * 224 + s * 8,           \
              lds + (BUF) * 14336 + u * 8);                                   \
    }                                                                         \
  } while (0)

__global__ __launch_bounds__(256, 2)
void k_mlp(const unsigned short* __restrict__ Wcat, const unsigned short* __restrict__ Scat,
           const float* __restrict__ mlp_b, float* __restrict__ G) {
  __shared__ unsigned short lds[2 * 14336];  // two [28 slot][64 bn][8] S-slices (56KB)
  int tid = threadIdx.x;
  int bn0 = blockIdx.x * 64;
  int w = tid >> 6, lane = tid & 63;
  int lr = lane & 15, g = lane >> 4;
  int p = w & 1, q = w >> 1;
  const unsigned short* w1 = Wcat + (size_t)(p * 16 + lr) * 672 + g * 8;
  const unsigned short* w2 = w1 + 32 * 672;
  f32x4 acc[3][4];

  MLPSTG(0, 0);
  asm volatile("s_waitcnt vmcnt(0)" ::: "memory");
  __syncthreads();

#pragma unroll
  for (int l = 0; l < 12; ++l) {
    if (l < 11) MLPSTG(l + 1, (l + 1) & 1);
    if (l <= 9) {
#pragma unroll
      for (int f = 0; f < 4; ++f) acc[l % 3][f] = (f32x4){0.f, 0.f, 0.f, 0.f};
    }
    const unsigned short* sb = lds + (l & 1) * 14336;
#pragma unroll
    for (int kt = 0; kt < 3; ++kt) {
      int t = l - kt;
      if (t < 0 || t > 9) continue;
      int st = t % 3;
#pragma unroll
      for (int ks = 0; ks < 7; ++ks) {
        s16x8 a1 = *(const s16x8*)(w1 + kt * 224 + ks * 32);
        s16x8 a2 = *(const s16x8*)(w2 + kt * 224 + ks * 32);
        const unsigned short* bbase = sb + ((ks * 4 + g) * 64 + q * 32 + lr) * 8;
        s16x8 b0 = *(const s16x8*)(bbase);
        s16x8 b1 = *(const s16x8*)(bbase + 128);   // +16 bn rows
        acc[st][0] = MFMA_(a1, b0, acc[st][0]);
        acc[st][1] = MFMA_(a1, b1, acc[st][1]);
        acc[st][2] = MFMA_(a2, b0, acc[st][2]);
        acc[st][3] = MFMA_(a2, b1, acc[st][3]);
      }
    }
    if (l >= 2) {                     // retire t = l-2 (complete after kt=2)
      int t = l - 2, st = t % 3;
#pragma unroll
      for (int bf = 0; bf < 2; ++bf) {
        int nglob = bn0 + q * 32 + bf * 16 + lr;
        int b = nglob / 4000, nn = nglob - b * 4000;
        float* gout = G + ((size_t)(b * 10 + t) * 32) * 4096 + nn;
#pragma unroll
        for (int r = 0; r < 4; ++r) {
          int c = p * 16 + g * 4 + r;
          float v1 = acc[st][bf][r] + mlp_b[c];
          float v2 = acc[st][2 + bf][r] + mlp_b[c + 32];
          gout[(size_t)c * 4096] = tanhf(v1) * (1.0f / (1.0f + __expf(-v2)));
        }
      }
    }
    asm volatile("s_waitcnt vmcnt(0)" ::: "memory");
    __syncthreads();
  }
}

// ct1: g6[b][c][n][q] = ct1_b[q] + sum_{l<10} ct1_w[q][l] * G[b][l][c][n]
__global__ void k_ct1(const float* __restrict__ G, const float* __restrict__ ct1_w,
                      const float* __restrict__ ct1_b, float* __restrict__ g6) {
  int idx = blockIdx.x * 256 + threadIdx.x;
  if (idx >= 8 * 32 * 4000) return;
  int n = idx % 4000;
  int c = (idx / 4000) % 32;
  int b = idx / (4000 * 32);
  const float* gp = G + ((size_t)(b * 10) * 32 + c) * 4096 + n;
  float v[10];
#pragma unroll
  for (int l = 0; l < 10; ++l) v[l] = gp[(size_t)l * 32 * 4096];
  float* o = g6 + (size_t)idx * 6;
#pragma unroll
  for (int q = 0; q < 6; ++q) {
    float a = ct1_b[q];
#pragma unroll
    for (int l = 0; l < 10; ++l) a += ct1_w[q * 10 + l] * v[l];
    o[q] = a;
  }
}

// f1[b][t][n] = sum_c c1[c] * g6[b][c][n][t]
__global__ void k_f1(const float* __restrict__ g6, const float* __restrict__ c1,
                     float* __restrict__ f1) {
  int idx = blockIdx.x * 128 + threadIdx.x;
  if (idx >= 8 * 4000) return;
  int n = idx % 4000, b = idx / 4000;
  float acc[6] = {};
  const float* gp = g6 + ((size_t)b * 32 * 4000 + n) * 6;
  for (int c = 0; c < 32; ++c) {
    float wv = c1[c];
    const float* p = gp + (size_t)c * 4000 * 6;
#pragma unroll
    for (int t = 0; t < 6; ++t) acc[t] += wv * p[t];
  }
  for (int t = 0; t < 6; ++t) f1[((size_t)b * 6 + t) * 4000 + n] = acc[t];
}

// f2[b][c][t] = sum_n c2[n] * g6[b][c][n][t]
__global__ void k_f2(const float* __restrict__ g6, const float* __restrict__ c2,
                     float* __restrict__ f2) {
  __shared__ float red[256 * 6];
  int bc = blockIdx.x;
  int tid = threadIdx.x;
  float acc[6] = {};
  const float* gp = g6 + (size_t)bc * 4000 * 6;
  for (int n = tid; n < 4000; n += 256) {
    float wv = c2[n];
#pragma unroll
    for (int t = 0; t < 6; ++t) acc[t] += wv * gp[(size_t)n * 6 + t];
  }
  for (int t = 0; t < 6; ++t) red[tid * 6 + t] = acc[t];
  __syncthreads();
  for (int s = 128; s > 0; s >>= 1) {
    if (tid < s)
      for (int t = 0; t < 6; ++t) red[tid * 6 + t] += red[(tid + s) * 6 + t];
    __syncthreads();
  }
  if (tid < 6) f2[bc * 6 + tid] = red[tid];
}

// m1[b][t][c] += sum over n-chunk of f1[b][t][n] * tat_w[n][c]; grid (48,16)
__global__ void k_m1(const float* __restrict__ f1, const float* __restrict__ tw,
                     float* __restrict__ m1) {
  __shared__ float red[8][32];
  int bt = blockIdx.x;
  int nc = blockIdx.y;
  int tid = threadIdx.x;
  int c = tid & 31, gi = tid >> 5;
  float acc = 0.f;
  const float* fp = f1 + (size_t)bt * 4000 + nc * 250;
  const float* twp = tw + ((size_t)nc * 250) * 32 + c;
  for (int n = gi; n < 250; n += 8) acc += fp[n] * twp[n * 32];
  red[gi][c] = acc;
  __syncthreads();
  if (tid < 32) {
    float s = 0.f;
#pragma unroll
    for (int gg = 0; gg < 8; ++gg) s += red[gg][c];
    atomicAdd(&m1[(size_t)bt * 32 + c], s);
  }
}

// logits -> sigmoid -> tat_v mix -> BN1 -> softmax -> coefs[b][t][q]
__global__ void k_att(const float* __restrict__ m1, const float* __restrict__ f2,
                      const float* __restrict__ bias, const float* __restrict__ tv,
                      const float* __restrict__ g1, const float* __restrict__ b1,
                      float* __restrict__ coefs) {
  __shared__ float sig[48 * 6], lgs[48 * 6], mu[6], iv[6];
  int tid = threadIdx.x;
  int b = tid / 6, t = tid % 6;
  if (tid < 48) {
    for (int s = 0; s < 6; ++s) {
      float a = bias[t * 6 + s];
      for (int c = 0; c < 32; ++c)
        a += m1[((size_t)b * 6 + t) * 32 + c] * f2[((size_t)b * 32 + c) * 6 + s];
      sig[tid * 6 + s] = 1.0f / (1.0f + __expf(-a));
    }
  }
  __syncthreads();
  if (tid < 48) {
    for (int q = 0; q < 6; ++q) {
      float a = 0.f;
      for (int s = 0; s < 6; ++s) a += tv[t * 6 + s] * sig[(b * 6 + s) * 6 + q];
      lgs[tid * 6 + q] = a;
    }
  }
  __syncthreads();
  if (tid < 6) {
    float s = 0, s2 = 0;
    for (int r = 0; r < 48; ++r) { float v = lgs[r * 6 + tid]; s += v; s2 += v * v; }
    float m = s / 48.f;
    mu[tid] = m;
    iv[tid] = rsqrtf(s2 / 48.f - m * m + 1e-5f);
  }
  __syncthreads();
  if (tid < 48) {
    float v[6], mx = -1e30f;
    for (int q = 0; q < 6; ++q) {
      v[q] = (lgs[tid * 6 + q] - mu[q]) * iv[q] * g1[q] + b1[q];
      mx = fmaxf(mx, v[q]);
    }
    float s = 0;
    for (int q = 0; q < 6; ++q) { v[q] = __expf(v[q] - mx); s += v[q]; }
    float inv = 1.0f / s;
    for (int q = 0; q < 6; ++q) coefs[tid * 6 + q] = v[q] * inv;
  }
}

// y = attention-mix(g6) + conv1(x)[...,6:] -> out (pre-BN2)
__global__ void k_final1(const float* __restrict__ x, const float* __restrict__ cw,
                         const float* __restrict__ cb, const float* __restrict__ g6,
                         const float* __restrict__ coefs, float* __restrict__ out) {
  __shared__ float xt[32 * 8 * 6];
  __shared__ float cwT[1024];
  __shared__ float cfs[36], cbs[32];
  int n0 = blockIdx.x * 8;
  int b = blockIdx.y;
  int tid = threadIdx.x;
  {
    int ci = tid >> 3, seg = tid & 7;
    const float* xp = x + ((size_t)(b * 32 + ci) * 4000 + n0 + seg) * 12 + 6;
#pragma unroll
    for (int q = 0; q < 6; ++q) xt[(ci * 8 + seg) * 6 + q] = xp[q];
  }
  for (int i = tid; i < 1024; i += 256) { int o = i >> 5, ci = i & 31; cwT[ci * 32 + o] = cw[i]; }
  if (tid < 36) cfs[tid] = coefs[b * 36 + tid];
  if (tid < 32) cbs[tid] = cb[tid];
  __syncthreads();
  int nn = tid & 7, c = tid >> 3;
  const float* gp = g6 + ((size_t)(b * 32 + c) * 4000 + n0 + nn) * 6;
  float gv[6];
#pragma unroll
  for (int l = 0; l < 6; ++l) gv[l] = gp[l];
  float y[6];
#pragma unroll
  for (int q = 0; q < 6; ++q) {
    float at = 0.f;
#pragma unroll
    for (int l = 0; l < 6; ++l) at += gv[l] * cfs[q * 6 + l];
    y[q] = at + cbs[c];
  }
  for (int ci = 0; ci < 32; ++ci) {
    float wv = cwT[ci * 32 + c];
#pragma unroll
    for (int q = 0; q < 6; ++q) y[q] += wv * xt[(ci * 8 + nn) * 6 + q];
  }
  float* op = out + ((size_t)(b * 32 + c) * 4000 + n0 + nn) * 6;
#pragma unroll
  for (int q = 0; q < 6; ++q) op[q] = y[q];
}

// per-channel sum/sumsq of out: grid (4, 256), f32x4 + shfl reduce + atomicAdd
__global__ void k_stats(const float* __restrict__ out, float* __restrict__ stats) {
  __shared__ float r1[4], r2[4];
  int bc = blockIdx.y;
  int c = bc & 31;
  int tid = threadIdx.x;
  const float* p = out + (size_t)bc * 24000 + blockIdx.x * 6000;
  float s = 0.f, s2 = 0.f;
  for (int i = tid * 4; i < 6000; i += 1024) {
    f32x4 v = *(const f32x4*)(p + i);
    s  += v.x + v.y + v.z + v.w;
    s2 += v.x * v.x + v.y * v.y + v.z * v.z + v.w * v.w;
  }
#pragma unroll
  for (int off = 32; off > 0; off >>= 1) {
    s  += __shfl_down(s, off);
    s2 += __shfl_down(s2, off);
  }
  int lane = tid & 63, w = tid >> 6;
  if (lane == 0) { r1[w] = s; r2[w] = s2; }
  __syncthreads();
  if (tid == 0) {
    atomicAdd(&stats[c],      r1[0] + r1[1] + r1[2] + r1[3]);
    atomicAdd(&stats[32 + c], r2[0] + r2[1] + r2[2] + r2[3]);
  }
}

__global__ void k_final2(float* __restrict__ out, const float* __restrict__ stats,
                         const float* __restrict__ g2, const float* __restrict__ b2) {
  int idx = (blockIdx.x * 256 + threadIdx.x) * 4;
  if (idx >= 6144000) return;
  int c = (idx / 24000) % 32;
  float mean = stats[c] * (1.0f / 192000.f);
  float var = stats[32 + c] * (1.0f / 192000.f) - mean * mean;
  float sc = rsqrtf(var + 1e-5f) * g2[c];
  float sh = b2[c] - mean * sc;
  f32x4 v = *(f32x4*)(out + idx);
  v.x = v.x * sc + sh; v.y = v.y * sc + sh; v.z = v.z * sc + sh; v.w = v.w * sc + sh;
  *(f32x4*)(out + idx) = v;
}

// ---------------------------------------------------------------------------
extern "C" void kernel_launch(void* const* d_in, const int* in_sizes, int n_in,
                              void* d_out, int out_size, void* d_ws, size_t ws_size,
                              hipStream_t stream) {
  (void)in_sizes; (void)n_in; (void)out_size;
  const float* x       = (const float*)d_in[0];
  const float* A[3]    = {(const float*)d_in[1], (const float*)d_in[2], (const float*)d_in[3]};
  const float* conv1_w = (const float*)d_in[4];
  const float* conv1_b = (const float*)d_in[5];
  const float* mlp_w   = (const float*)d_in[6];
  const float* mlp_b   = (const float*)d_in[7];
  const float* ct1_w   = (const float*)d_in[8];
  const float* ct1_b   = (const float*)d_in[9];
  const float* c1w     = (const float*)d_in[10];
  const float* c2w     = (const float*)d_in[11];
  const float* tw      = (const float*)d_in[12];
  const float* tbias   = (const float*)d_in[13];
  const float* tv      = (const float*)d_in[14];
  const float* bn1g    = (const float*)d_in[15];
  const float* bn1b    = (const float*)d_in[16];
  const float* bn2g    = (const float*)d_in[17];
  const float* bn2b    = (const float*)d_in[18];
  float* out = (float*)d_out;

  char* ws = (char*)d_ws;
  size_t off = 0;
  auto alloc = [&](size_t bytes) { size_t r = off; off += (bytes + 255) & ~(size_t)255; return r; };
  size_t oScat = alloc(172032000);   // [32000*12][224] bf16
  size_t oXt   = alloc(25165824);    // [3072][4096] bf16 ; later g6 (24.576MB f32)
  size_t oA    = alloc(33554432);    // Abf [4096][4096] bf16 ; with oY1t, later G
  size_t oY1t  = alloc(25165824);    // [3072][4096] bf16
  size_t oWcat = alloc(86016);
  size_t oF1 = alloc(768000);
  size_t oF2 = alloc(6144);
  size_t oM1 = alloc(6144);
  size_t oCf = alloc(1152);
  size_t oSt = alloc(256);
  if (ws_size < off) return;  // insufficient scratch -> visible validation failure

  unsigned short* Scat = (unsigned short*)(ws + oScat);
  unsigned short* Xt   = (unsigned short*)(ws + oXt);
  float*          g6   = (float*)(ws + oXt);
  unsigned short* Abf  = (unsigned short*)(ws + oA);
  float*          G    = (float*)(ws + oA);
  unsigned short* Y1t  = (unsigned short*)(ws + oY1t);
  unsigned short* Wcat = (unsigned short*)(ws + oWcat);

  hipFuncSetAttribute((const void*)k_gemm<0>, hipFuncAttributeMaxDynamicSharedMemorySize, 114688);
  hipFuncSetAttribute((const void*)k_gemm<1>, hipFuncAttributeMaxDynamicSharedMemorySize, 114688);

  hipMemsetAsync(Xt, 0, 25165824, stream);       // v-padding 4000..4095 must be 0
  hipMemsetAsync(ws + oSt, 0, 256, stream);      // stats accumulators
  hipMemsetAsync(ws + oM1, 0, 6144, stream);     // m1 accumulators
  k_transpose<<<dim3(125, 8), 256, 0, stream>>>(x, Xt, Scat);
  k_wcat<<<168, 256, 0, stream>>>(mlp_w, Wcat);
  for (int i = 0; i < 3; ++i) {
    k_castA<<<16384, 256, 0, stream>>>(A[i], Abf);
    // Y1t[col][node] = sum_v Xt[col][v]*Abf[node][v]; Scat j=2i+1
    k_gemm<1><<<256, 512, 114688, stream>>>(Xt, Abf, Y1t, Scat, (2 * i + 1) * 32);
    // x2^T[col][node] = sum_v Y1t[col][v]*Abf[node][v]; Scat j=2i+2
    k_gemm<0><<<256, 512, 114688, stream>>>(Y1t, Abf, nullptr, Scat, (2 * i + 2) * 32);
  }
  k_mlp<<<500, 256, 0, stream>>>(Wcat, Scat, mlp_b, G);
  k_ct1<<<4000, 256, 0, stream>>>(G, ct1_w, ct1_b, g6);
  k_f1<<<250, 128, 0, stream>>>(g6, c1w, (float*)(ws + oF1));
  k_f2<<<256, 256, 0, stream>>>(g6, c2w, (float*)(ws + oF2));
  k_m1<<<dim3(48, 16), 256, 0, stream>>>((float*)(ws + oF1), tw, (float*)(ws + oM1));
  k_att<<<1, 64, 0, stream>>>((float*)(ws + oM1), (float*)(ws + oF2), tbias, tv, bn1g, bn1b,
                              (float*)(ws + oCf));
  k_final1<<<dim3(500, 8), 256, 0, stream>>>(x, conv1_w, conv1_b, g6, (float*)(ws + oCf), out);
  k_stats<<<dim3(4, 256), 256, 0, stream>>>(out, (float*)(ws + oSt));
  k_final2<<<6000, 256, 0, stream>>>(out, (float*)(ws + oSt), bn2g, bn2b);
}

// Round 12
// 761.182 us; speedup vs baseline: 1.7778x; 1.0623x over previous
//
#include <hip/hip_runtime.h>
#include <hip/hip_bf16.h>
#include <cstdint>
#include <cstddef>

// ---------------------------------------------------------------------------
// GCNPool fused pipeline, MI355X/gfx950.  B=8, C=32, N=4000 (pad 4096), T=12.
// Round 12: kill the k_mlp request storm.  (1) Scat -> l-major k-slot layout
// [l][bn/64][28][64][16B]: mlp stages one contiguous 28KB block per slice;
// GEMM/transpose epilogues write contiguous 16Bx64 streams per slot.
// (2) W hoisted to registers once via per-thread-contiguous Wcat2 (wa/wb[21],
// 168 VGPR; 512-thr 8-wave blocks, 16-bn waves).  (3) ct1 fused into retire
// (g6a[4][6] += ct1_w[q][t]*gated) -> k_ct1 and the G intermediate removed.
// ---------------------------------------------------------------------------

typedef __attribute__((ext_vector_type(8))) short s16x8;
typedef __attribute__((ext_vector_type(4))) short s16x4;
typedef __attribute__((ext_vector_type(4))) float f32x4;

#define DEVFN __device__ __forceinline__

DEVFN void gload16(const void* g, void* l) {
  __builtin_amdgcn_global_load_lds((const __attribute__((address_space(1))) unsigned int*)g,
                                   (__attribute__((address_space(3))) unsigned int*)l, 16, 0, 0);
}

DEVFN unsigned short f2bf(float f) {  // round-to-nearest-even f32 -> bf16
  union { float f; unsigned int u; } v; v.f = f;
  unsigned int u = v.u;
  return (unsigned short)((u + 0x7fffu + ((u >> 16) & 1u)) >> 16);
}

// ---------------------------------------------------------------------------
// x (B,C,4000,12) f32 -> Xt[col=b*384+l*32+c][v 4096] bf16  (GEMM1 P operand)
//                     -> Scat slice j=0 (slots 0..3) in l-major k-slot layout
// Scat index: (((l*500 + bn/64)*28 + slot)*64 + bn%64)*8 shorts, bn=b*4000+v.
// ---------------------------------------------------------------------------
__global__ void k_transpose(const float* __restrict__ x,
                            unsigned short* __restrict__ Xt,
                            unsigned short* __restrict__ Scat) {
  __shared__ float ldsT[32 * 417];   // [c]*417 + vv*13 + l
  int v0 = blockIdx.x * 32;
  int b = blockIdx.y;
  int tid = threadIdx.x;
  for (int i = tid; i < 1024; i += 256) {
    int c = i >> 5, vv = i & 31;
    const float* src = x + ((size_t)(b * 32 + c) * 4000 + v0 + vv) * 12;
    f32x4 a0 = *(const f32x4*)(src);
    f32x4 a1 = *(const f32x4*)(src + 4);
    f32x4 a2 = *(const f32x4*)(src + 8);
    float* d = ldsT + c * 417 + vv * 13;
    d[0] = a0.x; d[1] = a0.y; d[2] = a0.z; d[3] = a0.w;
    d[4] = a1.x; d[5] = a1.y; d[6] = a1.z; d[7] = a1.w;
    d[8] = a2.x; d[9] = a2.y; d[10] = a2.z; d[11] = a2.w;
  }
  __syncthreads();
  for (int unit = tid; unit < 384; unit += 256) {
    int l = unit >> 5, c = unit & 31;
    alignas(16) unsigned short tmp[32];
#pragma unroll
    for (int vv = 0; vv < 32; ++vv) tmp[vv] = f2bf(ldsT[c * 417 + vv * 13 + l]);
    unsigned short* dst = Xt + (size_t)(b * 384 + l * 32 + c) * 4096 + v0;
#pragma unroll
    for (int j = 0; j < 4; ++j) *(s16x8*)(dst + j * 8) = *(const s16x8*)(tmp + j * 8);
  }
  for (int unit = tid; unit < 384; unit += 256) {
    int l = unit >> 5, vv = unit & 31;
    alignas(16) unsigned short tmp[32];
#pragma unroll
    for (int c = 0; c < 32; ++c) tmp[c] = f2bf(ldsT[c * 417 + vv * 13 + l]);
    int bn = b * 4000 + v0 + vv;
    unsigned short* dst = Scat + ((((size_t)l * 500 + (bn >> 6)) * 28) * 64 + (bn & 63)) * 8;
#pragma unroll
    for (int j = 0; j < 4; ++j) *(s16x8*)(dst + j * 512) = *(const s16x8*)(tmp + j * 8);
  }
}

// A (4000,4000) f32 -> A_bf[4096][4096] bf16, zero-padded rows/cols.
__global__ void k_castA(const float* __restrict__ A, unsigned short* __restrict__ Abf) {
  int idx = blockIdx.x * 256 + threadIdx.x;
  int r = idx >> 10;
  int c4 = (idx & 1023) << 2;
  alignas(8) unsigned short o[4] = {0, 0, 0, 0};
  if (r < 4000 && c4 < 4000) {
    f32x4 v = *(const f32x4*)(A + (size_t)r * 4000 + c4);
    o[0] = f2bf(v.x); o[1] = f2bf(v.y); o[2] = f2bf(v.z); o[3] = f2bf(v.w);
  }
  *(s16x4*)(Abf + (size_t)r * 4096 + c4) = *(const s16x4*)o;
}

// mlp_w (64,224,1,3) f32 -> Wcat2 per-thread-contiguous:
// [row=(p2*4+g)*16+lr][set s][chunk j=kt*7+ks][8], oc = s*32 + p2*16+lr,
// ic = ks*32+g*8+e.  Size 128*2*21*8 = 43008 shorts = 86KB.
__global__ void k_wcat(const float* __restrict__ mlp_w, unsigned short* __restrict__ Wcat) {
  int i = blockIdx.x * 256 + threadIdx.x;
  if (i >= 43008) return;
  int e = i & 7;
  int j = (i >> 3) % 21;
  int rs = (i >> 3) / 21;
  int s = rs & 1, row = rs >> 1;
  int kt = j / 7, ks = j % 7;
  int p2 = row >> 6, g = (row >> 4) & 3, lr = row & 15;
  int oc = (s ? 32 : 0) + p2 * 16 + lr;
  int ic = ks * 32 + g * 8 + e;
  Wcat[i] = f2bf(mlp_w[((size_t)oc * 224 + ic) * 3 + kt]);
}

// ---------------------------------------------------------------------------
// C[m][n] = sum_k P[m][k] * Q[n][k], bf16, K=4096.  192x256 tile, BK=64,
// 8 waves (2M x 4N, wave-tile 96x64), 6 single-barrier phases per 2 K-tiles,
// counted vmcnt(2), XOR k-slot swizzle.  Grid 256 = 1/CU.
// ---------------------------------------------------------------------------
#define MFMA_(a, b, c) __builtin_amdgcn_mfma_f32_16x16x32_bf16(a, b, c, 0, 0, 0)

#define STGA(d, t) do {                                                          \
    const unsigned short* _s = aSrc + (size_t)(t) * 64;                          \
    unsigned short* _l = smem + (d) * 12288;                                     \
    gload16(_s,          _l + tid * 8);                                          \
    gload16(_s + 262144, _l + (512 + tid) * 8);                                  \
    gload16(_s + 524288, _l + (1024 + tid) * 8);                                 \
  } while (0)

#define STGB(d, h, t) do {                                                       \
    const unsigned short* _s = bSrc + (size_t)(h) * 524288 + (size_t)(t) * 64;   \
    unsigned short* _l = smem + 24576 + ((d) * 2 + (h)) * 8192;                  \
    gload16(_s,          _l + tid * 8);                                          \
    gload16(_s + 262144, _l + (512 + tid) * 8);                                  \
  } while (0)

#define LDA_(d, f, kk) (*(const s16x8*)(smem + (d) * 12288 + aoff + (f) * 1024 + ((kk) ? sxor : 0)))
#define LDB_(d, nf, kk) (*(const s16x8*)(smem + 24576 + ((d) * 2 + hb) * 8192 + boff + (nf) * 1024 + ((kk) ? sxor : 0)))

// single-barrier phase: {reads; stage; [vmcnt]; barrier; lgkm(0); MFMA}
#define PHASE(d, mp, FIRST, STAGE_CODE, VM) do {                                 \
    s16x8 a00 = LDA_(d, 2 * (mp), 0),     a01 = LDA_(d, 2 * (mp), 1);            \
    s16x8 a10 = LDA_(d, 2 * (mp) + 1, 0), a11 = LDA_(d, 2 * (mp) + 1, 1);        \
    if (FIRST) {                                                                 \
      _Pragma("unroll")                                                          \
      for (int nf = 0; nf < 4; ++nf) { bfr[nf][0] = LDB_(d, nf, 0); bfr[nf][1] = LDB_(d, nf, 1); } \
    }                                                                            \
    STAGE_CODE;                                                                  \
    if (VM) asm volatile("s_waitcnt vmcnt(2)" ::: "memory");                     \
    __builtin_amdgcn_s_barrier();                                                \
    asm volatile("s_waitcnt lgkmcnt(0)" ::: "memory");                           \
    __builtin_amdgcn_s_setprio(1);                                               \
    _Pragma("unroll")                                                            \
    for (int nf = 0; nf < 4; ++nf) {                                             \
      acc[2 * (mp)][nf]     = MFMA_(a00, bfr[nf][0], acc[2 * (mp)][nf]);         \
      acc[2 * (mp)][nf]     = MFMA_(a01, bfr[nf][1], acc[2 * (mp)][nf]);         \
      acc[2 * (mp) + 1][nf] = MFMA_(a10, bfr[nf][0], acc[2 * (mp) + 1][nf]);     \
      acc[2 * (mp) + 1][nf] = MFMA_(a11, bfr[nf][1], acc[2 * (mp) + 1][nf]);     \
    }                                                                            \
    __builtin_amdgcn_s_setprio(0);                                               \
  } while (0)

template <int WRITE_C1>
__global__ __launch_bounds__(512, 2)
void k_gemm(const unsigned short* __restrict__ P, const unsigned short* __restrict__ Q,
            unsigned short* __restrict__ C1, unsigned short* __restrict__ Scat, int jslot) {
  extern __shared__ unsigned short smem[];   // 57344 shorts = 112 KiB
  int tid = threadIdx.x;
  int w = tid >> 6, lane = tid & 63;
  int lr = lane & 15, g = lane >> 4;
  int mq = w >> 2, nq = w & 3;               // 2M x 4N wave grid (96 x 64 each)
  int bid = blockIdx.x;
  int xcd = bid & 7, lid = bid >> 3;         // 256 blocks; per XCD: 2 n-tiles x 16 m-tiles
  int nt = xcd * 2 + (lid >> 4);
  int mt = lid & 15;
  int m0 = mt * 192, n0 = nt * 256;
  int hb = nq >> 1;
  int slot0 = (g ^ (lr & 7)) * 8;
  int sxor = (slot0 & 32) ? -32 : 32;
  int aoff = (mq * 96 + lr) * 64 + slot0;
  int boff = ((nq & 1) * 64 + lr) * 64 + slot0;
  int gk = ((tid & 7) ^ ((tid >> 3) & 7)) * 8;   // pre-swizzled global k offset
  const unsigned short* aSrc = P + (size_t)(m0 + (tid >> 3)) * 4096 + gk;
  const unsigned short* bSrc = Q + (size_t)(n0 + (tid >> 3)) * 4096 + gk;
  f32x4 acc[6][4] = {};
  s16x8 bfr[4][2];

  STGA(0, 0);
  STGB(0, 0, 0); STGB(0, 1, 0);
  STGB(1, 0, 1);
  asm volatile("s_waitcnt vmcnt(2)" ::: "memory");
  __builtin_amdgcn_s_barrier();

#pragma unroll 1
  for (int i = 0; i < 32; ++i) {
    int t1 = 2 * i + 1, t2 = 2 * i + 2, t3 = 2 * i + 3;
    PHASE(0, 0, 1, STGB(1, 1, t1), 0);   // ph1: B(d1,h1,t1)
    PHASE(0, 1, 0, STGA(1, t1),    0);   // ph2: A(d1,t1)
    PHASE(0, 2, 0, STGB(0, 0, t2), 1);   // ph3: B(d0,h0,t2) + vmcnt(2)
    PHASE(1, 0, 1, STGB(0, 1, t2), 0);   // ph4: B(d0,h1,t2)
    PHASE(1, 1, 0, STGA(0, t2),    0);   // ph5: A(d0,t2)
    PHASE(1, 2, 0, STGB(1, 0, t3), 1);   // ph6: B(d1,h0,t3) + vmcnt(2)
  }

  // epilogue: drain, single-pass repack via LDS [192][264]
  asm volatile("s_waitcnt vmcnt(0) lgkmcnt(0)" ::: "memory");
  __syncthreads();
  unsigned short* eld = smem;
  int rb = g * 4;
#pragma unroll
  for (int f = 0; f < 6; ++f)
#pragma unroll
    for (int nf = 0; nf < 4; ++nf)
#pragma unroll
      for (int r = 0; r < 4; ++r)
        eld[(mq * 96 + f * 16 + rb + r) * 264 + nq * 64 + nf * 16 + lr] = f2bf(acc[f][nf][r]);
  __syncthreads();
  if (WRITE_C1) {
#pragma unroll
    for (int uu = 0; uu < 2; ++uu) {
      int u = uu * 512 + tid;
      if (u < 768) {
        int row = u >> 2, q = u & 3;
        unsigned short* dst = C1 + (size_t)(m0 + row) * 4096 + n0 + q * 64;
        const unsigned short* sp = eld + row * 264 + q * 64;
#pragma unroll
        for (int j = 0; j < 8; ++j) *(s16x8*)(dst + j * 8) = *(const s16x8*)(sp + j * 8);
      }
    }
  }
  int bb2 = m0 / 384, lb = (m0 % 384) >> 5;
#pragma unroll
  for (int uu = 0; uu < 3; ++uu) {
    int u = uu * 512 + tid;                  // 1536 units: 6 lg x 256 nl
    int lg = u >> 8, nl = u & 255;
    int node = n0 + nl;
    if (node < 4000) {
      alignas(16) unsigned short tmp[32];
#pragma unroll
      for (int c = 0; c < 32; ++c) tmp[c] = eld[(lg * 32 + c) * 264 + nl];
      int bn = bb2 * 4000 + node;
      int l2 = lb + lg;
      unsigned short* d2 = Scat + ((((size_t)l2 * 500 + (bn >> 6)) * 28 + jslot) * 64 + (bn & 63)) * 8;
#pragma unroll
      for (int j = 0; j < 4; ++j) *(s16x8*)(d2 + j * 512) = *(const s16x8*)(tmp + j * 8);
    }
  }
}

// ---------------------------------------------------------------------------
// k_mlp v3 + fused ct1: 512 threads (8 waves: p2=w&1 oc-pair-set, bnq=w>>1),
// grid 500 (bn-group of 64).  W hoisted to wa/wb[21] once (per-thread-
// contiguous Wcat2).  l = 0..11: stage slice (contiguous 28KB) into dbuf;
// rolling acc[3][2]; retire t=l-2 -> gate -> accumulate ct1 into g6a[4][6];
// write g6 at the end.
// ---------------------------------------------------------------------------
#define MLPSTG(L, BUF) do {                                                    \
    const unsigned short* _sb = Scat + ((size_t)(L) * 500 + grp) * 14336;      \
    unsigned short* _lb = lds + (BUF) * 14336;                                 \
    gload16(_sb + tid * 8,          _lb + tid * 8);                            \
    gload16(_sb + (512 + tid) * 8,  _lb + (512 + tid) * 8);                    \
    gload16(_sb + (1024 + tid) * 8, _lb + (1024 + tid) * 8);                   \
    if (tid < 256) gload16(_sb + (1536 + tid) * 8, _lb + (1536 + tid) * 8);    \
  } while (0)

__global__ __launch_bounds__(512, 2)
void k_mlp(const unsigned short* __restrict__ Wcat, const unsigned short* __restrict__ Scat,
           const float* __restrict__ mlp_b, const float* __restrict__ ct1_w,
           const float* __restrict__ ct1_b, float* __restrict__ g6) {
  __shared__ unsigned short lds[2 * 14336];  // two [28][64][8] S-slices (56KB)
  int tid = threadIdx.x;
  int grp = blockIdx.x;
  int w = tid >> 6, lane = tid & 63;
  int lr = lane & 15, g = lane >> 4;
  int p2 = w & 1, bnq = w >> 1;
  const unsigned short* wrow = Wcat + (size_t)(((p2 * 4 + g) * 16 + lr) * 2) * 168;
  s16x8 wa[21], wb[21];
#pragma unroll
  for (int j = 0; j < 21; ++j) {
    wa[j] = *(const s16x8*)(wrow + j * 8);
    wb[j] = *(const s16x8*)(wrow + 168 + j * 8);
  }
  float mb1[4], mb2[4];
#pragma unroll
  for (int r = 0; r < 4; ++r) {
    mb1[r] = mlp_b[p2 * 16 + g * 4 + r];
    mb2[r] = mlp_b[32 + p2 * 16 + g * 4 + r];
  }
  f32x4 acc[3][2];
  float g6a[4][6] = {};

  MLPSTG(0, 0);
  asm volatile("s_waitcnt vmcnt(0)" ::: "memory");
  __syncthreads();

#pragma unroll
  for (int l = 0; l < 12; ++l) {
    if (l < 11) MLPSTG(l + 1, (l + 1) & 1);
    if (l <= 9) {
      acc[l % 3][0] = (f32x4){0.f, 0.f, 0.f, 0.f};
      acc[l % 3][1] = (f32x4){0.f, 0.f, 0.f, 0.f};
    }
    const unsigned short* sb = lds + (l & 1) * 14336;
#pragma unroll
    for (int kt = 0; kt < 3; ++kt) {
      int t = l - kt;
      if (t < 0 || t > 9) continue;
      int st = t % 3;
#pragma unroll
      for (int ks = 0; ks < 7; ++ks) {
        int j = kt * 7 + ks;
        s16x8 bb = *(const s16x8*)(sb + ((ks * 4 + g) * 64 + bnq * 16 + lr) * 8);
        acc[st][0] = MFMA_(wa[j], bb, acc[st][0]);
        acc[st][1] = MFMA_(wb[j], bb, acc[st][1]);
      }
    }
    if (l >= 2) {                     // retire t = l-2
      int t = l - 2, st = t % 3;
#pragma unroll
      for (int r = 0; r < 4; ++r) {
        float v1 = acc[st][0][r] + mb1[r];
        float v2 = acc[st][1][r] + mb2[r];
        float gg = tanhf(v1) * (1.0f / (1.0f + __expf(-v2)));
#pragma unroll
        for (int q6 = 0; q6 < 6; ++q6) g6a[r][q6] += ct1_w[q6 * 10 + t] * gg;
      }
    }
    asm volatile("s_waitcnt vmcnt(0)" ::: "memory");
    __syncthreads();
  }

  int nglob = grp * 64 + bnq * 16 + lr;
  int b = nglob / 4000, nn = nglob - b * 4000;
#pragma unroll
  for (int r = 0; r < 4; ++r) {
    int c = p2 * 16 + g * 4 + r;
    float* op = g6 + ((size_t)(b * 32 + c) * 4000 + nn) * 6;
#pragma unroll
    for (int q6 = 0; q6 < 6; ++q6) op[q6] = g6a[r][q6] + ct1_b[q6];
  }
}

// f1[b][t][n] = sum_c c1[c] * g6[b][c][n][t]
__global__ void k_f1(const float* __restrict__ g6, const float* __restrict__ c1,
                     float* __restrict__ f1) {
  int idx = blockIdx.x * 128 + threadIdx.x;
  if (idx >= 8 * 4000) return;
  int n = idx % 4000, b = idx / 4000;
  float acc[6] = {};
  const float* gp = g6 + ((size_t)b * 32 * 4000 + n) * 6;
  for (int c = 0; c < 32; ++c) {
    float wv = c1[c];
    const float* p = gp + (size_t)c * 4000 * 6;
#pragma unroll
    for (int t = 0; t < 6; ++t) acc[t] += wv * p[t];
  }
  for (int t = 0; t < 6; ++t) f1[((size_t)b * 6 + t) * 4000 + n] = acc[t];
}

// f2[b][c][t] = sum_n c2[n] * g6[b][c][n][t]
__global__ void k_f2(const float* __restrict__ g6, const float* __restrict__ c2,
                     float* __restrict__ f2) {
  __shared__ float red[256 * 6];
  int bc = blockIdx.x;
  int tid = threadIdx.x;
  float acc[6] = {};
  const float* gp = g6 + (size_t)bc * 4000 * 6;
  for (int n = tid; n < 4000; n += 256) {
    float wv = c2[n];
#pragma unroll
    for (int t = 0; t < 6; ++t) acc[t] += wv * gp[(size_t)n * 6 + t];
  }
  for (int t = 0; t < 6; ++t) red[tid * 6 + t] = acc[t];
  __syncthreads();
  for (int s = 128; s > 0; s >>= 1) {
    if (tid < s)
      for (int t = 0; t < 6; ++t) red[tid * 6 + t] += red[(tid + s) * 6 + t];
    __syncthreads();
  }
  if (tid < 6) f2[bc * 6 + tid] = red[tid];
}

// m1[b][t][c] += sum over n-chunk of f1[b][t][n] * tat_w[n][c]; grid (48,16)
__global__ void k_m1(const float* __restrict__ f1, const float* __restrict__ tw,
                     float* __restrict__ m1) {
  __shared__ float red[8][32];
  int bt = blockIdx.x;
  int nc = blockIdx.y;
  int tid = threadIdx.x;
  int c = tid & 31, gi = tid >> 5;
  float acc = 0.f;
  const float* fp = f1 + (size_t)bt * 4000 + nc * 250;
  const float* twp = tw + ((size_t)nc * 250) * 32 + c;
  for (int n = gi; n < 250; n += 8) acc += fp[n] * twp[n * 32];
  red[gi][c] = acc;
  __syncthreads();
  if (tid < 32) {
    float s = 0.f;
#pragma unroll
    for (int gg = 0; gg < 8; ++gg) s += red[gg][c];
    atomicAdd(&m1[(size_t)bt * 32 + c], s);
  }
}

// logits -> sigmoid -> tat_v mix -> BN1 -> softmax -> coefs[b][t][q]
__global__ void k_att(const float* __restrict__ m1, const float* __restrict__ f2,
                      const float* __restrict__ bias, const float* __restrict__ tv,
                      const float* __restrict__ g1, const float* __restrict__ b1,
                      float* __restrict__ coefs) {
  __shared__ float sig[48 * 6], lgs[48 * 6], mu[6], iv[6];
  int tid = threadIdx.x;
  int b = tid / 6, t = tid % 6;
  if (tid < 48) {
    for (int s = 0; s < 6; ++s) {
      float a = bias[t * 6 + s];
      for (int c = 0; c < 32; ++c)
        a += m1[((size_t)b * 6 + t) * 32 + c] * f2[((size_t)b * 32 + c) * 6 + s];
      sig[tid * 6 + s] = 1.0f / (1.0f + __expf(-a));
    }
  }
  __syncthreads();
  if (tid < 48) {
    for (int q = 0; q < 6; ++q) {
      float a = 0.f;
      for (int s = 0; s < 6; ++s) a += tv[t * 6 + s] * sig[(b * 6 + s) * 6 + q];
      lgs[tid * 6 + q] = a;
    }
  }
  __syncthreads();
  if (tid < 6) {
    float s = 0, s2 = 0;
    for (int r = 0; r < 48; ++r) { float v = lgs[r * 6 + tid]; s += v; s2 += v * v; }
    float m = s / 48.f;
    mu[tid] = m;
    iv[tid] = rsqrtf(s2 / 48.f - m * m + 1e-5f);
  }
  __syncthreads();
  if (tid < 48) {
    float v[6], mx = -1e30f;
    for (int q = 0; q < 6; ++q) {
      v[q] = (lgs[tid * 6 + q] - mu[q]) * iv[q] * g1[q] + b1[q];
      mx = fmaxf(mx, v[q]);
    }
    float s = 0;
    for (int q = 0; q < 6; ++q) { v[q] = __expf(v[q] - mx); s += v[q]; }
    float inv = 1.0f / s;
    for (int q = 0; q < 6; ++q) coefs[tid * 6 + q] = v[q] * inv;
  }
}

// y = attention-mix(g6) + conv1(x)[...,6:] -> out (pre-BN2)
__global__ void k_final1(const float* __restrict__ x, const float* __restrict__ cw,
                         const float* __restrict__ cb, const float* __restrict__ g6,
                         const float* __restrict__ coefs, float* __restrict__ out) {
  __shared__ float xt[32 * 8 * 6];
  __shared__ float cwT[1024];
  __shared__ float cfs[36], cbs[32];
  int n0 = blockIdx.x * 8;
  int b = blockIdx.y;
  int tid = threadIdx.x;
  {
    int ci = tid >> 3, seg = tid & 7;
    const float* xp = x + ((size_t)(b * 32 + ci) * 4000 + n0 + seg) * 12 + 6;
#pragma unroll
    for (int q = 0; q < 6; ++q) xt[(ci * 8 + seg) * 6 + q] = xp[q];
  }
  for (int i = tid; i < 1024; i += 256) { int o = i >> 5, ci = i & 31; cwT[ci * 32 + o] = cw[i]; }
  if (tid < 36) cfs[tid] = coefs[b * 36 + tid];
  if (tid < 32) cbs[tid] = cb[tid];
  __syncthreads();
  int nn = tid & 7, c = tid >> 3;
  const float* gp = g6 + ((size_t)(b * 32 + c) * 4000 + n0 + nn) * 6;
  float gv[6];
#pragma unroll
  for (int l = 0; l < 6; ++l) gv[l] = gp[l];
  float y[6];
#pragma unroll
  for (int q = 0; q < 6; ++q) {
    float at = 0.f;
#pragma unroll
    for (int l = 0; l < 6; ++l) at += gv[l] * cfs[q * 6 + l];
    y[q] = at + cbs[c];
  }
  for (int ci = 0; ci < 32; ++ci) {
    float wv = cwT[ci * 32 + c];
#pragma unroll
    for (int q = 0; q < 6; ++q) y[q] += wv * xt[(ci * 8 + nn) * 6 + q];
  }
  float* op = out + ((size_t)(b * 32 + c) * 4000 + n0 + nn) * 6;
#pragma unroll
  for (int q = 0; q < 6; ++q) op[q] = y[q];
}

// per-channel sum/sumsq of out: grid (4, 256), f32x4 + shfl reduce + atomicAdd
__global__ void k_stats(const float* __restrict__ out, float* __restrict__ stats) {
  __shared__ float r1[4], r2[4];
  int bc = blockIdx.y;
  int c = bc & 31;
  int tid = threadIdx.x;
  const float* p = out + (size_t)bc * 24000 + blockIdx.x * 6000;
  float s = 0.f, s2 = 0.f;
  for (int i = tid * 4; i < 6000; i += 1024) {
    f32x4 v = *(const f32x4*)(p + i);
    s  += v.x + v.y + v.z + v.w;
    s2 += v.x * v.x + v.y * v.y + v.z * v.z + v.w * v.w;
  }
#pragma unroll
  for (int off = 32; off > 0; off >>= 1) {
    s  += __shfl_down(s, off);
    s2 += __shfl_down(s2, off);
  }
  int lane = tid & 63, w = tid >> 6;
  if (lane == 0) { r1[w] = s; r2[w] = s2; }
  __syncthreads();
  if (tid == 0) {
    atomicAdd(&stats[c],      r1[0] + r1[1] + r1[2] + r1[3]);
    atomicAdd(&stats[32 + c], r2[0] + r2[1] + r2[2] + r2[3]);
  }
}

__global__ void k_final2(float* __restrict__ out, const float* __restrict__ stats,
                         const float* __restrict__ g2, const float* __restrict__ b2) {
  int idx = (blockIdx.x * 256 + threadIdx.x) * 4;
  if (idx >= 6144000) return;
  int c = (idx / 24000) % 32;
  float mean = stats[c] * (1.0f / 192000.f);
  float var = stats[32 + c] * (1.0f / 192000.f) - mean * mean;
  float sc = rsqrtf(var + 1e-5f) * g2[c];
  float sh = b2[c] - mean * sc;
  f32x4 v = *(f32x4*)(out + idx);
  v.x = v.x * sc + sh; v.y = v.y * sc + sh; v.z = v.z * sc + sh; v.w = v.w * sc + sh;
  *(f32x4*)(out + idx) = v;
}

// ---------------------------------------------------------------------------
extern "C" void kernel_launch(void* const* d_in, const int* in_sizes, int n_in,
                              void* d_out, int out_size, void* d_ws, size_t ws_size,
                              hipStream_t stream) {
  (void)in_sizes; (void)n_in; (void)out_size;
  const float* x       = (const float*)d_in[0];
  const float* A[3]    = {(const float*)d_in[1], (const float*)d_in[2], (const float*)d_in[3]};
  const float* conv1_w = (const float*)d_in[4];
  const float* conv1_b = (const float*)d_in[5];
  const float* mlp_w   = (const float*)d_in[6];
  const float* mlp_b   = (const float*)d_in[7];
  const float* ct1_w   = (const float*)d_in[8];
  const float* ct1_b   = (const float*)d_in[9];
  const float* c1w     = (const float*)d_in[10];
  const float* c2w     = (const float*)d_in[11];
  const float* tw      = (const float*)d_in[12];
  const float* tbias   = (const float*)d_in[13];
  const float* tv      = (const float*)d_in[14];
  const float* bn1g    = (const float*)d_in[15];
  const float* bn1b    = (const float*)d_in[16];
  const float* bn2g    = (const float*)d_in[17];
  const float* bn2b    = (const float*)d_in[18];
  float* out = (float*)d_out;

  char* ws = (char*)d_ws;
  size_t off = 0;
  auto alloc = [&](size_t bytes) { size_t r = off; off += (bytes + 255) & ~(size_t)255; return r; };
  size_t oScat = alloc(172032000);   // [12][500][28][64][8] bf16
  size_t oXt   = alloc(25165824);    // [3072][4096] bf16 ; later g6 (24.576MB f32)
  size_t oA    = alloc(33554432);    // Abf [4096][4096] bf16
  size_t oY1t  = alloc(25165824);    // [3072][4096] bf16
  size_t oWcat = alloc(86016);
  size_t oF1 = alloc(768000);
  size_t oF2 = alloc(6144);
  size_t oM1 = alloc(6144);
  size_t oCf = alloc(1152);
  size_t oSt = alloc(256);
  if (ws_size < off) return;  // insufficient scratch -> visible validation failure

  unsigned short* Scat = (unsigned short*)(ws + oScat);
  unsigned short* Xt   = (unsigned short*)(ws + oXt);
  float*          g6   = (float*)(ws + oXt);
  unsigned short* Abf  = (unsigned short*)(ws + oA);
  unsigned short* Y1t  = (unsigned short*)(ws + oY1t);
  unsigned short* Wcat = (unsigned short*)(ws + oWcat);

  hipFuncSetAttribute((const void*)k_gemm<0>, hipFuncAttributeMaxDynamicSharedMemorySize, 114688);
  hipFuncSetAttribute((const void*)k_gemm<1>, hipFuncAttributeMaxDynamicSharedMemorySize, 114688);

  hipMemsetAsync(Xt, 0, 25165824, stream);       // v-padding 4000..4095 must be 0
  hipMemsetAsync(ws + oSt, 0, 256, stream);      // stats accumulators
  hipMemsetAsync(ws + oM1, 0, 6144, stream);     // m1 accumulators
  k_transpose<<<dim3(125, 8), 256, 0, stream>>>(x, Xt, Scat);
  k_wcat<<<168, 256, 0, stream>>>(mlp_w, Wcat);
  for (int i = 0; i < 3; ++i) {
    k_castA<<<16384, 256, 0, stream>>>(A[i], Abf);
    // Y1t[col][node] = sum_v Xt[col][v]*Abf[node][v]; Scat slots (2i+1)*4..
    k_gemm<1><<<256, 512, 114688, stream>>>(Xt, Abf, Y1t, Scat, (2 * i + 1) * 4);
    // x2^T[col][node] = sum_v Y1t[col][v]*Abf[node][v]; Scat slots (2i+2)*4..
    k_gemm<0><<<256, 512, 114688, stream>>>(Y1t, Abf, nullptr, Scat, (2 * i + 2) * 4);
  }
  k_mlp<<<500, 512, 0, stream>>>(Wcat, Scat, mlp_b, ct1_w, ct1_b, g6);
  k_f1<<<250, 128, 0, stream>>>(g6, c1w, (float*)(ws + oF1));
  k_f2<<<256, 256, 0, stream>>>(g6, c2w, (float*)(ws + oF2));
  k_m1<<<dim3(48, 16), 256, 0, stream>>>((float*)(ws + oF1), tw, (float*)(ws + oM1));
  k_att<<<1, 64, 0, stream>>>((float*)(ws + oM1), (float*)(ws + oF2), tbias, tv, bn1g, bn1b,
                              (float*)(ws + oCf));
  k_final1<<<dim3(500, 8), 256, 0, stream>>>(x, conv1_w, conv1_b, g6, (float*)(ws + oCf), out);
  k_stats<<<dim3(4, 256), 256, 0, stream>>>(out, (float*)(ws + oSt));
  k_final2<<<6000, 256, 0, stream>>>(out, (float*)(ws + oSt), bn2g, bn2b);
}